// Round 1
// baseline (335.203 us; speedup 1.0000x reference)
//
#include <hip/hip_runtime.h>
#include <hip/hip_bf16.h>
#include <stdint.h>

// ---------------------------------------------------------------------------
// MHA block: out = softmax( rope(xWq^T) rope(xWk^T)^T / 8 ) (xWv^T) Wo^T
// B=2 S=2048 H=16 D=64 DIM=1024.  bf16 MFMA compute, fp32 accum/softmax.
// ---------------------------------------------------------------------------

#define AS1(p) ((const __attribute__((address_space(1))) void*)(p))
#define AS3(p) ((__attribute__((address_space(3))) void*)(p))

typedef __attribute__((ext_vector_type(8))) __bf16 bf16x8;
typedef __attribute__((ext_vector_type(4))) float  f32x4;

__device__ __forceinline__ ushort f2b(float f) {
  union { float f; uint32_t u; } v; v.f = f;
  uint32_t u = v.u;
  u += 0x7fffu + ((u >> 16) & 1);   // RNE
  return (ushort)(u >> 16);
}
__device__ __forceinline__ float b2f(ushort s) {
  union { uint32_t u; float f; } v; v.u = ((uint32_t)s) << 16;
  return v.f;
}

// ---------------------------------------------------------------------------
// 1) fp32 -> bf16 conversion of x and the four weights (contiguous in ws).
//    float4-index regions: x 1048576, then 262144 per weight.
// ---------------------------------------------------------------------------
__global__ __launch_bounds__(256) void cvt_all_k(
    const float* __restrict__ x,  const float* __restrict__ wq,
    const float* __restrict__ wk, const float* __restrict__ wv,
    const float* __restrict__ wo, ushort* __restrict__ dst) {
  int i = blockIdx.x * 256 + threadIdx.x;          // 2,097,152 total
  const float* src;
  if      (i < 1048576) src = x  + (size_t)i * 4;
  else if (i < 1310720) src = wq + (size_t)(i - 1048576) * 4;
  else if (i < 1572864) src = wk + (size_t)(i - 1310720) * 4;
  else if (i < 1835008) src = wv + (size_t)(i - 1572864) * 4;
  else                  src = wo + (size_t)(i - 1835008) * 4;
  float4 v = *(const float4*)src;
  ushort4 o;
  o.x = f2b(v.x); o.y = f2b(v.y); o.z = f2b(v.z); o.w = f2b(v.w);
  ((ushort4*)dst)[i] = o;
}

// ---------------------------------------------------------------------------
// 2) GEMM mainloop: C = A(MxK) * W(NxK)^T, 128x128 tile, BK=32, 4 waves (2x2),
//    global_load_lds width=16 staging, m97 2-barrier structure.
//    MFMA 16x16x32 bf16. A-frag: row=lane&15, k=8*(lane>>4)+i (contig 16B).
//    C/D: col=lane&15, row=(lane>>4)*4+reg  [m89-verified].
// ---------------------------------------------------------------------------
__device__ __forceinline__ void gemm_mainloop(
    const ushort* __restrict__ A, const ushort* __restrict__ W,
    int row0, int col0, ushort* lA, ushort* lB, f32x4 acc[4][4]) {
  const int K = 1024;
  int tid = threadIdx.x;
  int lane = tid & 63, wid = tid >> 6;
  int wr = wid >> 1, wc = wid & 1;
  int lr = lane >> 4, lc = lane & 15;
  for (int k0 = 0; k0 < K; k0 += 32) {
#pragma unroll
    for (int i = 0; i < 2; i++) {
      int idx = tid + i * 256;                       // 16B chunk id, 4 per row
      const ushort* ga = A + (size_t)(row0 + (idx >> 2)) * K + k0 + (idx & 3) * 8;
      __builtin_amdgcn_global_load_lds(AS1(ga), AS3(lA + (i * 256 + wid * 64) * 8), 16, 0, 0);
      const ushort* gb = W + (size_t)(col0 + (idx >> 2)) * K + k0 + (idx & 3) * 8;
      __builtin_amdgcn_global_load_lds(AS1(gb), AS3(lB + (i * 256 + wid * 64) * 8), 16, 0, 0);
    }
    __syncthreads();                                 // drains vmcnt -> tile ready
    bf16x8 af[4], bf[4];
#pragma unroll
    for (int m = 0; m < 4; m++)
      af[m] = *(const bf16x8*)(lA + (wr * 64 + m * 16 + lc) * 32 + lr * 8);
#pragma unroll
    for (int n = 0; n < 4; n++)
      bf[n] = *(const bf16x8*)(lB + (wc * 64 + n * 16 + lc) * 32 + lr * 8);
#pragma unroll
    for (int m = 0; m < 4; m++)
#pragma unroll
      for (int n = 0; n < 4; n++)
        acc[m][n] = __builtin_amdgcn_mfma_f32_16x16x32_bf16(af[m], bf[n], acc[m][n], 0, 0, 0);
    __syncthreads();                                 // reads done before next stage
  }
}

// QKV projections in one launch (z = 0:Q, 1:K, 2:V).
// Q,K -> [B,H,S,D] bf16 ; V -> [B,H,D,S] bf16 (transposed for PV B-operand).
__global__ __launch_bounds__(256) void gemm_qkv_k(
    const ushort* __restrict__ xb,
    const ushort* __restrict__ wqb, const ushort* __restrict__ wkb,
    const ushort* __restrict__ wvb,
    ushort* __restrict__ Qb, ushort* __restrict__ Kb, ushort* __restrict__ Vtb) {
  __shared__ ushort lA[4096], lB[4096];
  int z = blockIdx.z;
  const ushort* w = (z == 0) ? wqb : (z == 1) ? wkb : wvb;
  int row0 = blockIdx.x * 128, col0 = blockIdx.y * 128;
  f32x4 acc[4][4] = {};
  gemm_mainloop(xb, w, row0, col0, lA, lB, acc);

  int tid = threadIdx.x, lane = tid & 63, wid = tid >> 6;
  int wr = wid >> 1, wc = wid & 1, lr = lane >> 4, lc = lane & 15;
  ushort* dst = (z == 0) ? Qb : (z == 1) ? Kb : Vtb;
#pragma unroll
  for (int m = 0; m < 4; m++)
#pragma unroll
    for (int n = 0; n < 4; n++)
#pragma unroll
      for (int j = 0; j < 4; j++) {
        int i = row0 + wr * 64 + m * 16 + lr * 4 + j;   // row in [0,4096): b,s
        int c = col0 + wc * 64 + n * 16 + lc;           // col in [0,1024): h,d
        int b = i >> 11, s = i & 2047, h = c >> 6, d = c & 63;
        ushort v = f2b(acc[m][n][j]);
        size_t base = (size_t)(b * 16 + h) * 131072;    // 2048*64 per head
        if (z < 2) dst[base + (size_t)s * 64 + d] = v;
        else       dst[base + (size_t)d * 2048 + s] = v;
      }
}

// Final projection: out(fp32, row-major [4096][1024]) = attn @ Wo^T.
__global__ __launch_bounds__(256) void gemm_out_k(
    const ushort* __restrict__ Ab, const ushort* __restrict__ wob,
    float* __restrict__ out) {
  __shared__ ushort lA[4096], lB[4096];
  int row0 = blockIdx.x * 128, col0 = blockIdx.y * 128;
  f32x4 acc[4][4] = {};
  gemm_mainloop(Ab, wob, row0, col0, lA, lB, acc);

  int tid = threadIdx.x, lane = tid & 63, wid = tid >> 6;
  int wr = wid >> 1, wc = wid & 1, lr = lane >> 4, lc = lane & 15;
#pragma unroll
  for (int m = 0; m < 4; m++)
#pragma unroll
    for (int n = 0; n < 4; n++)
#pragma unroll
      for (int j = 0; j < 4; j++) {
        int i = row0 + wr * 64 + m * 16 + lr * 4 + j;
        int c = col0 + wc * 64 + n * 16 + lc;
        out[(size_t)i * 1024 + c] = acc[m][n][j];
      }
}

// ---------------------------------------------------------------------------
// 3) RoPE in place on Q,K ([B,H,S,D]); thread = (bh, s, d') with d' in [0,32).
//    q'[d'] = q[d']*c - q[d'+32]*s ; q'[d'+32] = q[d'+32]*c + q[d']*s.
// ---------------------------------------------------------------------------
__global__ __launch_bounds__(256) void rope_k(ushort* __restrict__ Qb,
                                              ushort* __restrict__ Kb) {
  int idx = blockIdx.x * 256 + threadIdx.x;   // 32*2048*32 = 2,097,152
  int dp = idx & 31;
  int s  = (idx >> 5) & 2047;
  int bh = idx >> 16;
  // inv_freq = 10000^(-dp/32) ; log2(10000) = 13.287712379549449
  float inv = exp2f((float)dp * (-13.2877123795494f / 32.0f));
  float ang = (float)s * inv;
  float sn, cs;
  sincosf(ang, &sn, &cs);
  size_t off = (size_t)bh * 131072 + (size_t)s * 64 + dp;
  float q1 = b2f(Qb[off]), q2 = b2f(Qb[off + 32]);
  Qb[off]      = f2b(q1 * cs - q2 * sn);
  Qb[off + 32] = f2b(q2 * cs + q1 * sn);
  float k1 = b2f(Kb[off]), k2 = b2f(Kb[off + 32]);
  Kb[off]      = f2b(k1 * cs - k2 * sn);
  Kb[off + 32] = f2b(k2 * cs + k1 * sn);
}

// ---------------------------------------------------------------------------
// 4) Flash attention. Block = 4 waves; wave owns 16 q-rows; KVBLK=32.
//    Scores: A=Q-frag, B=K rows (contig 16B from [B,H,S,D]).
//    Online softmax on C-layout (col=lane&15=key, row=(lane>>4)*4+j).
//    P goes through per-wave LDS to A-operand layout; V read from [B,H,D,S].
// ---------------------------------------------------------------------------
__global__ __launch_bounds__(256) void attn_k(
    const ushort* __restrict__ Qb, const ushort* __restrict__ Kb,
    const ushort* __restrict__ Vtb, ushort* __restrict__ Ob) {
  __shared__ ushort plds[4][16][32];
  int tid = threadIdx.x, lane = tid & 63, wid = tid >> 6;
  int lr = lane >> 4, lc = lane & 15;
  int bh = blockIdx.y;
  int q0 = blockIdx.x * 64 + wid * 16;
  const ushort* Qp = Qb  + (size_t)bh * 131072 + (size_t)q0 * 64;
  const ushort* Kp = Kb  + (size_t)bh * 131072;
  const ushort* Vp = Vtb + (size_t)bh * 131072;

  bf16x8 qf0 = *(const bf16x8*)(Qp + lc * 64 + lr * 8);
  bf16x8 qf1 = *(const bf16x8*)(Qp + lc * 64 + 32 + lr * 8);

  f32x4 o[4] = {};
  float mx[4], ls[4];
#pragma unroll
  for (int j = 0; j < 4; j++) { mx[j] = -1e30f; ls[j] = 0.f; }
  ushort (*pw)[32] = plds[wid];
  const float LOG2E = 1.44269504088896f;

  for (int kv = 0; kv < 2048; kv += 32) {
    bf16x8 kf00 = *(const bf16x8*)(Kp + (size_t)(kv + lc) * 64 + lr * 8);
    bf16x8 kf01 = *(const bf16x8*)(Kp + (size_t)(kv + lc) * 64 + 32 + lr * 8);
    bf16x8 kf10 = *(const bf16x8*)(Kp + (size_t)(kv + 16 + lc) * 64 + lr * 8);
    bf16x8 kf11 = *(const bf16x8*)(Kp + (size_t)(kv + 16 + lc) * 64 + 32 + lr * 8);
    f32x4 s0 = {}, s1 = {};
    s0 = __builtin_amdgcn_mfma_f32_16x16x32_bf16(qf0, kf00, s0, 0, 0, 0);
    s0 = __builtin_amdgcn_mfma_f32_16x16x32_bf16(qf1, kf01, s0, 0, 0, 0);
    s1 = __builtin_amdgcn_mfma_f32_16x16x32_bf16(qf0, kf10, s1, 0, 0, 0);
    s1 = __builtin_amdgcn_mfma_f32_16x16x32_bf16(qf1, kf11, s1, 0, 0, 0);

    float pm[4], al[4], p0[4], p1[4], rs[4];
#pragma unroll
    for (int j = 0; j < 4; j++) {
      s0[j] *= 0.125f; s1[j] *= 0.125f;
      pm[j] = fmaxf(s0[j], s1[j]);
    }
#pragma unroll
    for (int m = 1; m < 16; m <<= 1)
#pragma unroll
      for (int j = 0; j < 4; j++) pm[j] = fmaxf(pm[j], __shfl_xor(pm[j], m));
#pragma unroll
    for (int j = 0; j < 4; j++) {
      float mn = fmaxf(mx[j], pm[j]);
      al[j] = exp2f((mx[j] - mn) * LOG2E);
      mx[j] = mn;
      p0[j] = exp2f((s0[j] - mn) * LOG2E);
      p1[j] = exp2f((s1[j] - mn) * LOG2E);
      rs[j] = p0[j] + p1[j];
    }
#pragma unroll
    for (int m = 1; m < 16; m <<= 1)
#pragma unroll
      for (int j = 0; j < 4; j++) rs[j] += __shfl_xor(rs[j], m);
#pragma unroll
    for (int j = 0; j < 4; j++) ls[j] = ls[j] * al[j] + rs[j];
#pragma unroll
    for (int n = 0; n < 4; n++)
#pragma unroll
      for (int j = 0; j < 4; j++) o[n][j] *= al[j];

    // P (fp32 C-layout) -> LDS -> bf16 A-operand frag
#pragma unroll
    for (int j = 0; j < 4; j++) {
      pw[lr * 4 + j][lc]      = f2b(p0[j]);
      pw[lr * 4 + j][16 + lc] = f2b(p1[j]);
    }
    bf16x8 pf = *(const bf16x8*)(&pw[lc][lr * 8]);
#pragma unroll
    for (int n = 0; n < 4; n++) {
      bf16x8 vf = *(const bf16x8*)(Vp + (size_t)(n * 16 + lc) * 2048 + kv + lr * 8);
      o[n] = __builtin_amdgcn_mfma_f32_16x16x32_bf16(pf, vf, o[n], 0, 0, 0);
    }
  }

  int b = bh >> 4, h = bh & 15;
  ushort* Op = Ob + ((size_t)(b * 2048 + q0)) * 1024 + h * 64;
#pragma unroll
  for (int n = 0; n < 4; n++)
#pragma unroll
    for (int j = 0; j < 4; j++)
      Op[(size_t)(lr * 4 + j) * 1024 + n * 16 + lc] = f2b(o[n][j] / ls[j]);
}

// ---------------------------------------------------------------------------
// Workspace layout (bytes):
//  0      xb   8 MiB   [4096][1024] bf16
//  8 MiB  wqb  2 MiB   then wkb, wvb, wob (2 MiB each)  -> ends 16 MiB
// 16 MiB  Qb   8 MiB   [B,H,S,D]
// 24 MiB  Kb   8 MiB   [B,H,S,D]
// 32 MiB  Vtb  8 MiB   [B,H,D,S]
// 40 MiB  Ob   8 MiB   [4096][1024] bf16 (attention out)   total 48 MiB
// ---------------------------------------------------------------------------
extern "C" void kernel_launch(void* const* d_in, const int* in_sizes, int n_in,
                              void* d_out, int out_size, void* d_ws, size_t ws_size,
                              hipStream_t stream) {
  const float* x  = (const float*)d_in[0];
  const float* wq = (const float*)d_in[1];
  const float* wk = (const float*)d_in[2];
  const float* wv = (const float*)d_in[3];
  const float* wo = (const float*)d_in[4];
  float* out = (float*)d_out;
  char* ws = (char*)d_ws;
  const size_t MiB = 1024 * 1024;
  ushort* xb  = (ushort*)(ws + 0);
  ushort* wqb = (ushort*)(ws + 8 * MiB);
  ushort* wkb = (ushort*)(ws + 10 * MiB);
  ushort* wvb = (ushort*)(ws + 12 * MiB);
  ushort* wob = (ushort*)(ws + 14 * MiB);
  ushort* Qb  = (ushort*)(ws + 16 * MiB);
  ushort* Kb  = (ushort*)(ws + 24 * MiB);
  ushort* Vtb = (ushort*)(ws + 32 * MiB);
  ushort* Ob  = (ushort*)(ws + 40 * MiB);

  cvt_all_k<<<8192, 256, 0, stream>>>(x, wq, wk, wv, wo, xb);
  dim3 gqkv(32, 8, 3);
  gemm_qkv_k<<<gqkv, 256, 0, stream>>>(xb, wqb, wkb, wvb, Qb, Kb, Vtb);
  rope_k<<<8192, 256, 0, stream>>>(Qb, Kb);
  dim3 gat(32, 32);
  attn_k<<<gat, 256, 0, stream>>>(Qb, Kb, Vtb, Ob);
  dim3 gout(32, 8);
  gemm_out_k<<<gout, 256, 0, stream>>>(Ob, wob, out);
}

// Round 2
// 333.987 us; speedup vs baseline: 1.0036x; 1.0036x over previous
//
#include <hip/hip_runtime.h>
#include <hip/hip_bf16.h>
#include <stdint.h>

// ---------------------------------------------------------------------------
// MHA block: out = softmax( rope(xWq^T) rope(xWk^T)^T / 8 ) (xWv^T) Wo^T
// B=2 S=2048 H=16 D=64 DIM=1024.  bf16 MFMA compute, fp32 accum/softmax.
// ---------------------------------------------------------------------------

#define AS1(p) ((const __attribute__((address_space(1))) void*)(p))
#define AS3(p) ((__attribute__((address_space(3))) void*)(p))

typedef __attribute__((ext_vector_type(8))) __bf16 bf16x8;
typedef __attribute__((ext_vector_type(4))) float  f32x4;

__device__ __forceinline__ ushort f2b(float f) {
  union { float f; uint32_t u; } v; v.f = f;
  uint32_t u = v.u;
  u += 0x7fffu + ((u >> 16) & 1);   // RNE
  return (ushort)(u >> 16);
}
__device__ __forceinline__ float b2f(ushort s) {
  union { uint32_t u; float f; } v; v.u = ((uint32_t)s) << 16;
  return v.f;
}

// ---------------------------------------------------------------------------
// 1) fp32 -> bf16 conversion of x and the four weights (contiguous in ws).
// ---------------------------------------------------------------------------
__global__ __launch_bounds__(256) void cvt_all_k(
    const float* __restrict__ x,  const float* __restrict__ wq,
    const float* __restrict__ wk, const float* __restrict__ wv,
    const float* __restrict__ wo, ushort* __restrict__ dst) {
  int i = blockIdx.x * 256 + threadIdx.x;          // 2,097,152 total
  const float* src;
  if      (i < 1048576) src = x  + (size_t)i * 4;
  else if (i < 1310720) src = wq + (size_t)(i - 1048576) * 4;
  else if (i < 1572864) src = wk + (size_t)(i - 1310720) * 4;
  else if (i < 1835008) src = wv + (size_t)(i - 1572864) * 4;
  else                  src = wo + (size_t)(i - 1835008) * 4;
  float4 v = *(const float4*)src;
  ushort4 o;
  o.x = f2b(v.x); o.y = f2b(v.y); o.z = f2b(v.z); o.w = f2b(v.w);
  ((ushort4*)dst)[i] = o;
}

// ---------------------------------------------------------------------------
// 2) GEMM mainloop: C = A(MxK) * W(NxK)^T, 128x128 tile, BK=32, 4 waves (2x2),
//    global_load_lds width=16 staging, m97 2-barrier structure.
// ---------------------------------------------------------------------------
__device__ __forceinline__ void gemm_mainloop(
    const ushort* __restrict__ A, const ushort* __restrict__ W,
    int row0, int col0, ushort* lA, ushort* lB, f32x4 acc[4][4]) {
  const int K = 1024;
  int tid = threadIdx.x;
  int lane = tid & 63, wid = tid >> 6;
  int wr = wid >> 1, wc = wid & 1;
  int lr = lane >> 4, lc = lane & 15;
  for (int k0 = 0; k0 < K; k0 += 32) {
#pragma unroll
    for (int i = 0; i < 2; i++) {
      int idx = tid + i * 256;                       // 16B chunk id, 4 per row
      const ushort* ga = A + (size_t)(row0 + (idx >> 2)) * K + k0 + (idx & 3) * 8;
      __builtin_amdgcn_global_load_lds(AS1(ga), AS3(lA + (i * 256 + wid * 64) * 8), 16, 0, 0);
      const ushort* gb = W + (size_t)(col0 + (idx >> 2)) * K + k0 + (idx & 3) * 8;
      __builtin_amdgcn_global_load_lds(AS1(gb), AS3(lB + (i * 256 + wid * 64) * 8), 16, 0, 0);
    }
    __syncthreads();
    bf16x8 af[4], bfr[4];
#pragma unroll
    for (int m = 0; m < 4; m++)
      af[m] = *(const bf16x8*)(lA + (wr * 64 + m * 16 + lc) * 32 + lr * 8);
#pragma unroll
    for (int n = 0; n < 4; n++)
      bfr[n] = *(const bf16x8*)(lB + (wc * 64 + n * 16 + lc) * 32 + lr * 8);
#pragma unroll
    for (int m = 0; m < 4; m++)
#pragma unroll
      for (int n = 0; n < 4; n++)
        acc[m][n] = __builtin_amdgcn_mfma_f32_16x16x32_bf16(af[m], bfr[n], acc[m][n], 0, 0, 0);
    __syncthreads();
  }
}

// QKV projections in one launch (z = 0:Q, 1:K, 2:V).
__global__ __launch_bounds__(256) void gemm_qkv_k(
    const ushort* __restrict__ xb,
    const ushort* __restrict__ wqb, const ushort* __restrict__ wkb,
    const ushort* __restrict__ wvb,
    ushort* __restrict__ Qb, ushort* __restrict__ Kb, ushort* __restrict__ Vtb) {
  __shared__ ushort lA[4096], lB[4096];
  int z = blockIdx.z;
  const ushort* w = (z == 0) ? wqb : (z == 1) ? wkb : wvb;
  int row0 = blockIdx.x * 128, col0 = blockIdx.y * 128;
  f32x4 acc[4][4] = {};
  gemm_mainloop(xb, w, row0, col0, lA, lB, acc);

  int tid = threadIdx.x, lane = tid & 63, wid = tid >> 6;
  int wr = wid >> 1, wc = wid & 1, lr = lane >> 4, lc = lane & 15;
  ushort* dst = (z == 0) ? Qb : (z == 1) ? Kb : Vtb;
#pragma unroll
  for (int m = 0; m < 4; m++)
#pragma unroll
    for (int n = 0; n < 4; n++)
#pragma unroll
      for (int j = 0; j < 4; j++) {
        int i = row0 + wr * 64 + m * 16 + lr * 4 + j;   // row: b,s
        int c = col0 + wc * 64 + n * 16 + lc;           // col: h,d
        int b = i >> 11, s = i & 2047, h = c >> 6, d = c & 63;
        ushort v = f2b(acc[m][n][j]);
        size_t base = (size_t)(b * 16 + h) * 131072;
        if (z < 2) dst[base + (size_t)s * 64 + d] = v;
        else       dst[base + (size_t)d * 2048 + s] = v;
      }
}

// Final projection: out(fp32) = attn @ Wo^T.
__global__ __launch_bounds__(256) void gemm_out_k(
    const ushort* __restrict__ Ab, const ushort* __restrict__ wob,
    float* __restrict__ out) {
  __shared__ ushort lA[4096], lB[4096];
  int row0 = blockIdx.x * 128, col0 = blockIdx.y * 128;
  f32x4 acc[4][4] = {};
  gemm_mainloop(Ab, wob, row0, col0, lA, lB, acc);

  int tid = threadIdx.x, lane = tid & 63, wid = tid >> 6;
  int wr = wid >> 1, wc = wid & 1, lr = lane >> 4, lc = lane & 15;
#pragma unroll
  for (int m = 0; m < 4; m++)
#pragma unroll
    for (int n = 0; n < 4; n++)
#pragma unroll
      for (int j = 0; j < 4; j++) {
        int i = row0 + wr * 64 + m * 16 + lr * 4 + j;
        int c = col0 + wc * 64 + n * 16 + lc;
        out[(size_t)i * 1024 + c] = acc[m][n][j];
      }
}

// ---------------------------------------------------------------------------
// 3) RoPE in place on Q,K.  Q additionally folded-scaled by 0.125*log2(e)
//    so attention scores are natively in exp2 domain.
// ---------------------------------------------------------------------------
__global__ __launch_bounds__(256) void rope_k(ushort* __restrict__ Qb,
                                              ushort* __restrict__ Kb) {
  const float QSCL = 0.125f * 1.44269504088896f;
  int idx = blockIdx.x * 256 + threadIdx.x;   // 32*2048*32 = 2,097,152
  int dp = idx & 31;
  int s  = (idx >> 5) & 2047;
  int bh = idx >> 16;
  float inv = exp2f((float)dp * (-13.2877123795494f / 32.0f));
  float ang = (float)s * inv;
  float sn, cs;
  sincosf(ang, &sn, &cs);
  size_t off = (size_t)bh * 131072 + (size_t)s * 64 + dp;
  float q1 = b2f(Qb[off]), q2 = b2f(Qb[off + 32]);
  Qb[off]      = f2b((q1 * cs - q2 * sn) * QSCL);
  Qb[off + 32] = f2b((q2 * cs + q1 * sn) * QSCL);
  float k1 = b2f(Kb[off]), k2 = b2f(Kb[off + 32]);
  Kb[off]      = f2b(k1 * cs - k2 * sn);
  Kb[off + 32] = f2b(k2 * cs + k1 * sn);
}

// ---------------------------------------------------------------------------
// 4) Flash attention. Block = 4 waves; wave owns 16 q-rows; KVBLK=64.
//    Scores in exp2 domain (scale folded into Q). Online softmax with:
//      - per-lane partial row-sums (single reduce tree after the loop)
//      - defer-rescale (skip o/ls rescale while max doesn't grow; THR=8)
//      - cvt_pk bf16 packing of P; XOR-swizzled P tile in LDS
//      - K software-pipelined one KV-step ahead; V issued before softmax
// ---------------------------------------------------------------------------
__global__ __launch_bounds__(256) void attn_k(
    const ushort* __restrict__ Qb, const ushort* __restrict__ Kb,
    const ushort* __restrict__ Vtb, ushort* __restrict__ Ob) {
  __shared__ ushort plds[4][16][64];   // per-wave P tile, XOR-swizzled rows
  int tid = threadIdx.x, lane = tid & 63, wid = tid >> 6;
  int lr = lane >> 4, lc = lane & 15;
  int bh = blockIdx.y;
  int q0 = blockIdx.x * 64 + wid * 16;
  const ushort* Qp = Qb  + (size_t)bh * 131072 + (size_t)q0 * 64;
  const ushort* Kp = Kb  + (size_t)bh * 131072;
  const ushort* Vp = Vtb + (size_t)bh * 131072;
  char* pbase = (char*)&plds[wid][0][0];

  bf16x8 qf0 = *(const bf16x8*)(Qp + lc * 64 + lr * 8);
  bf16x8 qf1 = *(const bf16x8*)(Qp + lc * 64 + 32 + lr * 8);

  f32x4 o[4] = {};
  float mx[4], lsum[4];
#pragma unroll
  for (int j = 0; j < 4; j++) { mx[j] = -1e30f; lsum[j] = 0.f; }

  // preload K fragments for kv=0
  bf16x8 kf[4][2];
#pragma unroll
  for (int g = 0; g < 4; g++)
#pragma unroll
    for (int h = 0; h < 2; h++)
      kf[g][h] = *(const bf16x8*)(Kp + (size_t)(g * 16 + lc) * 64 + h * 32 + lr * 8);

  for (int kv = 0; kv < 2048; kv += 64) {
    // QK^T for 64 keys (scores already in exp2 domain)
    f32x4 s[4];
#pragma unroll
    for (int g = 0; g < 4; g++) {
      f32x4 z = {0.f, 0.f, 0.f, 0.f};
      s[g] = __builtin_amdgcn_mfma_f32_16x16x32_bf16(qf0, kf[g][0], z, 0, 0, 0);
      s[g] = __builtin_amdgcn_mfma_f32_16x16x32_bf16(qf1, kf[g][1], s[g], 0, 0, 0);
    }
    // prefetch next-step K into the same regs (latency hidden by softmax+PV)
    int kvn = (kv + 64) & 2047;
#pragma unroll
    for (int g = 0; g < 4; g++)
#pragma unroll
      for (int h = 0; h < 2; h++)
        kf[g][h] = *(const bf16x8*)(Kp + (size_t)(kvn + g * 16 + lc) * 64 + h * 32 + lr * 8);
    // V fragments for this step (consumed after softmax)
    bf16x8 vf[4][2];
#pragma unroll
    for (int n = 0; n < 4; n++)
#pragma unroll
      for (int c = 0; c < 2; c++)
        vf[n][c] = *(const bf16x8*)(Vp + (size_t)(n * 16 + lc) * 2048 + kv + c * 32 + lr * 8);

    // row max (only remaining shuffle tree)
    float pm[4];
#pragma unroll
    for (int j = 0; j < 4; j++)
      pm[j] = fmaxf(fmaxf(s[0][j], s[1][j]), fmaxf(s[2][j], s[3][j]));
#pragma unroll
    for (int m = 1; m < 16; m <<= 1)
#pragma unroll
      for (int j = 0; j < 4; j++) pm[j] = fmaxf(pm[j], __shfl_xor(pm[j], m));

    // defer-rescale: only rescale when some row max grew beyond THR=8 (log2)
    int ok = (pm[0] <= mx[0] + 8.f) & (pm[1] <= mx[1] + 8.f) &
             (pm[2] <= mx[2] + 8.f) & (pm[3] <= mx[3] + 8.f);
    if (!__all(ok)) {
#pragma unroll
      for (int j = 0; j < 4; j++) {
        float mn = fmaxf(mx[j], pm[j]);
        float al = exp2f(mx[j] - mn);
        mx[j] = mn;
        lsum[j] *= al;
#pragma unroll
        for (int n = 0; n < 4; n++) o[n][j] *= al;
      }
    }
    // P = exp2(s - mx); per-lane partial sums (no per-step reduce)
#pragma unroll
    for (int g = 0; g < 4; g++)
#pragma unroll
      for (int j = 0; j < 4; j++) s[g][j] = exp2f(s[g][j] - mx[j]);
#pragma unroll
    for (int j = 0; j < 4; j++)
      lsum[j] += (s[0][j] + s[1][j]) + (s[2][j] + s[3][j]);

    // pack P -> LDS (bf16, XOR-swizzled: byte ^= (row&7)<<4)
#pragma unroll
    for (int g = 0; g < 4; g++)
#pragma unroll
      for (int jp = 0; jp < 2; jp++) {
        uint32_t w;
        asm("v_cvt_pk_bf16_f32 %0, %1, %2"
            : "=v"(w) : "v"(s[g][2 * jp]), "v"(s[g][2 * jp + 1]));
        int r0 = lr * 4 + 2 * jp, r1 = r0 + 1;
        int kb = (g * 16 + lc) * 2;
        *(ushort*)(pbase + r0 * 128 + (kb ^ ((r0 & 7) << 4))) = (ushort)w;
        *(ushort*)(pbase + r1 * 128 + (kb ^ ((r1 & 7) << 4))) = (ushort)(w >> 16);
      }
    bf16x8 pf0 = *(const bf16x8*)(pbase + lc * 128 + ((lr * 16) ^ ((lc & 7) << 4)));
    bf16x8 pf1 = *(const bf16x8*)(pbase + lc * 128 + ((64 + lr * 16) ^ ((lc & 7) << 4)));
#pragma unroll
    for (int n = 0; n < 4; n++) {
      o[n] = __builtin_amdgcn_mfma_f32_16x16x32_bf16(pf0, vf[n][0], o[n], 0, 0, 0);
      o[n] = __builtin_amdgcn_mfma_f32_16x16x32_bf16(pf1, vf[n][1], o[n], 0, 0, 0);
    }
  }

  // single row-sum reduce
#pragma unroll
  for (int m = 1; m < 16; m <<= 1)
#pragma unroll
    for (int j = 0; j < 4; j++) lsum[j] += __shfl_xor(lsum[j], m);
  float inv[4];
#pragma unroll
  for (int j = 0; j < 4; j++) inv[j] = 1.0f / lsum[j];

  int b = bh >> 4, h = bh & 15;
  ushort* Op = Ob + ((size_t)(b * 2048 + q0)) * 1024 + h * 64;
#pragma unroll
  for (int n = 0; n < 4; n++)
#pragma unroll
    for (int j = 0; j < 4; j++)
      Op[(size_t)(lr * 4 + j) * 1024 + n * 16 + lc] = f2b(o[n][j] * inv[j]);
}

// ---------------------------------------------------------------------------
// Workspace layout: xb 8M | wqb/wkb/wvb/wob 2M each | Qb 8M | Kb 8M | Vtb 8M
// | Ob 8M  (total 48 MiB)
// ---------------------------------------------------------------------------
extern "C" void kernel_launch(void* const* d_in, const int* in_sizes, int n_in,
                              void* d_out, int out_size, void* d_ws, size_t ws_size,
                              hipStream_t stream) {
  const float* x  = (const float*)d_in[0];
  const float* wq = (const float*)d_in[1];
  const float* wk = (const float*)d_in[2];
  const float* wv = (const float*)d_in[3];
  const float* wo = (const float*)d_in[4];
  float* out = (float*)d_out;
  char* ws = (char*)d_ws;
  const size_t MiB = 1024 * 1024;
  ushort* xb  = (ushort*)(ws + 0);
  ushort* wqb = (ushort*)(ws + 8 * MiB);
  ushort* wkb = (ushort*)(ws + 10 * MiB);
  ushort* wvb = (ushort*)(ws + 12 * MiB);
  ushort* wob = (ushort*)(ws + 14 * MiB);
  ushort* Qb  = (ushort*)(ws + 16 * MiB);
  ushort* Kb  = (ushort*)(ws + 24 * MiB);
  ushort* Vtb = (ushort*)(ws + 32 * MiB);
  ushort* Ob  = (ushort*)(ws + 40 * MiB);

  cvt_all_k<<<8192, 256, 0, stream>>>(x, wq, wk, wv, wo, xb);
  dim3 gqkv(32, 8, 3);
  gemm_qkv_k<<<gqkv, 256, 0, stream>>>(xb, wqb, wkb, wvb, Qb, Kb, Vtb);
  rope_k<<<8192, 256, 0, stream>>>(Qb, Kb);
  dim3 gat(32, 32);
  attn_k<<<gat, 256, 0, stream>>>(Qb, Kb, Vtb, Ob);
  dim3 gout(32, 8);
  gemm_out_k<<<gout, 256, 0, stream>>>(Ob, wob, out);
}

// Round 5
// 189.207 us; speedup vs baseline: 1.7716x; 1.7652x over previous
//
#include <hip/hip_runtime.h>
#include <hip/hip_bf16.h>
#include <stdint.h>

// ---------------------------------------------------------------------------
// MHA block: out = softmax( rope(xWq^T) rope(xWk^T)^T / 8 ) (xWv^T) Wo^T
// B=2 S=2048 H=16 D=64 DIM=1024.  bf16 MFMA compute, fp32 accum/softmax.
// ---------------------------------------------------------------------------

#define AS1(p) ((const __attribute__((address_space(1))) void*)(p))
#define AS3(p) ((__attribute__((address_space(3))) void*)(p))

typedef __attribute__((ext_vector_type(8))) __bf16 bf16x8;
typedef __attribute__((ext_vector_type(4))) float  f32x4;

__device__ __forceinline__ ushort f2b(float f) {
  union { float f; uint32_t u; } v; v.f = f;
  uint32_t u = v.u;
  u += 0x7fffu + ((u >> 16) & 1);   // RNE
  return (ushort)(u >> 16);
}
__device__ __forceinline__ float b2f(ushort s) {
  union { uint32_t u; float f; } v; v.u = ((uint32_t)s) << 16;
  return v.f;
}

// ---------------------------------------------------------------------------
// 1) fp32 -> bf16 conversion of x and the four weights (contiguous in ws).
// ---------------------------------------------------------------------------
__global__ __launch_bounds__(256) void cvt_all_k(
    const float* __restrict__ x,  const float* __restrict__ wq,
    const float* __restrict__ wk, const float* __restrict__ wv,
    const float* __restrict__ wo, ushort* __restrict__ dst) {
  int i = blockIdx.x * 256 + threadIdx.x;          // 2,097,152 total
  const float* src;
  if      (i < 1048576) src = x  + (size_t)i * 4;
  else if (i < 1310720) src = wq + (size_t)(i - 1048576) * 4;
  else if (i < 1572864) src = wk + (size_t)(i - 1310720) * 4;
  else if (i < 1835008) src = wv + (size_t)(i - 1572864) * 4;
  else                  src = wo + (size_t)(i - 1835008) * 4;
  float4 v = *(const float4*)src;
  ushort4 o;
  o.x = f2b(v.x); o.y = f2b(v.y); o.z = f2b(v.z); o.w = f2b(v.w);
  ((ushort4*)dst)[i] = o;
}

// ---------------------------------------------------------------------------
// 2) GEMM mainloop: C = A(MxK) * W(NxK)^T, 128x128 tile, BK=32, 4 waves (2x2),
//    global_load_lds width=16 staging, m97 2-barrier structure.
// ---------------------------------------------------------------------------
__device__ __forceinline__ void gemm_mainloop(
    const ushort* __restrict__ A, const ushort* __restrict__ W,
    int row0, int col0, ushort* lA, ushort* lB, f32x4 acc[4][4]) {
  const int K = 1024;
  int tid = threadIdx.x;
  int lane = tid & 63, wid = tid >> 6;
  int wr = wid >> 1, wc = wid & 1;
  int lr = lane >> 4, lc = lane & 15;
  for (int k0 = 0; k0 < K; k0 += 32) {
#pragma unroll
    for (int i = 0; i < 2; i++) {
      int idx = tid + i * 256;                       // 16B chunk id, 4 per row
      const ushort* ga = A + (size_t)(row0 + (idx >> 2)) * K + k0 + (idx & 3) * 8;
      __builtin_amdgcn_global_load_lds(AS1(ga), AS3(lA + (i * 256 + wid * 64) * 8), 16, 0, 0);
      const ushort* gb = W + (size_t)(col0 + (idx >> 2)) * K + k0 + (idx & 3) * 8;
      __builtin_amdgcn_global_load_lds(AS1(gb), AS3(lB + (i * 256 + wid * 64) * 8), 16, 0, 0);
    }
    __syncthreads();
    bf16x8 af[4], bfr[4];
#pragma unroll
    for (int m = 0; m < 4; m++)
      af[m] = *(const bf16x8*)(lA + (wr * 64 + m * 16 + lc) * 32 + lr * 8);
#pragma unroll
    for (int n = 0; n < 4; n++)
      bfr[n] = *(const bf16x8*)(lB + (wc * 64 + n * 16 + lc) * 32 + lr * 8);
#pragma unroll
    for (int m = 0; m < 4; m++)
#pragma unroll
      for (int n = 0; n < 4; n++)
        acc[m][n] = __builtin_amdgcn_mfma_f32_16x16x32_bf16(af[m], bfr[n], acc[m][n], 0, 0, 0);
    __syncthreads();
  }
}

// QKV projections in one launch (z = 0:Q, 1:K, 2:V).
__global__ __launch_bounds__(256) void gemm_qkv_k(
    const ushort* __restrict__ xb,
    const ushort* __restrict__ wqb, const ushort* __restrict__ wkb,
    const ushort* __restrict__ wvb,
    ushort* __restrict__ Qb, ushort* __restrict__ Kb, ushort* __restrict__ Vtb) {
  __shared__ ushort lA[4096], lB[4096];
  int z = blockIdx.z;
  const ushort* w = (z == 0) ? wqb : (z == 1) ? wkb : wvb;
  int row0 = blockIdx.x * 128, col0 = blockIdx.y * 128;
  f32x4 acc[4][4] = {};
  gemm_mainloop(xb, w, row0, col0, lA, lB, acc);

  int tid = threadIdx.x, lane = tid & 63, wid = tid >> 6;
  int wr = wid >> 1, wc = wid & 1, lr = lane >> 4, lc = lane & 15;
  ushort* dst = (z == 0) ? Qb : (z == 1) ? Kb : Vtb;
#pragma unroll
  for (int m = 0; m < 4; m++)
#pragma unroll
    for (int n = 0; n < 4; n++)
#pragma unroll
      for (int j = 0; j < 4; j++) {
        int i = row0 + wr * 64 + m * 16 + lr * 4 + j;   // row: b,s
        int c = col0 + wc * 64 + n * 16 + lc;           // col: h,d
        int b = i >> 11, s = i & 2047, h = c >> 6, d = c & 63;
        ushort v = f2b(acc[m][n][j]);
        size_t base = (size_t)(b * 16 + h) * 131072;
        if (z < 2) dst[base + (size_t)s * 64 + d] = v;
        else       dst[base + (size_t)d * 2048 + s] = v;
      }
}

// Final projection: out(fp32) = attn @ Wo^T.
__global__ __launch_bounds__(256) void gemm_out_k(
    const ushort* __restrict__ Ab, const ushort* __restrict__ wob,
    float* __restrict__ out) {
  __shared__ ushort lA[4096], lB[4096];
  int row0 = blockIdx.x * 128, col0 = blockIdx.y * 128;
  f32x4 acc[4][4] = {};
  gemm_mainloop(Ab, wob, row0, col0, lA, lB, acc);

  int tid = threadIdx.x, lane = tid & 63, wid = tid >> 6;
  int wr = wid >> 1, wc = wid & 1, lr = lane >> 4, lc = lane & 15;
#pragma unroll
  for (int m = 0; m < 4; m++)
#pragma unroll
    for (int n = 0; n < 4; n++)
#pragma unroll
      for (int j = 0; j < 4; j++) {
        int i = row0 + wr * 64 + m * 16 + lr * 4 + j;
        int c = col0 + wc * 64 + n * 16 + lc;
        out[(size_t)i * 1024 + c] = acc[m][n][j];
      }
}

// ---------------------------------------------------------------------------
// 3) RoPE in place on Q,K.  Q additionally folded-scaled by 0.125*log2(e)
//    so attention scores are natively in exp2 domain.
// ---------------------------------------------------------------------------
__global__ __launch_bounds__(256) void rope_k(ushort* __restrict__ Qb,
                                              ushort* __restrict__ Kb) {
  const float QSCL = 0.125f * 1.44269504088896f;
  int idx = blockIdx.x * 256 + threadIdx.x;   // 32*2048*32 = 2,097,152
  int dp = idx & 31;
  int s  = (idx >> 5) & 2047;
  int bh = idx >> 16;
  float inv = exp2f((float)dp * (-13.2877123795494f / 32.0f));
  float ang = (float)s * inv;
  float sn, cs;
  sincosf(ang, &sn, &cs);
  size_t off = (size_t)bh * 131072 + (size_t)s * 64 + dp;
  float q1 = b2f(Qb[off]), q2 = b2f(Qb[off + 32]);
  Qb[off]      = f2b((q1 * cs - q2 * sn) * QSCL);
  Qb[off + 32] = f2b((q2 * cs + q1 * sn) * QSCL);
  float k1 = b2f(Kb[off]), k2 = b2f(Kb[off + 32]);
  Kb[off]      = f2b(k1 * cs - k2 * sn);
  Kb[off + 32] = f2b(k2 * cs + k1 * sn);
}

// ---------------------------------------------------------------------------
// 4) Flash attention.  512 threads = 8 waves/block, wave owns 16 q-rows
//    (QBLK=128), KVBLK=64.  K,V staged block-wide in LDS (double-buffered,
//    global_load_lds w16, one 16B chunk per thread).  LDS dest is the
//    WAVE-UNIFORM base wid*1024 (HW appends lane*16); swizzle achieved by
//    pre-swizzling the per-lane GLOBAL source (m173 / rule #21).
//    Grid swizzled so a head's 512KB K/V stays on one XCD's L2.
//    Online softmax in exp2 domain, defer-rescale THR=8, cvt_pk P-packing.
// ---------------------------------------------------------------------------
__global__ __launch_bounds__(512, 4) void attn_k(
    const ushort* __restrict__ Qb, const ushort* __restrict__ Kb,
    const ushort* __restrict__ Vtb, ushort* __restrict__ Ob) {
  __shared__ ushort kvlds[2][2][4096];   // [buf][0=K,1=V][64 rows * 64], 32 KiB
  __shared__ ushort plds[8][16][64];     // per-wave P tile, 16 KiB
  int tid = threadIdx.x, lane = tid & 63, wid = tid >> 6;   // wid in [0,8)
  int lr = lane >> 4, lc = lane & 15;

  // XCD swizzle: bh = (bid&7) + 8*(bid>>7)  -> all q-tiles of a head on 1 XCD
  int bid = blockIdx.x;
  int qt = (bid >> 3) & 15;
  int bh = (bid & 7) + ((bid >> 7) << 3);
  int q0 = qt * 128 + wid * 16;
  const ushort* Qp = Qb  + (size_t)bh * 131072 + (size_t)q0 * 64;
  const ushort* Kp = Kb  + (size_t)bh * 131072;
  const ushort* Vp = Vtb + (size_t)bh * 131072;
  char* pbase = (char*)&plds[wid][0][0];

  bf16x8 qf0 = *(const bf16x8*)(Qp + lc * 64 + lr * 8);
  bf16x8 qf1 = *(const bf16x8*)(Qp + lc * 64 + 32 + lr * 8);

  f32x4 o[4] = {};
  float mx[4], lsum[4];
#pragma unroll
  for (int j = 0; j < 4; j++) { mx[j] = -1e30f; lsum[j] = 0.f; }

  // stage K,V tile [kv, kv+64) into buf. 512 threads x one 16B chunk each.
  // Lane's chunk id = tid; r = tid>>3 (row), cp = tid&7 (chunk in row).
  // LDS dest = wave-uniform wid*1024 bytes; HW appends lane*16 -> chunk
  // lands at tid*16 (linear). Global source pre-swizzled (chunk cp^(r&7))
  // so XOR-swizzled reads see logical data (involution both sides).
  auto stage = [&](int buf, int kv) {
    int r = tid >> 3, cp = tid & 7;
    int ubase = wid * 1024;                 // wave-uniform byte base
    const ushort* gk = Kp + (size_t)(kv + r) * 64 + ((cp ^ (r & 7)) << 3);
    __builtin_amdgcn_global_load_lds(AS1(gk),
        AS3((char*)&kvlds[buf][0][0] + ubase), 16, 0, 0);
    const ushort* gv = Vp + (size_t)r * 2048 + kv + ((cp ^ (r & 7)) << 3);
    __builtin_amdgcn_global_load_lds(AS1(gv),
        AS3((char*)&kvlds[buf][1][0] + ubase), 16, 0, 0);
  };

  stage(0, 0);
  __syncthreads();
  int cur = 0;

  for (int kv = 0; kv < 2048; kv += 64) {
    if (kv + 64 < 2048) stage(cur ^ 1, kv + 64);
    const char* kbuf = (const char*)&kvlds[cur][0][0];
    const char* vbuf = (const char*)&kvlds[cur][1][0];

    // K fragments from LDS (swizzled), QK^T for 64 keys
    f32x4 s[4];
#pragma unroll
    for (int g = 0; g < 4; g++) {
      int r = g * 16 + lc;
      bf16x8 k0 = *(const bf16x8*)(kbuf + r * 128 + ((lr * 16) ^ ((r & 7) << 4)));
      bf16x8 k1 = *(const bf16x8*)(kbuf + r * 128 + ((64 + lr * 16) ^ ((r & 7) << 4)));
      f32x4 z = {0.f, 0.f, 0.f, 0.f};
      s[g] = __builtin_amdgcn_mfma_f32_16x16x32_bf16(qf0, k0, z, 0, 0, 0);
      s[g] = __builtin_amdgcn_mfma_f32_16x16x32_bf16(qf1, k1, s[g], 0, 0, 0);
    }

    // row max (16-lane tree)
    float pm[4];
#pragma unroll
    for (int j = 0; j < 4; j++)
      pm[j] = fmaxf(fmaxf(s[0][j], s[1][j]), fmaxf(s[2][j], s[3][j]));
#pragma unroll
    for (int m = 1; m < 16; m <<= 1)
#pragma unroll
      for (int j = 0; j < 4; j++) pm[j] = fmaxf(pm[j], __shfl_xor(pm[j], m));

    // defer-rescale (THR=8 in log2 units)
    int ok = (pm[0] <= mx[0] + 8.f) & (pm[1] <= mx[1] + 8.f) &
             (pm[2] <= mx[2] + 8.f) & (pm[3] <= mx[3] + 8.f);
    if (!__all(ok)) {
#pragma unroll
      for (int j = 0; j < 4; j++) {
        float mn = fmaxf(mx[j], pm[j]);
        float al = exp2f(mx[j] - mn);
        mx[j] = mn;
        lsum[j] *= al;
#pragma unroll
        for (int n = 0; n < 4; n++) o[n][j] *= al;
      }
    }
    // P = exp2(s - mx); per-lane partial sums
#pragma unroll
    for (int g = 0; g < 4; g++)
#pragma unroll
      for (int j = 0; j < 4; j++) s[g][j] = exp2f(s[g][j] - mx[j]);
#pragma unroll
    for (int j = 0; j < 4; j++)
      lsum[j] += (s[0][j] + s[1][j]) + (s[2][j] + s[3][j]);

    // pack P -> LDS (bf16, XOR-swizzled rows)
#pragma unroll
    for (int g = 0; g < 4; g++)
#pragma unroll
      for (int jp = 0; jp < 2; jp++) {
        uint32_t w;
        asm("v_cvt_pk_bf16_f32 %0, %1, %2"
            : "=v"(w) : "v"(s[g][2 * jp]), "v"(s[g][2 * jp + 1]));
        int r0 = lr * 4 + 2 * jp, r1 = r0 + 1;
        int kb = (g * 16 + lc) * 2;
        *(ushort*)(pbase + r0 * 128 + (kb ^ ((r0 & 7) << 4))) = (ushort)w;
        *(ushort*)(pbase + r1 * 128 + (kb ^ ((r1 & 7) << 4))) = (ushort)(w >> 16);
      }
    bf16x8 pf0 = *(const bf16x8*)(pbase + lc * 128 + ((lr * 16) ^ ((lc & 7) << 4)));
    bf16x8 pf1 = *(const bf16x8*)(pbase + lc * 128 + ((64 + lr * 16) ^ ((lc & 7) << 4)));

    // PV: V fragments straight from LDS at use
#pragma unroll
    for (int n = 0; n < 4; n++) {
      int d = n * 16 + lc;
      bf16x8 v0 = *(const bf16x8*)(vbuf + d * 128 + ((lr * 16) ^ ((d & 7) << 4)));
      bf16x8 v1 = *(const bf16x8*)(vbuf + d * 128 + ((64 + lr * 16) ^ ((d & 7) << 4)));
      o[n] = __builtin_amdgcn_mfma_f32_16x16x32_bf16(pf0, v0, o[n], 0, 0, 0);
      o[n] = __builtin_amdgcn_mfma_f32_16x16x32_bf16(pf1, v1, o[n], 0, 0, 0);
    }
    __syncthreads();
    cur ^= 1;
  }

  // single row-sum reduce
#pragma unroll
  for (int m = 1; m < 16; m <<= 1)
#pragma unroll
    for (int j = 0; j < 4; j++) lsum[j] += __shfl_xor(lsum[j], m);
  float inv[4];
#pragma unroll
  for (int j = 0; j < 4; j++) inv[j] = 1.0f / lsum[j];

  int b = bh >> 4, h = bh & 15;
  ushort* Op = Ob + ((size_t)(b * 2048 + q0)) * 1024 + h * 64;
#pragma unroll
  for (int n = 0; n < 4; n++)
#pragma unroll
    for (int j = 0; j < 4; j++)
      Op[(size_t)(lr * 4 + j) * 1024 + n * 16 + lc] = f2b(o[n][j] * inv[j]);
}

// ---------------------------------------------------------------------------
// Workspace layout: xb 8M | wqb/wkb/wvb/wob 2M each | Qb 8M | Kb 8M | Vtb 8M
// | Ob 8M  (total 48 MiB)
// ---------------------------------------------------------------------------
extern "C" void kernel_launch(void* const* d_in, const int* in_sizes, int n_in,
                              void* d_out, int out_size, void* d_ws, size_t ws_size,
                              hipStream_t stream) {
  const float* x  = (const float*)d_in[0];
  const float* wq = (const float*)d_in[1];
  const float* wk = (const float*)d_in[2];
  const float* wv = (const float*)d_in[3];
  const float* wo = (const float*)d_in[4];
  float* out = (float*)d_out;
  char* ws = (char*)d_ws;
  const size_t MiB = 1024 * 1024;
  ushort* xb  = (ushort*)(ws + 0);
  ushort* wqb = (ushort*)(ws + 8 * MiB);
  ushort* wkb = (ushort*)(ws + 10 * MiB);
  ushort* wvb = (ushort*)(ws + 12 * MiB);
  ushort* wob = (ushort*)(ws + 14 * MiB);
  ushort* Qb  = (ushort*)(ws + 16 * MiB);
  ushort* Kb  = (ushort*)(ws + 24 * MiB);
  ushort* Vtb = (ushort*)(ws + 32 * MiB);
  ushort* Ob  = (ushort*)(ws + 40 * MiB);

  cvt_all_k<<<8192, 256, 0, stream>>>(x, wq, wk, wv, wo, xb);
  dim3 gqkv(32, 8, 3);
  gemm_qkv_k<<<gqkv, 256, 0, stream>>>(xb, wqb, wkb, wvb, Qb, Kb, Vtb);
  rope_k<<<8192, 256, 0, stream>>>(Qb, Kb);
  attn_k<<<512, 512, 0, stream>>>(Qb, Kb, Vtb, Ob);
  dim3 gout(32, 8);
  gemm_out_k<<<gout, 256, 0, stream>>>(Ob, wob, out);
}

// Round 7
// 163.871 us; speedup vs baseline: 2.0455x; 1.1546x over previous
//
#include <hip/hip_runtime.h>
#include <hip/hip_bf16.h>
#include <stdint.h>

// ---------------------------------------------------------------------------
// MHA block: out = softmax( rope(xWq^T) rope(xWk^T)^T / 8 ) (xWv^T) Wo^T
// B=2 S=2048 H=16 D=64 DIM=1024.  bf16 MFMA compute, fp32 accum/softmax.
// ---------------------------------------------------------------------------

#define AS1(p) ((const __attribute__((address_space(1))) void*)(p))
#define AS3(p) ((__attribute__((address_space(3))) void*)(p))

typedef __attribute__((ext_vector_type(8))) __bf16 bf16x8;
typedef __attribute__((ext_vector_type(4))) float  f32x4;

__device__ __forceinline__ ushort f2b(float f) {
  union { float f; uint32_t u; } v; v.f = f;
  uint32_t u = v.u;
  u += 0x7fffu + ((u >> 16) & 1);   // RNE
  return (ushort)(u >> 16);
}
__device__ __forceinline__ float b2f(ushort s) {
  union { uint32_t u; float f; } v; v.u = ((uint32_t)s) << 16;
  return v.f;
}

// ---------------------------------------------------------------------------
// 1) fp32 -> bf16 conversion of x and the four weights (contiguous in ws).
// ---------------------------------------------------------------------------
__global__ __launch_bounds__(256) void cvt_all_k(
    const float* __restrict__ x,  const float* __restrict__ wq,
    const float* __restrict__ wk, const float* __restrict__ wv,
    const float* __restrict__ wo, ushort* __restrict__ dst) {
  int i = blockIdx.x * 256 + threadIdx.x;          // 2,097,152 total
  const float* src;
  if      (i < 1048576) src = x  + (size_t)i * 4;
  else if (i < 1310720) src = wq + (size_t)(i - 1048576) * 4;
  else if (i < 1572864) src = wk + (size_t)(i - 1310720) * 4;
  else if (i < 1835008) src = wv + (size_t)(i - 1572864) * 4;
  else                  src = wo + (size_t)(i - 1835008) * 4;
  float4 v = *(const float4*)src;
  ushort4 o;
  o.x = f2b(v.x); o.y = f2b(v.y); o.z = f2b(v.z); o.w = f2b(v.w);
  ((ushort4*)dst)[i] = o;
}

// ---------------------------------------------------------------------------
// 2) GEMM mainloop: C = A(MxK) * W(NxK)^T, 128x128 tile, BK=32, 4 waves (2x2),
//    global_load_lds width=16 staging, m97 2-barrier structure.
// ---------------------------------------------------------------------------
__device__ __forceinline__ void gemm_mainloop(
    const ushort* __restrict__ A, const ushort* __restrict__ W,
    int row0, int col0, ushort* lA, ushort* lB, f32x4 acc[4][4]) {
  const int K = 1024;
  int tid = threadIdx.x;
  int lane = tid & 63, wid = tid >> 6;
  int wr = wid >> 1, wc = wid & 1;
  int lr = lane >> 4, lc = lane & 15;
  for (int k0 = 0; k0 < K; k0 += 32) {
#pragma unroll
    for (int i = 0; i < 2; i++) {
      int idx = tid + i * 256;                       // 16B chunk id, 4 per row
      const ushort* ga = A + (size_t)(row0 + (idx >> 2)) * K + k0 + (idx & 3) * 8;
      __builtin_amdgcn_global_load_lds(AS1(ga), AS3(lA + (i * 256 + wid * 64) * 8), 16, 0, 0);
      const ushort* gb = W + (size_t)(col0 + (idx >> 2)) * K + k0 + (idx & 3) * 8;
      __builtin_amdgcn_global_load_lds(AS1(gb), AS3(lB + (i * 256 + wid * 64) * 8), 16, 0, 0);
    }
    __syncthreads();
    bf16x8 af[4], bfr[4];
#pragma unroll
    for (int m = 0; m < 4; m++)
      af[m] = *(const bf16x8*)(lA + (wr * 64 + m * 16 + lc) * 32 + lr * 8);
#pragma unroll
    for (int n = 0; n < 4; n++)
      bfr[n] = *(const bf16x8*)(lB + (wc * 64 + n * 16 + lc) * 32 + lr * 8);
#pragma unroll
    for (int m = 0; m < 4; m++)
#pragma unroll
      for (int n = 0; n < 4; n++)
        acc[m][n] = __builtin_amdgcn_mfma_f32_16x16x32_bf16(af[m], bfr[n], acc[m][n], 0, 0, 0);
    __syncthreads();
  }
}

// QKV projections in one launch (z = 0:Q, 1:K, 2:V).
__global__ __launch_bounds__(256) void gemm_qkv_k(
    const ushort* __restrict__ xb,
    const ushort* __restrict__ wqb, const ushort* __restrict__ wkb,
    const ushort* __restrict__ wvb,
    ushort* __restrict__ Qb, ushort* __restrict__ Kb, ushort* __restrict__ Vtb) {
  __shared__ ushort lA[4096], lB[4096];
  int z = blockIdx.z;
  const ushort* w = (z == 0) ? wqb : (z == 1) ? wkb : wvb;
  int row0 = blockIdx.x * 128, col0 = blockIdx.y * 128;
  f32x4 acc[4][4] = {};
  gemm_mainloop(xb, w, row0, col0, lA, lB, acc);

  int tid = threadIdx.x, lane = tid & 63, wid = tid >> 6;
  int wr = wid >> 1, wc = wid & 1, lr = lane >> 4, lc = lane & 15;
  ushort* dst = (z == 0) ? Qb : (z == 1) ? Kb : Vtb;
#pragma unroll
  for (int m = 0; m < 4; m++)
#pragma unroll
    for (int n = 0; n < 4; n++)
#pragma unroll
      for (int j = 0; j < 4; j++) {
        int i = row0 + wr * 64 + m * 16 + lr * 4 + j;   // row: b,s
        int c = col0 + wc * 64 + n * 16 + lc;           // col: h,d
        int b = i >> 11, s = i & 2047, h = c >> 6, d = c & 63;
        ushort v = f2b(acc[m][n][j]);
        size_t base = (size_t)(b * 16 + h) * 131072;
        if (z < 2) dst[base + (size_t)s * 64 + d] = v;
        else       dst[base + (size_t)d * 2048 + s] = v;
      }
}

// Final projection: out(fp32) = attn @ Wo^T.
__global__ __launch_bounds__(256) void gemm_out_k(
    const ushort* __restrict__ Ab, const ushort* __restrict__ wob,
    float* __restrict__ out) {
  __shared__ ushort lA[4096], lB[4096];
  int row0 = blockIdx.x * 128, col0 = blockIdx.y * 128;
  f32x4 acc[4][4] = {};
  gemm_mainloop(Ab, wob, row0, col0, lA, lB, acc);

  int tid = threadIdx.x, lane = tid & 63, wid = tid >> 6;
  int wr = wid >> 1, wc = wid & 1, lr = lane >> 4, lc = lane & 15;
#pragma unroll
  for (int m = 0; m < 4; m++)
#pragma unroll
    for (int n = 0; n < 4; n++)
#pragma unroll
      for (int j = 0; j < 4; j++) {
        int i = row0 + wr * 64 + m * 16 + lr * 4 + j;
        int c = col0 + wc * 64 + n * 16 + lc;
        out[(size_t)i * 1024 + c] = acc[m][n][j];
      }
}

// ---------------------------------------------------------------------------
// 3) RoPE in place on Q,K.  Q additionally folded-scaled by 0.125*log2(e)
//    so attention scores are natively in exp2 domain.
// ---------------------------------------------------------------------------
__global__ __launch_bounds__(256) void rope_k(ushort* __restrict__ Qb,
                                              ushort* __restrict__ Kb) {
  const float QSCL = 0.125f * 1.44269504088896f;
  int idx = blockIdx.x * 256 + threadIdx.x;   // 32*2048*32 = 2,097,152
  int dp = idx & 31;
  int s  = (idx >> 5) & 2047;
  int bh = idx >> 16;
  float inv = exp2f((float)dp * (-13.2877123795494f / 32.0f));
  float ang = (float)s * inv;
  float sn, cs;
  sincosf(ang, &sn, &cs);
  size_t off = (size_t)bh * 131072 + (size_t)s * 64 + dp;
  float q1 = b2f(Qb[off]), q2 = b2f(Qb[off + 32]);
  Qb[off]      = f2b((q1 * cs - q2 * sn) * QSCL);
  Qb[off + 32] = f2b((q2 * cs + q1 * sn) * QSCL);
  float k1 = b2f(Kb[off]), k2 = b2f(Kb[off + 32]);
  Kb[off]      = f2b(k1 * cs - k2 * sn);
  Kb[off + 32] = f2b(k2 * cs + k1 * sn);
}

// ---------------------------------------------------------------------------
// 4) Flash attention.  512 threads = 8 waves/block, wave owns 16 q-rows
//    (QBLK=128), KVBLK=64.  K,V staged block-wide in LDS (double-buffered,
//    global_load_lds w16, wave-uniform dest + pre-swizzled global source).
//    FIXED-SHIFT softmax: P = exp2(s - 16), the -16 fed as the QK MFMA's
//    C-input.  Exact (we normalize by lsum at the end); no max tracking,
//    no shfl tree in the loop, no rescales.
//    NOTE (R6 lesson): swizzle-XOR offsets are NOT additive across the
//    swizzle field -- the +64 second-chunk offset must sit INSIDE the XOR
//    (mask (r&7)<<4 covers bit 6).  Hence two hoisted offsets rdoff0/rdoff1.
// ---------------------------------------------------------------------------
__global__ __launch_bounds__(512, 4) void attn_k(
    const ushort* __restrict__ Qb, const ushort* __restrict__ Kb,
    const ushort* __restrict__ Vtb, ushort* __restrict__ Ob) {
  __shared__ ushort kvlds[2][2][4096];   // [buf][0=K,1=V][64 rows * 64], 32 KiB
  __shared__ ushort plds[8][16][64];     // per-wave P tile, 16 KiB
  int tid = threadIdx.x, lane = tid & 63, wid = tid >> 6;   // wid in [0,8)
  int lr = lane >> 4, lc = lane & 15;

  // XCD swizzle: bh = (bid&7) + 8*(bid>>7)  -> all q-tiles of a head on 1 XCD
  int bid = blockIdx.x;
  int qt = (bid >> 3) & 15;
  int bh = (bid & 7) + ((bid >> 7) << 3);
  int q0 = qt * 128 + wid * 16;
  const ushort* Qp = Qb  + (size_t)bh * 131072 + (size_t)q0 * 64;
  const ushort* Kp = Kb  + (size_t)bh * 131072;
  const ushort* Vp = Vtb + (size_t)bh * 131072;
  char* pbase = (char*)&plds[wid][0][0];

  bf16x8 qf0 = *(const bf16x8*)(Qp + lc * 64 + lr * 8);
  bf16x8 qf1 = *(const bf16x8*)(Qp + lc * 64 + 32 + lr * 8);

  f32x4 o[4] = {};
  float lsum[4] = {0.f, 0.f, 0.f, 0.f};

  // Loop-invariant swizzled byte offsets for row lc (r&7 == lc&7 for all
  // g since g*16 = 0 mod 8).  Chunk XOR applied to the FULL logical chunk.
  const int rdoff0 = lc * 128 + ((lr * 16) ^ ((lc & 7) << 4));
  const int rdoff1 = lc * 128 + ((64 + lr * 16) ^ ((lc & 7) << 4));

  // stage K,V tile [kv, kv+64): 512 threads x one 16B chunk each.
  // LDS dest = wave-uniform wid*1024 (HW appends lane*16 -> linear tid*16);
  // global source pre-swizzled (chunk cp^(r&7)) so swizzled reads see
  // logical data (involution both sides).
  auto stage = [&](int buf, int kv) {
    int r = tid >> 3, cp = tid & 7;
    int ubase = wid * 1024;                 // wave-uniform byte base
    const ushort* gk = Kp + (size_t)(kv + r) * 64 + ((cp ^ (r & 7)) << 3);
    __builtin_amdgcn_global_load_lds(AS1(gk),
        AS3((char*)&kvlds[buf][0][0] + ubase), 16, 0, 0);
    const ushort* gv = Vp + (size_t)r * 2048 + kv + ((cp ^ (r & 7)) << 3);
    __builtin_amdgcn_global_load_lds(AS1(gv),
        AS3((char*)&kvlds[buf][1][0] + ubase), 16, 0, 0);
  };

  stage(0, 0);
  __syncthreads();
  int cur = 0;

  for (int kv = 0; kv < 2048; kv += 64) {
    if (kv + 64 < 2048) stage(cur ^ 1, kv + 64);
    const char* kbuf = (const char*)&kvlds[cur][0][0];
    const char* vbuf = (const char*)&kvlds[cur][1][0];

    // QK^T for 64 keys; C-in = -16 applies the fixed softmax shift for free
    f32x4 s[4];
    const f32x4 bias = {-16.f, -16.f, -16.f, -16.f};
#pragma unroll
    for (int g = 0; g < 4; g++) {
      bf16x8 k0 = *(const bf16x8*)(kbuf + g * 2048 + rdoff0);
      bf16x8 k1 = *(const bf16x8*)(kbuf + g * 2048 + rdoff1);
      s[g] = __builtin_amdgcn_mfma_f32_16x16x32_bf16(qf0, k0, bias, 0, 0, 0);
      s[g] = __builtin_amdgcn_mfma_f32_16x16x32_bf16(qf1, k1, s[g], 0, 0, 0);
    }

    // P = exp2(s); per-lane partial row sums (one tree after the loop)
#pragma unroll
    for (int g = 0; g < 4; g++)
#pragma unroll
      for (int j = 0; j < 4; j++) s[g][j] = exp2f(s[g][j]);
#pragma unroll
    for (int j = 0; j < 4; j++)
      lsum[j] += (s[0][j] + s[1][j]) + (s[2][j] + s[3][j]);

    // pack P -> LDS (bf16, XOR-swizzled rows)
#pragma unroll
    for (int g = 0; g < 4; g++)
#pragma unroll
      for (int jp = 0; jp < 2; jp++) {
        uint32_t w;
        asm("v_cvt_pk_bf16_f32 %0, %1, %2"
            : "=v"(w) : "v"(s[g][2 * jp]), "v"(s[g][2 * jp + 1]));
        int r0 = lr * 4 + 2 * jp, r1 = r0 + 1;
        int kb = (g * 16 + lc) * 2;
        *(ushort*)(pbase + r0 * 128 + (kb ^ ((r0 & 7) << 4))) = (ushort)w;
        *(ushort*)(pbase + r1 * 128 + (kb ^ ((r1 & 7) << 4))) = (ushort)(w >> 16);
      }
    bf16x8 pf0 = *(const bf16x8*)(pbase + rdoff0);
    bf16x8 pf1 = *(const bf16x8*)(pbase + rdoff1);

    // PV: V fragments straight from LDS at use
#pragma unroll
    for (int n = 0; n < 4; n++) {
      bf16x8 v0 = *(const bf16x8*)(vbuf + n * 2048 + rdoff0);
      bf16x8 v1 = *(const bf16x8*)(vbuf + n * 2048 + rdoff1);
      o[n] = __builtin_amdgcn_mfma_f32_16x16x32_bf16(pf0, v0, o[n], 0, 0, 0);
      o[n] = __builtin_amdgcn_mfma_f32_16x16x32_bf16(pf1, v1, o[n], 0, 0, 0);
    }
    __syncthreads();
    cur ^= 1;
  }

  // single row-sum reduce (keys spread over the 16-lane group)
#pragma unroll
  for (int m = 1; m < 16; m <<= 1)
#pragma unroll
    for (int j = 0; j < 4; j++) lsum[j] += __shfl_xor(lsum[j], m);
  float inv[4];
#pragma unroll
  for (int j = 0; j < 4; j++) inv[j] = 1.0f / lsum[j];

  int b = bh >> 4, h = bh & 15;
  ushort* Op = Ob + ((size_t)(b * 2048 + q0)) * 1024 + h * 64;
#pragma unroll
  for (int n = 0; n < 4; n++)
#pragma unroll
    for (int j = 0; j < 4; j++)
      Op[(size_t)(lr * 4 + j) * 1024 + n * 16 + lc] = f2b(o[n][j] * inv[j]);
}

// ---------------------------------------------------------------------------
// Workspace layout: xb 8M | wqb/wkb/wvb/wob 2M each | Qb 8M | Kb 8M | Vtb 8M
// | Ob 8M  (total 48 MiB)
// ---------------------------------------------------------------------------
extern "C" void kernel_launch(void* const* d_in, const int* in_sizes, int n_in,
                              void* d_out, int out_size, void* d_ws, size_t ws_size,
                              hipStream_t stream) {
  const float* x  = (const float*)d_in[0];
  const float* wq = (const float*)d_in[1];
  const float* wk = (const float*)d_in[2];
  const float* wv = (const float*)d_in[3];
  const float* wo = (const float*)d_in[4];
  float* out = (float*)d_out;
  char* ws = (char*)d_ws;
  const size_t MiB = 1024 * 1024;
  ushort* xb  = (ushort*)(ws + 0);
  ushort* wqb = (ushort*)(ws + 8 * MiB);
  ushort* wkb = (ushort*)(ws + 10 * MiB);
  ushort* wvb = (ushort*)(ws + 12 * MiB);
  ushort* wob = (ushort*)(ws + 14 * MiB);
  ushort* Qb  = (ushort*)(ws + 16 * MiB);
  ushort* Kb  = (ushort*)(ws + 24 * MiB);
  ushort* Vtb = (ushort*)(ws + 32 * MiB);
  ushort* Ob  = (ushort*)(ws + 40 * MiB);

  cvt_all_k<<<8192, 256, 0, stream>>>(x, wq, wk, wv, wo, xb);
  dim3 gqkv(32, 8, 3);
  gemm_qkv_k<<<gqkv, 256, 0, stream>>>(xb, wqb, wkb, wvb, Qb, Kb, Vtb);
  rope_k<<<8192, 256, 0, stream>>>(Qb, Kb);
  attn_k<<<512, 512, 0, stream>>>(Qb, Kb, Vtb, Ob);
  dim3 gout(32, 8);
  gemm_out_k<<<gout, 256, 0, stream>>>(Ob, wob, out);
}

// Round 8
// 156.354 us; speedup vs baseline: 2.1439x; 1.0481x over previous
//
#include <hip/hip_runtime.h>
#include <hip/hip_bf16.h>
#include <stdint.h>

// ---------------------------------------------------------------------------
// MHA block: out = softmax( rope(xWq^T) rope(xWk^T)^T / 8 ) (xWv^T) Wo^T
// B=2 S=2048 H=16 D=64 DIM=1024.  bf16 MFMA compute, fp32 accum/softmax.
// ---------------------------------------------------------------------------

#define AS1(p) ((const __attribute__((address_space(1))) void*)(p))
#define AS3(p) ((__attribute__((address_space(3))) void*)(p))

typedef __attribute__((ext_vector_type(8)))  __bf16 bf16x8;
typedef __attribute__((ext_vector_type(4)))  float  f32x4;
typedef __attribute__((ext_vector_type(16))) float  f32x16;

__device__ __forceinline__ ushort f2b(float f) {
  union { float f; uint32_t u; } v; v.f = f;
  uint32_t u = v.u;
  u += 0x7fffu + ((u >> 16) & 1);   // RNE
  return (ushort)(u >> 16);
}
__device__ __forceinline__ float b2f(ushort s) {
  union { uint32_t u; float f; } v; v.u = ((uint32_t)s) << 16;
  return v.f;
}
__device__ __forceinline__ uint32_t pkbf16(float lo, float hi) {
  uint32_t w;
  asm("v_cvt_pk_bf16_f32 %0, %1, %2" : "=v"(w) : "v"(lo), "v"(hi));
  return w;
}

// ---------------------------------------------------------------------------
// 1) fp32 -> bf16 conversion of x and the four weights (contiguous in ws).
// ---------------------------------------------------------------------------
__global__ __launch_bounds__(256) void cvt_all_k(
    const float* __restrict__ x,  const float* __restrict__ wq,
    const float* __restrict__ wk, const float* __restrict__ wv,
    const float* __restrict__ wo, ushort* __restrict__ dst) {
  int i = blockIdx.x * 256 + threadIdx.x;          // 2,097,152 total
  const float* src;
  if      (i < 1048576) src = x  + (size_t)i * 4;
  else if (i < 1310720) src = wq + (size_t)(i - 1048576) * 4;
  else if (i < 1572864) src = wk + (size_t)(i - 1310720) * 4;
  else if (i < 1835008) src = wv + (size_t)(i - 1572864) * 4;
  else                  src = wo + (size_t)(i - 1835008) * 4;
  float4 v = *(const float4*)src;
  ushort4 o;
  o.x = f2b(v.x); o.y = f2b(v.y); o.z = f2b(v.z); o.w = f2b(v.w);
  ((ushort4*)dst)[i] = o;
}

// ---------------------------------------------------------------------------
// 2) GEMM mainloop: C = A(MxK) * W(NxK)^T, 128x128 tile, BK=32, 4 waves (2x2),
//    global_load_lds width=16 staging, m97 2-barrier structure.
// ---------------------------------------------------------------------------
__device__ __forceinline__ void gemm_mainloop(
    const ushort* __restrict__ A, const ushort* __restrict__ W,
    int row0, int col0, ushort* lA, ushort* lB, f32x4 acc[4][4]) {
  const int K = 1024;
  int tid = threadIdx.x;
  int lane = tid & 63, wid = tid >> 6;
  int wr = wid >> 1, wc = wid & 1;
  int lr = lane >> 4, lc = lane & 15;
  for (int k0 = 0; k0 < K; k0 += 32) {
#pragma unroll
    for (int i = 0; i < 2; i++) {
      int idx = tid + i * 256;                       // 16B chunk id, 4 per row
      const ushort* ga = A + (size_t)(row0 + (idx >> 2)) * K + k0 + (idx & 3) * 8;
      __builtin_amdgcn_global_load_lds(AS1(ga), AS3(lA + (i * 256 + wid * 64) * 8), 16, 0, 0);
      const ushort* gb = W + (size_t)(col0 + (idx >> 2)) * K + k0 + (idx & 3) * 8;
      __builtin_amdgcn_global_load_lds(AS1(gb), AS3(lB + (i * 256 + wid * 64) * 8), 16, 0, 0);
    }
    __syncthreads();
    bf16x8 af[4], bfr[4];
#pragma unroll
    for (int m = 0; m < 4; m++)
      af[m] = *(const bf16x8*)(lA + (wr * 64 + m * 16 + lc) * 32 + lr * 8);
#pragma unroll
    for (int n = 0; n < 4; n++)
      bfr[n] = *(const bf16x8*)(lB + (wc * 64 + n * 16 + lc) * 32 + lr * 8);
#pragma unroll
    for (int m = 0; m < 4; m++)
#pragma unroll
      for (int n = 0; n < 4; n++)
        acc[m][n] = __builtin_amdgcn_mfma_f32_16x16x32_bf16(af[m], bfr[n], acc[m][n], 0, 0, 0);
    __syncthreads();
  }
}

// QKV projections in one launch (z = 0:Q, 1:K, 2:V).
__global__ __launch_bounds__(256) void gemm_qkv_k(
    const ushort* __restrict__ xb,
    const ushort* __restrict__ wqb, const ushort* __restrict__ wkb,
    const ushort* __restrict__ wvb,
    ushort* __restrict__ Qb, ushort* __restrict__ Kb, ushort* __restrict__ Vtb) {
  __shared__ ushort lA[4096], lB[4096];
  int z = blockIdx.z;
  const ushort* w = (z == 0) ? wqb : (z == 1) ? wkb : wvb;
  int row0 = blockIdx.x * 128, col0 = blockIdx.y * 128;
  f32x4 acc[4][4] = {};
  gemm_mainloop(xb, w, row0, col0, lA, lB, acc);

  int tid = threadIdx.x, lane = tid & 63, wid = tid >> 6;
  int wr = wid >> 1, wc = wid & 1, lr = lane >> 4, lc = lane & 15;
  ushort* dst = (z == 0) ? Qb : (z == 1) ? Kb : Vtb;
#pragma unroll
  for (int m = 0; m < 4; m++)
#pragma unroll
    for (int n = 0; n < 4; n++)
#pragma unroll
      for (int j = 0; j < 4; j++) {
        int i = row0 + wr * 64 + m * 16 + lr * 4 + j;   // row: b,s
        int c = col0 + wc * 64 + n * 16 + lc;           // col: h,d
        int b = i >> 11, s = i & 2047, h = c >> 6, d = c & 63;
        ushort v = f2b(acc[m][n][j]);
        size_t base = (size_t)(b * 16 + h) * 131072;
        if (z < 2) dst[base + (size_t)s * 64 + d] = v;
        else       dst[base + (size_t)d * 2048 + s] = v;
      }
}

// Final projection: out(fp32) = attn @ Wo^T.
__global__ __launch_bounds__(256) void gemm_out_k(
    const ushort* __restrict__ Ab, const ushort* __restrict__ wob,
    float* __restrict__ out) {
  __shared__ ushort lA[4096], lB[4096];
  int row0 = blockIdx.x * 128, col0 = blockIdx.y * 128;
  f32x4 acc[4][4] = {};
  gemm_mainloop(Ab, wob, row0, col0, lA, lB, acc);

  int tid = threadIdx.x, lane = tid & 63, wid = tid >> 6;
  int wr = wid >> 1, wc = wid & 1, lr = lane >> 4, lc = lane & 15;
#pragma unroll
  for (int m = 0; m < 4; m++)
#pragma unroll
    for (int n = 0; n < 4; n++)
#pragma unroll
      for (int j = 0; j < 4; j++) {
        int i = row0 + wr * 64 + m * 16 + lr * 4 + j;
        int c = col0 + wc * 64 + n * 16 + lc;
        out[(size_t)i * 1024 + c] = acc[m][n][j];
      }
}

// ---------------------------------------------------------------------------
// 3) RoPE in place on Q,K.  Q additionally folded-scaled by 0.125*log2(e)
//    so attention scores are natively in exp2 domain.
// ---------------------------------------------------------------------------
__global__ __launch_bounds__(256) void rope_k(ushort* __restrict__ Qb,
                                              ushort* __restrict__ Kb) {
  const float QSCL = 0.125f * 1.44269504088896f;
  int idx = blockIdx.x * 256 + threadIdx.x;   // 32*2048*32 = 2,097,152
  int dp = idx & 31;
  int s  = (idx >> 5) & 2047;
  int bh = idx >> 16;
  float inv = exp2f((float)dp * (-13.2877123795494f / 32.0f));
  float ang = (float)s * inv;
  float sn, cs;
  sincosf(ang, &sn, &cs);
  size_t off = (size_t)bh * 131072 + (size_t)s * 64 + dp;
  float q1 = b2f(Qb[off]), q2 = b2f(Qb[off + 32]);
  Qb[off]      = f2b((q1 * cs - q2 * sn) * QSCL);
  Qb[off + 32] = f2b((q2 * cs + q1 * sn) * QSCL);
  float k1 = b2f(Kb[off]), k2 = b2f(Kb[off + 32]);
  Kb[off]      = f2b(k1 * cs - k2 * sn);
  Kb[off + 32] = f2b(k2 * cs + k1 * sn);
}

// ---------------------------------------------------------------------------
// 4) Flash attention, 32x32 swapped-QK structure (plain-HIP m214/§B port).
//    4 waves/block, wave owns 32 q-rows (QBLK=128), KVBLK=64.
//    QK^T computed as mfma(A=K, B=Q) -> C col = lane&31 = OWN q-row:
//    softmax fully in-register (scalar lsum/lane, no shuffles in loop).
//    P -> PV A-frags via 16 cvt_pk + 8 permlane32_swap (T12); no P-LDS.
//    K,V staged in LDS (dbuf, global_load_lds w16, wave-uniform dest +
//    pre-swizzled global source; read chunk ^= row&7).
//    Fixed-shift softmax: P = exp2(s - 16), -16 fed as MFMA C-in.
//    32x32x16 layouts (m74/m101): A row=lane&31, B col=lane&31,
//    k = 8*(lane>>5)+i;  C col=lane&31, row=(reg&3)+8*(reg>>2)+4*(lane>>5).
// ---------------------------------------------------------------------------
__global__ __launch_bounds__(256, 3) void attn_k(
    const ushort* __restrict__ Qb, const ushort* __restrict__ Kb,
    const ushort* __restrict__ Vtb, ushort* __restrict__ Ob) {
  __shared__ ushort kvlds[2][2][4096];   // [buf][0=K,1=V][64 rows][64], 32 KiB
  int tid = threadIdx.x, lane = tid & 63, wid = tid >> 6;   // wid in [0,4)
  int lc5 = lane & 31, hi = lane >> 5;

  // XCD swizzle: all q-tiles of a head on one XCD
  int bid = blockIdx.x;
  int qt = (bid >> 3) & 15;
  int bh = (bid & 7) + ((bid >> 7) << 3);
  int q0 = qt * 128 + wid * 32;
  const ushort* Qp = Qb  + (size_t)bh * 131072 + (size_t)q0 * 64;
  const ushort* Kp = Kb  + (size_t)bh * 131072;
  const ushort* Vp = Vtb + (size_t)bh * 131072;

  // Q as B-operand: col = q = lc5, k-dim = d: slice ks -> d = ks*16+8*hi+i
  bf16x8 qf[4];
#pragma unroll
  for (int ks = 0; ks < 4; ks++)
    qf[ks] = *(const bf16x8*)(Qp + lc5 * 64 + ks * 16 + hi * 8);

  f32x16 o0, o1, bias;
#pragma unroll
  for (int i = 0; i < 16; i++) { o0[i] = 0.f; o1[i] = 0.f; bias[i] = -16.f; }
  float lsum = 0.f;

  // swizzled in-row chunk offsets: chunk(ks) = (2ks+hi) ^ (row&7), row&7=lc5&7
  int swz[4];
#pragma unroll
  for (int ks = 0; ks < 4; ks++)
    swz[ks] = (((2 * ks + hi) ^ (lc5 & 7)) << 4);
  const int rbase = lc5 * 128;

  // stage K,V tile [kv,kv+64): 256 threads x 2 chunks each (16B chunks).
  // LDS dest = wave-uniform (HW appends lane*16); global source pre-swizzled.
  auto stage = [&](int buf, int kv) {
#pragma unroll
    for (int i = 0; i < 2; i++) {
      int idx = i * 256 + tid;
      int r = idx >> 3, cp = idx & 7;
      int ubase = (i * 256 + wid * 64) * 16;
      const ushort* gk = Kp + (size_t)(kv + r) * 64 + ((cp ^ (r & 7)) << 3);
      __builtin_amdgcn_global_load_lds(AS1(gk),
          AS3((char*)&kvlds[buf][0][0] + ubase), 16, 0, 0);
      const ushort* gv = Vp + (size_t)r * 2048 + kv + ((cp ^ (r & 7)) << 3);
      __builtin_amdgcn_global_load_lds(AS1(gv),
          AS3((char*)&kvlds[buf][1][0] + ubase), 16, 0, 0);
    }
  };

  stage(0, 0);
  __syncthreads();
  int cur = 0;

  for (int kv = 0; kv < 2048; kv += 64) {
    if (kv + 64 < 2048) stage(cur ^ 1, kv + 64);
    const char* kbuf = (const char*)&kvlds[cur][0][0];
    const char* vbuf = (const char*)&kvlds[cur][1][0];

    // QK^T: s[t] covers keys [kv+32t, kv+32t+32), col = own q
    f32x16 s0 = bias, s1 = bias;
#pragma unroll
    for (int ks = 0; ks < 4; ks++) {
      bf16x8 ka0 = *(const bf16x8*)(kbuf + rbase + swz[ks]);
      bf16x8 ka1 = *(const bf16x8*)(kbuf + 4096 + rbase + swz[ks]);
      s0 = __builtin_amdgcn_mfma_f32_32x32x16_bf16(ka0, qf[ks], s0, 0, 0, 0);
      s1 = __builtin_amdgcn_mfma_f32_32x32x16_bf16(ka1, qf[ks], s1, 0, 0, 0);
    }

    // P = exp2(s); per-lane scalar row-sum (lane owns q = lc5, its key-half)
#pragma unroll
    for (int i = 0; i < 16; i++) { s0[i] = exp2f(s0[i]); s1[i] = exp2f(s1[i]); }
    float acc = 0.f;
#pragma unroll
    for (int i = 0; i < 16; i++) acc += s0[i] + s1[i];
    lsum += acc;

    // P -> PV A-frags: for slice ks (keys 16ks+8hi+j), reg rb=8*(ks&1)(+4 hi
    // half via swap).  swap(pk(rb,rb+1), pk(rb+4,rb+5)) yields both words.
    bf16x8 a[4];
#pragma unroll
    for (int t = 0; t < 2; t++) {
      const f32x16& s = t ? s1 : s0;
#pragma unroll
      for (int h2 = 0; h2 < 2; h2++) {
        int rb = 8 * h2;
        uint32_t wa1 = pkbf16(s[rb],     s[rb + 1]);
        uint32_t wb1 = pkbf16(s[rb + 4], s[rb + 5]);
        asm("v_permlane32_swap_b32 %0, %1" : "+v"(wa1), "+v"(wb1));
        uint32_t wa2 = pkbf16(s[rb + 2], s[rb + 3]);
        uint32_t wb2 = pkbf16(s[rb + 6], s[rb + 7]);
        asm("v_permlane32_swap_b32 %0, %1" : "+v"(wa2), "+v"(wb2));
        union { uint32_t u[4]; bf16x8 v; } tmp;
        tmp.u[0] = wa1; tmp.u[1] = wa2; tmp.u[2] = wb1; tmp.u[3] = wb2;
        a[t * 2 + h2] = tmp.v;
      }
    }

    // PV: B = V^T rows = d, k-dim = keys (same slice/swizzle pattern as K)
#pragma unroll
    for (int ks = 0; ks < 4; ks++) {
      bf16x8 vb0 = *(const bf16x8*)(vbuf + rbase + swz[ks]);
      bf16x8 vb1 = *(const bf16x8*)(vbuf + 4096 + rbase + swz[ks]);
      o0 = __builtin_amdgcn_mfma_f32_32x32x16_bf16(a[ks], vb0, o0, 0, 0, 0);
      o1 = __builtin_amdgcn_mfma_f32_32x32x16_bf16(a[ks], vb1, o1, 0, 0, 0);
    }
    __syncthreads();
    cur ^= 1;
  }

  // combine the two key-halves of lsum (lanes q and q+32), then normalize
  lsum += __shfl_xor(lsum, 32);
  float invq = 1.0f / lsum;
  float invr[16];
#pragma unroll
  for (int r = 0; r < 16; r++)
    invr[r] = __shfl(invq, (r & 3) + 8 * (r >> 2) + 4 * hi);

  int b = bh >> 4, h = bh & 15;
  ushort* Op = Ob + (size_t)(b * 2048 + q0) * 1024 + h * 64 + lc5;
#pragma unroll
  for (int r = 0; r < 16; r++) {
    int rrow = (r & 3) + 8 * (r >> 2) + 4 * hi;
    Op[(size_t)rrow * 1024]      = f2b(o0[r] * invr[r]);
    Op[(size_t)rrow * 1024 + 32] = f2b(o1[r] * invr[r]);
  }
}

// ---------------------------------------------------------------------------
// Workspace layout: xb 8M | wqb/wkb/wvb/wob 2M each | Qb 8M | Kb 8M | Vtb 8M
// | Ob 8M  (total 48 MiB)
// ---------------------------------------------------------------------------
extern "C" void kernel_launch(void* const* d_in, const int* in_sizes, int n_in,
                              void* d_out, int out_size, void* d_ws, size_t ws_size,
                              hipStream_t stream) {
  const float* x  = (const float*)d_in[0];
  const float* wq = (const float*)d_in[1];
  const float* wk = (const float*)d_in[2];
  const float* wv = (const float*)d_in[3];
  const float* wo = (const float*)d_in[4];
  float* out = (float*)d_out;
  char* ws = (char*)d_ws;
  const size_t MiB = 1024 * 1024;
  ushort* xb  = (ushort*)(ws + 0);
  ushort* wqb = (ushort*)(ws + 8 * MiB);
  ushort* wkb = (ushort*)(ws + 10 * MiB);
  ushort* wvb = (ushort*)(ws + 12 * MiB);
  ushort* wob = (ushort*)(ws + 14 * MiB);
  ushort* Qb  = (ushort*)(ws + 16 * MiB);
  ushort* Kb  = (ushort*)(ws + 24 * MiB);
  ushort* Vtb = (ushort*)(ws + 32 * MiB);
  ushort* Ob  = (ushort*)(ws + 40 * MiB);

  cvt_all_k<<<8192, 256, 0, stream>>>(x, wq, wk, wv, wo, xb);
  dim3 gqkv(32, 8, 3);
  gemm_qkv_k<<<gqkv, 256, 0, stream>>>(xb, wqb, wkb, wvb, Qb, Kb, Vtb);
  rope_k<<<8192, 256, 0, stream>>>(Qb, Kb);
  attn_k<<<512, 256, 0, stream>>>(Qb, Kb, Vtb, Ob);
  dim3 gout(32, 8);
  gemm_out_k<<<gout, 256, 0, stream>>>(Ob, wob, out);
}

// Round 9
// 144.802 us; speedup vs baseline: 2.3149x; 1.0798x over previous
//
#include <hip/hip_runtime.h>
#include <hip/hip_bf16.h>
#include <stdint.h>

// ---------------------------------------------------------------------------
// MHA block: out = softmax( rope(xWq^T) rope(xWk^T)^T / 8 ) (xWv^T) Wo^T
// B=2 S=2048 H=16 D=64 DIM=1024.  bf16 MFMA compute, fp32 accum/softmax.
// ---------------------------------------------------------------------------

#define AS1(p) ((const __attribute__((address_space(1))) void*)(p))
#define AS3(p) ((__attribute__((address_space(3))) void*)(p))

typedef __attribute__((ext_vector_type(8)))  __bf16 bf16x8;
typedef __attribute__((ext_vector_type(4)))  float  f32x4;
typedef __attribute__((ext_vector_type(16))) float  f32x16;

__device__ __forceinline__ ushort f2b(float f) {
  union { float f; uint32_t u; } v; v.f = f;
  uint32_t u = v.u;
  u += 0x7fffu + ((u >> 16) & 1);   // RNE
  return (ushort)(u >> 16);
}
__device__ __forceinline__ float b2f(ushort s) {
  union { uint32_t u; float f; } v; v.u = ((uint32_t)s) << 16;
  return v.f;
}
__device__ __forceinline__ uint32_t pkbf16(float lo, float hi) {
  uint32_t w;
  asm("v_cvt_pk_bf16_f32 %0, %1, %2" : "=v"(w) : "v"(lo), "v"(hi));
  return w;
}
// raw v_exp_f32 (args here are in [-130, ~21]: tail flush-to-zero is fine)
__device__ __forceinline__ float fast_exp2(float x) {
#if __has_builtin(__builtin_amdgcn_exp2f)
  return __builtin_amdgcn_exp2f(x);
#else
  float r;
  asm("v_exp_f32 %0, %1" : "=v"(r) : "v"(x));
  return r;
#endif
}

// ---------------------------------------------------------------------------
// 1) fp32 -> bf16 conversion of x and the four weights (contiguous in ws).
// ---------------------------------------------------------------------------
__global__ __launch_bounds__(256) void cvt_all_k(
    const float* __restrict__ x,  const float* __restrict__ wq,
    const float* __restrict__ wk, const float* __restrict__ wv,
    const float* __restrict__ wo, ushort* __restrict__ dst) {
  int i = blockIdx.x * 256 + threadIdx.x;          // 2,097,152 total
  const float* src;
  if      (i < 1048576) src = x  + (size_t)i * 4;
  else if (i < 1310720) src = wq + (size_t)(i - 1048576) * 4;
  else if (i < 1572864) src = wk + (size_t)(i - 1310720) * 4;
  else if (i < 1835008) src = wv + (size_t)(i - 1572864) * 4;
  else                  src = wo + (size_t)(i - 1835008) * 4;
  float4 v = *(const float4*)src;
  ushort4 o;
  o.x = f2b(v.x); o.y = f2b(v.y); o.z = f2b(v.z); o.w = f2b(v.w);
  ((ushort4*)dst)[i] = o;
}

// ---------------------------------------------------------------------------
// 2) GEMM mainloop: C = A(MxK) * W(NxK)^T, 128x128 tile, BK=32, 4 waves (2x2),
//    global_load_lds width=16 staging, m97 2-barrier structure.
// ---------------------------------------------------------------------------
__device__ __forceinline__ void gemm_mainloop(
    const ushort* __restrict__ A, const ushort* __restrict__ W,
    int row0, int col0, ushort* lA, ushort* lB, f32x4 acc[4][4]) {
  const int K = 1024;
  int tid = threadIdx.x;
  int lane = tid & 63, wid = tid >> 6;
  int wr = wid >> 1, wc = wid & 1;
  int lr = lane >> 4, lc = lane & 15;
  for (int k0 = 0; k0 < K; k0 += 32) {
#pragma unroll
    for (int i = 0; i < 2; i++) {
      int idx = tid + i * 256;                       // 16B chunk id, 4 per row
      const ushort* ga = A + (size_t)(row0 + (idx >> 2)) * K + k0 + (idx & 3) * 8;
      __builtin_amdgcn_global_load_lds(AS1(ga), AS3(lA + (i * 256 + wid * 64) * 8), 16, 0, 0);
      const ushort* gb = W + (size_t)(col0 + (idx >> 2)) * K + k0 + (idx & 3) * 8;
      __builtin_amdgcn_global_load_lds(AS1(gb), AS3(lB + (i * 256 + wid * 64) * 8), 16, 0, 0);
    }
    __syncthreads();
    bf16x8 af[4], bfr[4];
#pragma unroll
    for (int m = 0; m < 4; m++)
      af[m] = *(const bf16x8*)(lA + (wr * 64 + m * 16 + lc) * 32 + lr * 8);
#pragma unroll
    for (int n = 0; n < 4; n++)
      bfr[n] = *(const bf16x8*)(lB + (wc * 64 + n * 16 + lc) * 32 + lr * 8);
#pragma unroll
    for (int m = 0; m < 4; m++)
#pragma unroll
      for (int n = 0; n < 4; n++)
        acc[m][n] = __builtin_amdgcn_mfma_f32_16x16x32_bf16(af[m], bfr[n], acc[m][n], 0, 0, 0);
    __syncthreads();
  }
}

// QKV projections in one launch (z = 0:Q, 1:K, 2:V).
__global__ __launch_bounds__(256) void gemm_qkv_k(
    const ushort* __restrict__ xb,
    const ushort* __restrict__ wqb, const ushort* __restrict__ wkb,
    const ushort* __restrict__ wvb,
    ushort* __restrict__ Qb, ushort* __restrict__ Kb, ushort* __restrict__ Vtb) {
  __shared__ ushort lA[4096], lB[4096];
  int z = blockIdx.z;
  const ushort* w = (z == 0) ? wqb : (z == 1) ? wkb : wvb;
  int row0 = blockIdx.x * 128, col0 = blockIdx.y * 128;
  f32x4 acc[4][4] = {};
  gemm_mainloop(xb, w, row0, col0, lA, lB, acc);

  int tid = threadIdx.x, lane = tid & 63, wid = tid >> 6;
  int wr = wid >> 1, wc = wid & 1, lr = lane >> 4, lc = lane & 15;
  ushort* dst = (z == 0) ? Qb : (z == 1) ? Kb : Vtb;
#pragma unroll
  for (int m = 0; m < 4; m++)
#pragma unroll
    for (int n = 0; n < 4; n++)
#pragma unroll
      for (int j = 0; j < 4; j++) {
        int i = row0 + wr * 64 + m * 16 + lr * 4 + j;   // row: b,s
        int c = col0 + wc * 64 + n * 16 + lc;           // col: h,d
        int b = i >> 11, s = i & 2047, h = c >> 6, d = c & 63;
        ushort v = f2b(acc[m][n][j]);
        size_t base = (size_t)(b * 16 + h) * 131072;
        if (z < 2) dst[base + (size_t)s * 64 + d] = v;
        else       dst[base + (size_t)d * 2048 + s] = v;
      }
}

// Final projection: out(fp32) = attn @ Wo^T.
__global__ __launch_bounds__(256) void gemm_out_k(
    const ushort* __restrict__ Ab, const ushort* __restrict__ wob,
    float* __restrict__ out) {
  __shared__ ushort lA[4096], lB[4096];
  int row0 = blockIdx.x * 128, col0 = blockIdx.y * 128;
  f32x4 acc[4][4] = {};
  gemm_mainloop(Ab, wob, row0, col0, lA, lB, acc);

  int tid = threadIdx.x, lane = tid & 63, wid = tid >> 6;
  int wr = wid >> 1, wc = wid & 1, lr = lane >> 4, lc = lane & 15;
#pragma unroll
  for (int m = 0; m < 4; m++)
#pragma unroll
    for (int n = 0; n < 4; n++)
#pragma unroll
      for (int j = 0; j < 4; j++) {
        int i = row0 + wr * 64 + m * 16 + lr * 4 + j;
        int c = col0 + wc * 64 + n * 16 + lc;
        out[(size_t)i * 1024 + c] = acc[m][n][j];
      }
}

// ---------------------------------------------------------------------------
// 3) RoPE in place on Q,K.  Q additionally folded-scaled by 0.125*log2(e)
//    so attention scores are natively in exp2 domain.
// ---------------------------------------------------------------------------
__global__ __launch_bounds__(256) void rope_k(ushort* __restrict__ Qb,
                                              ushort* __restrict__ Kb) {
  const float QSCL = 0.125f * 1.44269504088896f;
  int idx = blockIdx.x * 256 + threadIdx.x;   // 32*2048*32 = 2,097,152
  int dp = idx & 31;
  int s  = (idx >> 5) & 2047;
  int bh = idx >> 16;
  float inv = exp2f((float)dp * (-13.2877123795494f / 32.0f));
  float ang = (float)s * inv;
  float sn, cs;
  sincosf(ang, &sn, &cs);
  size_t off = (size_t)bh * 131072 + (size_t)s * 64 + dp;
  float q1 = b2f(Qb[off]), q2 = b2f(Qb[off + 32]);
  Qb[off]      = f2b((q1 * cs - q2 * sn) * QSCL);
  Qb[off + 32] = f2b((q2 * cs + q1 * sn) * QSCL);
  float k1 = b2f(Kb[off]), k2 = b2f(Kb[off + 32]);
  Kb[off]      = f2b(k1 * cs - k2 * sn);
  Kb[off + 32] = f2b(k2 * cs + k1 * sn);
}

// ---------------------------------------------------------------------------
// 4) Flash attention, 32x32 swapped-QK structure.
//    4 waves/block, wave owns 32 q-rows (QBLK=128), KVBLK=64.
//    QK^T computed as mfma(A=K, B=Q) -> C col = lane&31 = OWN q-row:
//    softmax fully in-register.  P -> PV A-frags via cvt_pk + permlane32_swap.
//    NO softmax shift at all: P = exp2(s_raw); o and lsum both carry the
//    common 2^16-ish scale which cancels in the final divide (s_raw <= ~21,
//    lsum <= 2^21 -- fp32-safe).  exp2 is raw v_exp_f32 (args >= -130:
//    flush-to-zero tail is negligible vs lsum).  s_setprio(1) around MFMA.
// ---------------------------------------------------------------------------
__global__ __launch_bounds__(256, 3) void attn_k(
    const ushort* __restrict__ Qb, const ushort* __restrict__ Kb,
    const ushort* __restrict__ Vtb, ushort* __restrict__ Ob) {
  __shared__ ushort kvlds[2][2][4096];   // [buf][0=K,1=V][64 rows][64], 32 KiB
  int tid = threadIdx.x, lane = tid & 63, wid = tid >> 6;   // wid in [0,4)
  int lc5 = lane & 31, hi = lane >> 5;

  // XCD swizzle: all q-tiles of a head on one XCD
  int bid = blockIdx.x;
  int qt = (bid >> 3) & 15;
  int bh = (bid & 7) + ((bid >> 7) << 3);
  int q0 = qt * 128 + wid * 32;
  const ushort* Qp = Qb  + (size_t)bh * 131072 + (size_t)q0 * 64;
  const ushort* Kp = Kb  + (size_t)bh * 131072;
  const ushort* Vp = Vtb + (size_t)bh * 131072;

  // Q as B-operand: col = q = lc5, k-dim = d: slice ks -> d = ks*16+8*hi+i
  bf16x8 qf[4];
#pragma unroll
  for (int ks = 0; ks < 4; ks++)
    qf[ks] = *(const bf16x8*)(Qp + lc5 * 64 + ks * 16 + hi * 8);

  f32x16 o0, o1;
#pragma unroll
  for (int i = 0; i < 16; i++) { o0[i] = 0.f; o1[i] = 0.f; }
  float lsum = 0.f;

  // swizzled in-row chunk offsets: chunk(ks) = (2ks+hi) ^ (row&7), row&7=lc5&7
  int swz[4];
#pragma unroll
  for (int ks = 0; ks < 4; ks++)
    swz[ks] = (((2 * ks + hi) ^ (lc5 & 7)) << 4);
  const int rbase = lc5 * 128;

  // stage K,V tile [kv,kv+64): 256 threads x 2 chunks each (16B chunks).
  // LDS dest = wave-uniform (HW appends lane*16); global source pre-swizzled.
  auto stage = [&](int buf, int kv) {
#pragma unroll
    for (int i = 0; i < 2; i++) {
      int idx = i * 256 + tid;
      int r = idx >> 3, cp = idx & 7;
      int ubase = (i * 256 + wid * 64) * 16;
      const ushort* gk = Kp + (size_t)(kv + r) * 64 + ((cp ^ (r & 7)) << 3);
      __builtin_amdgcn_global_load_lds(AS1(gk),
          AS3((char*)&kvlds[buf][0][0] + ubase), 16, 0, 0);
      const ushort* gv = Vp + (size_t)r * 2048 + kv + ((cp ^ (r & 7)) << 3);
      __builtin_amdgcn_global_load_lds(AS1(gv),
          AS3((char*)&kvlds[buf][1][0] + ubase), 16, 0, 0);
    }
  };

  stage(0, 0);
  __syncthreads();
  int cur = 0;

  for (int kv = 0; kv < 2048; kv += 64) {
    if (kv + 64 < 2048) stage(cur ^ 1, kv + 64);
    const char* kbuf = (const char*)&kvlds[cur][0][0];
    const char* vbuf = (const char*)&kvlds[cur][1][0];

    // QK^T: s[t] covers keys [kv+32t, kv+32t+32), col = own q
    f32x16 s0 = {}, s1 = {};
    __builtin_amdgcn_s_setprio(1);
#pragma unroll
    for (int ks = 0; ks < 4; ks++) {
      bf16x8 ka0 = *(const bf16x8*)(kbuf + rbase + swz[ks]);
      bf16x8 ka1 = *(const bf16x8*)(kbuf + 4096 + rbase + swz[ks]);
      s0 = __builtin_amdgcn_mfma_f32_32x32x16_bf16(ka0, qf[ks], s0, 0, 0, 0);
      s1 = __builtin_amdgcn_mfma_f32_32x32x16_bf16(ka1, qf[ks], s1, 0, 0, 0);
    }
    __builtin_amdgcn_s_setprio(0);

    // P = exp2(s_raw) (common scale cancels in final divide); scalar row-sum
#pragma unroll
    for (int i = 0; i < 16; i++) {
      s0[i] = fast_exp2(s0[i]);
      s1[i] = fast_exp2(s1[i]);
    }
    float acc = 0.f;
#pragma unroll
    for (int i = 0; i < 16; i++) acc += s0[i] + s1[i];
    lsum += acc;

    // P -> PV A-frags: 16 cvt_pk + 8 permlane32_swap (T12)
    bf16x8 a[4];
#pragma unroll
    for (int t = 0; t < 2; t++) {
      const f32x16& s = t ? s1 : s0;
#pragma unroll
      for (int h2 = 0; h2 < 2; h2++) {
        int rb = 8 * h2;
        uint32_t wa1 = pkbf16(s[rb],     s[rb + 1]);
        uint32_t wb1 = pkbf16(s[rb + 4], s[rb + 5]);
        asm("v_permlane32_swap_b32 %0, %1" : "+v"(wa1), "+v"(wb1));
        uint32_t wa2 = pkbf16(s[rb + 2], s[rb + 3]);
        uint32_t wb2 = pkbf16(s[rb + 6], s[rb + 7]);
        asm("v_permlane32_swap_b32 %0, %1" : "+v"(wa2), "+v"(wb2));
        union { uint32_t u[4]; bf16x8 v; } tmp;
        tmp.u[0] = wa1; tmp.u[1] = wa2; tmp.u[2] = wb1; tmp.u[3] = wb2;
        a[t * 2 + h2] = tmp.v;
      }
    }

    // PV: B = V^T rows = d, k-dim = keys (same slice/swizzle pattern as K)
    __builtin_amdgcn_s_setprio(1);
#pragma unroll
    for (int ks = 0; ks < 4; ks++) {
      bf16x8 vb0 = *(const bf16x8*)(vbuf + rbase + swz[ks]);
      bf16x8 vb1 = *(const bf16x8*)(vbuf + 4096 + rbase + swz[ks]);
      o0 = __builtin_amdgcn_mfma_f32_32x32x16_bf16(a[ks], vb0, o0, 0, 0, 0);
      o1 = __builtin_amdgcn_mfma_f32_32x32x16_bf16(a[ks], vb1, o1, 0, 0, 0);
    }
    __builtin_amdgcn_s_setprio(0);
    __syncthreads();
    cur ^= 1;
  }

  // combine the two key-halves of lsum (lanes q and q+32), then normalize
  lsum += __shfl_xor(lsum, 32);
  float invq = 1.0f / lsum;
  float invr[16];
#pragma unroll
  for (int r = 0; r < 16; r++)
    invr[r] = __shfl(invq, (r & 3) + 8 * (r >> 2) + 4 * hi);

  int b = bh >> 4, h = bh & 15;
  ushort* Op = Ob + (size_t)(b * 2048 + q0) * 1024 + h * 64 + lc5;
#pragma unroll
  for (int r = 0; r < 16; r++) {
    int rrow = (r & 3) + 8 * (r >> 2) + 4 * hi;
    Op[(size_t)rrow * 1024]      = f2b(o0[r] * invr[r]);
    Op[(size_t)rrow * 1024 + 32] = f2b(o1[r] * invr[r]);
  }
}

// ---------------------------------------------------------------------------
// Workspace layout: xb 8M | wqb/wkb/wvb/wob 2M each | Qb 8M | Kb 8M | Vtb 8M
// | Ob 8M  (total 48 MiB)
// ---------------------------------------------------------------------------
extern "C" void kernel_launch(void* const* d_in, const int* in_sizes, int n_in,
                              void* d_out, int out_size, void* d_ws, size_t ws_size,
                              hipStream_t stream) {
  const float* x  = (const float*)d_in[0];
  const float* wq = (const float*)d_in[1];
  const float* wk = (const float*)d_in[2];
  const float* wv = (const float*)d_in[3];
  const float* wo = (const float*)d_in[4];
  float* out = (float*)d_out;
  char* ws = (char*)d_ws;
  const size_t MiB = 1024 * 1024;
  ushort* xb  = (ushort*)(ws + 0);
  ushort* wqb = (ushort*)(ws + 8 * MiB);
  ushort* wkb = (ushort*)(ws + 10 * MiB);
  ushort* wvb = (ushort*)(ws + 12 * MiB);
  ushort* wob = (ushort*)(ws + 14 * MiB);
  ushort* Qb  = (ushort*)(ws + 16 * MiB);
  ushort* Kb  = (ushort*)(ws + 24 * MiB);
  ushort* Vtb = (ushort*)(ws + 32 * MiB);
  ushort* Ob  = (ushort*)(ws + 40 * MiB);

  cvt_all_k<<<8192, 256, 0, stream>>>(x, wq, wk, wv, wo, xb);
  dim3 gqkv(32, 8, 3);
  gemm_qkv_k<<<gqkv, 256, 0, stream>>>(xb, wqb, wkb, wvb, Qb, Kb, Vtb);
  rope_k<<<8192, 256, 0, stream>>>(Qb, Kb);
  attn_k<<<512, 256, 0, stream>>>(Qb, Kb, Vtb, Ob);
  dim3 gout(32, 8);
  gemm_out_k<<<gout, 256, 0, stream>>>(Ob, wob, out);
}

// Round 11
// 113.109 us; speedup vs baseline: 2.9636x; 1.2802x over previous
//
#include <hip/hip_runtime.h>
#include <hip/hip_bf16.h>
#include <stdint.h>

// ---------------------------------------------------------------------------
// MHA block: out = softmax( rope(xWq^T) rope(xWk^T)^T / 8 ) (xWv^T) Wo^T
// B=2 S=2048 H=16 D=64 DIM=1024.  bf16 MFMA compute, fp32 accum/softmax.
// ---------------------------------------------------------------------------

#define AS1(p) ((const __attribute__((address_space(1))) void*)(p))
#define AS3(p) ((__attribute__((address_space(3))) void*)(p))

typedef __attribute__((ext_vector_type(8)))  __bf16 bf16x8;
typedef __attribute__((ext_vector_type(4)))  float  f32x4;
typedef __attribute__((ext_vector_type(16))) float  f32x16;

__device__ __forceinline__ ushort f2b(float f) {
  union { float f; uint32_t u; } v; v.f = f;
  uint32_t u = v.u;
  u += 0x7fffu + ((u >> 16) & 1);   // RNE
  return (ushort)(u >> 16);
}
__device__ __forceinline__ float b2f(ushort s) {
  union { uint32_t u; float f; } v; v.u = ((uint32_t)s) << 16;
  return v.f;
}
__device__ __forceinline__ uint32_t pkbf16(float lo, float hi) {
  uint32_t w;
  asm("v_cvt_pk_bf16_f32 %0, %1, %2" : "=v"(w) : "v"(lo), "v"(hi));
  return w;
}
// Fast exp2 via native v_exp_f32.  R10 LESSON: raw inline-asm v_exp_f32 has
// a TRANS->VALU dependent-use hazard the compiler does NOT guard for asm
// (it doesn't parse asm contents) -> scattered corruption.  Prefer the
// builtin (compiler inserts the wait state); the asm fallback carries its
// own s_nop so a dependent consumer can never violate the hazard.
__device__ __forceinline__ float fast_exp2(float x) {
#if __has_builtin(__builtin_amdgcn_exp2f)
  return __builtin_amdgcn_exp2f(x);
#else
  float r;
  asm("v_exp_f32 %0, %1\n\ts_nop 1" : "=v"(r) : "v"(x));
  return r;
#endif
}

// ---------------------------------------------------------------------------
// 1) fp32 -> bf16 conversion of x and the four weights (contiguous in ws).
// ---------------------------------------------------------------------------
__global__ __launch_bounds__(256) void cvt_all_k(
    const float* __restrict__ x,  const float* __restrict__ wq,
    const float* __restrict__ wk, const float* __restrict__ wv,
    const float* __restrict__ wo, ushort* __restrict__ dst) {
  int i = blockIdx.x * 256 + threadIdx.x;          // 2,097,152 total
  const float* src;
  if      (i < 1048576) src = x  + (size_t)i * 4;
  else if (i < 1310720) src = wq + (size_t)(i - 1048576) * 4;
  else if (i < 1572864) src = wk + (size_t)(i - 1310720) * 4;
  else if (i < 1835008) src = wv + (size_t)(i - 1572864) * 4;
  else                  src = wo + (size_t)(i - 1835008) * 4;
  float4 v = *(const float4*)src;
  ushort4 o;
  o.x = f2b(v.x); o.y = f2b(v.y); o.z = f2b(v.z); o.w = f2b(v.w);
  ((ushort4*)dst)[i] = o;
}

// ---------------------------------------------------------------------------
// 2) GEMM mainloop: C = A(MxK) * W(NxK)^T, 128x128 tile, BK=32, 4 waves (2x2).
//    Double-buffered LDS, single barrier per K-step (stage(next) || compute).
// ---------------------------------------------------------------------------
__device__ __forceinline__ void gemm_mainloop(
    const ushort* __restrict__ A, const ushort* __restrict__ W,
    int row0, int col0, ushort* lds, f32x4 acc[4][4]) {
  const int K = 1024;
  int tid = threadIdx.x;
  int lane = tid & 63, wid = tid >> 6;
  int wr = wid >> 1, wc = wid & 1;
  int lr = lane >> 4, lc = lane & 15;
  ushort* lA = lds;
  ushort* lB = lds + 8192;

  auto stage = [&](int buf, int k0) {
#pragma unroll
    for (int i = 0; i < 2; i++) {
      int idx = tid + i * 256;                       // 16B chunk id, 4 per row
      const ushort* ga = A + (size_t)(row0 + (idx >> 2)) * K + k0 + (idx & 3) * 8;
      __builtin_amdgcn_global_load_lds(AS1(ga),
          AS3(lA + buf * 4096 + (i * 256 + wid * 64) * 8), 16, 0, 0);
      const ushort* gb = W + (size_t)(col0 + (idx >> 2)) * K + k0 + (idx & 3) * 8;
      __builtin_amdgcn_global_load_lds(AS1(gb),
          AS3(lB + buf * 4096 + (i * 256 + wid * 64) * 8), 16, 0, 0);
    }
  };

  stage(0, 0);
  __syncthreads();
  int cur = 0;
  for (int k0 = 0; k0 < K; k0 += 32) {
    if (k0 + 32 < K) stage(cur ^ 1, k0 + 32);
    const ushort* a  = lA + cur * 4096;
    const ushort* bm = lB + cur * 4096;
    bf16x8 af[4], bfr[4];
#pragma unroll
    for (int m = 0; m < 4; m++)
      af[m] = *(const bf16x8*)(a + (wr * 64 + m * 16 + lc) * 32 + lr * 8);
#pragma unroll
    for (int n = 0; n < 4; n++)
      bfr[n] = *(const bf16x8*)(bm + (wc * 64 + n * 16 + lc) * 32 + lr * 8);
#pragma unroll
    for (int m = 0; m < 4; m++)
#pragma unroll
      for (int n = 0; n < 4; n++)
        acc[m][n] = __builtin_amdgcn_mfma_f32_16x16x32_bf16(af[m], bfr[n], acc[m][n], 0, 0, 0);
    __syncthreads();     // drains: my ds_reads + next-buffer gload_lds writes
    cur ^= 1;
  }
}

// QKV projections in one launch (z = 0:Q, 1:K, 2:V).
// Q,K -> [B,H,S,D]; V -> [B,H,D,S] via XOR-swizzled LDS transpose.
__global__ __launch_bounds__(256) void gemm_qkv_k(
    const ushort* __restrict__ xb,
    const ushort* __restrict__ wqb, const ushort* __restrict__ wkb,
    const ushort* __restrict__ wvb,
    ushort* __restrict__ Qb, ushort* __restrict__ Kb, ushort* __restrict__ Vtb) {
  __shared__ ushort lds[16384];        // 32 KiB: dbuf staging, then V scratch
  int z = blockIdx.z;
  const ushort* w = (z == 0) ? wqb : (z == 1) ? wkb : wvb;
  int row0 = blockIdx.x * 128, col0 = blockIdx.y * 128;
  f32x4 acc[4][4] = {};
  gemm_mainloop(xb, w, row0, col0, lds, acc);

  int tid = threadIdx.x, lane = tid & 63, wid = tid >> 6;
  int wr = wid >> 1, wc = wid & 1, lr = lane >> 4, lc = lane & 15;

  if (z < 2) {
    ushort* dst = (z == 0) ? Qb : Kb;
#pragma unroll
    for (int m = 0; m < 4; m++)
#pragma unroll
      for (int n = 0; n < 4; n++)
#pragma unroll
        for (int j = 0; j < 4; j++) {
          int i = row0 + wr * 64 + m * 16 + lr * 4 + j;   // row: b,s
          int c = col0 + wc * 64 + n * 16 + lc;           // col: h,d
          int b = i >> 11, s = i & 2047, h = c >> 6, d = c & 63;
          dst[(size_t)(b * 16 + h) * 131072 + (size_t)s * 64 + d] = f2b(acc[m][n][j]);
        }
  } else {
    // V: transpose 128x128 tile through LDS (free after final barrier).
    // scratch[c][s ^ ((c&7)<<3)] (ushort idx), 4-ushort groups.
#pragma unroll
    for (int m = 0; m < 4; m++)
#pragma unroll
      for (int n = 0; n < 4; n++) {
        int c = wc * 64 + n * 16 + lc;
        int sb = wr * 64 + m * 16 + lr * 4;            // j=0..3 consecutive
        uint32_t w0 = pkbf16(acc[m][n][0], acc[m][n][1]);
        uint32_t w1 = pkbf16(acc[m][n][2], acc[m][n][3]);
        int soff = sb ^ ((c & 7) << 3);                // multiple of 4 ushorts
        uint2 val; val.x = w0; val.y = w1;
        *(uint2*)(lds + c * 128 + soff) = val;         // 8B store
      }
    __syncthreads();
    int b = row0 >> 11, srow = row0 & 2047;
#pragma unroll
    for (int i = 0; i < 8; i++) {
      int idx = i * 256 + tid;                 // 2048 16B chunks
      int cl = idx >> 4, sc = idx & 15;
      int soff = (sc * 8) ^ ((cl & 7) << 3);
      bf16x8 v = *(const bf16x8*)(lds + cl * 128 + soff);
      int cg = col0 + cl, h = cg >> 6, d = cg & 63;
      *(bf16x8*)(Vtb + (size_t)(b * 16 + h) * 131072 + (size_t)d * 2048 + srow + sc * 8) = v;
    }
  }
}

// Final projection: out(fp32) = attn @ Wo^T.
__global__ __launch_bounds__(256) void gemm_out_k(
    const ushort* __restrict__ Ab, const ushort* __restrict__ wob,
    float* __restrict__ out) {
  __shared__ ushort lds[16384];
  int row0 = blockIdx.x * 128, col0 = blockIdx.y * 128;
  f32x4 acc[4][4] = {};
  gemm_mainloop(Ab, wob, row0, col0, lds, acc);

  int tid = threadIdx.x, lane = tid & 63, wid = tid >> 6;
  int wr = wid >> 1, wc = wid & 1, lr = lane >> 4, lc = lane & 15;
#pragma unroll
  for (int m = 0; m < 4; m++)
#pragma unroll
    for (int n = 0; n < 4; n++)
#pragma unroll
      for (int j = 0; j < 4; j++) {
        int i = row0 + wr * 64 + m * 16 + lr * 4 + j;
        int c = col0 + wc * 64 + n * 16 + lc;
        out[(size_t)i * 1024 + c] = acc[m][n][j];
      }
}

// ---------------------------------------------------------------------------
// 3) RoPE in place on Q,K.  Q additionally folded-scaled by 0.125*log2(e)
//    so attention scores are natively in exp2 domain.
// ---------------------------------------------------------------------------
__global__ __launch_bounds__(256) void rope_k(ushort* __restrict__ Qb,
                                              ushort* __restrict__ Kb) {
  const float QSCL = 0.125f * 1.44269504088896f;
  int idx = blockIdx.x * 256 + threadIdx.x;   // 32*2048*32 = 2,097,152
  int dp = idx & 31;
  int s  = (idx >> 5) & 2047;
  int bh = idx >> 16;
  float inv = exp2f((float)dp * (-13.2877123795494f / 32.0f));
  float ang = (float)s * inv;
  float sn, cs;
  sincosf(ang, &sn, &cs);
  size_t off = (size_t)bh * 131072 + (size_t)s * 64 + dp;
  float q1 = b2f(Qb[off]), q2 = b2f(Qb[off + 32]);
  Qb[off]      = f2b((q1 * cs - q2 * sn) * QSCL);
  Qb[off + 32] = f2b((q2 * cs + q1 * sn) * QSCL);
  float k1 = b2f(Kb[off]), k2 = b2f(Kb[off + 32]);
  Kb[off]      = f2b(k1 * cs - k2 * sn);
  Kb[off + 32] = f2b(k2 * cs + k1 * sn);
}

// ---------------------------------------------------------------------------
// 4) Flash attention, 32x32 swapped-QK structure (R9 kernel, guarded exp2).
// ---------------------------------------------------------------------------
__global__ __launch_bounds__(256, 3) void attn_k(
    const ushort* __restrict__ Qb, const ushort* __restrict__ Kb,
    const ushort* __restrict__ Vtb, ushort* __restrict__ Ob) {
  __shared__ ushort kvlds[2][2][4096];   // [buf][0=K,1=V][64 rows][64], 32 KiB
  int tid = threadIdx.x, lane = tid & 63, wid = tid >> 6;   // wid in [0,4)
  int lc5 = lane & 31, hi = lane >> 5;

  int bid = blockIdx.x;
  int qt = (bid >> 3) & 15;
  int bh = (bid & 7) + ((bid >> 7) << 3);
  int q0 = qt * 128 + wid * 32;
  const ushort* Qp = Qb  + (size_t)bh * 131072 + (size_t)q0 * 64;
  const ushort* Kp = Kb  + (size_t)bh * 131072;
  const ushort* Vp = Vtb + (size_t)bh * 131072;

  bf16x8 qf[4];
#pragma unroll
  for (int ks = 0; ks < 4; ks++)
    qf[ks] = *(const bf16x8*)(Qp + lc5 * 64 + ks * 16 + hi * 8);

  f32x16 o0, o1;
#pragma unroll
  for (int i = 0; i < 16; i++) { o0[i] = 0.f; o1[i] = 0.f; }
  float lsum = 0.f;

  int swz[4];
#pragma unroll
  for (int ks = 0; ks < 4; ks++)
    swz[ks] = (((2 * ks + hi) ^ (lc5 & 7)) << 4);
  const int rbase = lc5 * 128;

  auto stage = [&](int buf, int kv) {
#pragma unroll
    for (int i = 0; i < 2; i++) {
      int idx = i * 256 + tid;
      int r = idx >> 3, cp = idx & 7;
      int ubase = (i * 256 + wid * 64) * 16;
      const ushort* gk = Kp + (size_t)(kv + r) * 64 + ((cp ^ (r & 7)) << 3);
      __builtin_amdgcn_global_load_lds(AS1(gk),
          AS3((char*)&kvlds[buf][0][0] + ubase), 16, 0, 0);
      const ushort* gv = Vp + (size_t)r * 2048 + kv + ((cp ^ (r & 7)) << 3);
      __builtin_amdgcn_global_load_lds(AS1(gv),
          AS3((char*)&kvlds[buf][1][0] + ubase), 16, 0, 0);
    }
  };

  stage(0, 0);
  __syncthreads();
  int cur = 0;

  for (int kv = 0; kv < 2048; kv += 64) {
    if (kv + 64 < 2048) stage(cur ^ 1, kv + 64);
    const char* kbuf = (const char*)&kvlds[cur][0][0];
    const char* vbuf = (const char*)&kvlds[cur][1][0];

    f32x16 s0 = {}, s1 = {};
    __builtin_amdgcn_s_setprio(1);
#pragma unroll
    for (int ks = 0; ks < 4; ks++) {
      bf16x8 ka0 = *(const bf16x8*)(kbuf + rbase + swz[ks]);
      bf16x8 ka1 = *(const bf16x8*)(kbuf + 4096 + rbase + swz[ks]);
      s0 = __builtin_amdgcn_mfma_f32_32x32x16_bf16(ka0, qf[ks], s0, 0, 0, 0);
      s1 = __builtin_amdgcn_mfma_f32_32x32x16_bf16(ka1, qf[ks], s1, 0, 0, 0);
    }
    __builtin_amdgcn_s_setprio(0);

#pragma unroll
    for (int i = 0; i < 16; i++) {
      s0[i] = fast_exp2(s0[i]);
      s1[i] = fast_exp2(s1[i]);
    }
    float acc = 0.f;
#pragma unroll
    for (int i = 0; i < 16; i++) acc += s0[i] + s1[i];
    lsum += acc;

    bf16x8 a[4];
#pragma unroll
    for (int t = 0; t < 2; t++) {
      const f32x16& s = t ? s1 : s0;
#pragma unroll
      for (int h2 = 0; h2 < 2; h2++) {
        int rb = 8 * h2;
        uint32_t wa1 = pkbf16(s[rb],     s[rb + 1]);
        uint32_t wb1 = pkbf16(s[rb + 4], s[rb + 5]);
        asm("v_permlane32_swap_b32 %0, %1" : "+v"(wa1), "+v"(wb1));
        uint32_t wa2 = pkbf16(s[rb + 2], s[rb + 3]);
        uint32_t wb2 = pkbf16(s[rb + 6], s[rb + 7]);
        asm("v_permlane32_swap_b32 %0, %1" : "+v"(wa2), "+v"(wb2));
        union { uint32_t u[4]; bf16x8 v; } tmp;
        tmp.u[0] = wa1; tmp.u[1] = wa2; tmp.u[2] = wb1; tmp.u[3] = wb2;
        a[t * 2 + h2] = tmp.v;
      }
    }

    __builtin_amdgcn_s_setprio(1);
#pragma unroll
    for (int ks = 0; ks < 4; ks++) {
      bf16x8 vb0 = *(const bf16x8*)(vbuf + rbase + swz[ks]);
      bf16x8 vb1 = *(const bf16x8*)(vbuf + 4096 + rbase + swz[ks]);
      o0 = __builtin_amdgcn_mfma_f32_32x32x16_bf16(a[ks], vb0, o0, 0, 0, 0);
      o1 = __builtin_amdgcn_mfma_f32_32x32x16_bf16(a[ks], vb1, o1, 0, 0, 0);
    }
    __builtin_amdgcn_s_setprio(0);
    __syncthreads();
    cur ^= 1;
  }

  lsum += __shfl_xor(lsum, 32);
  float invq = 1.0f / lsum;
  float invr[16];
#pragma unroll
  for (int r = 0; r < 16; r++)
    invr[r] = __shfl(invq, (r & 3) + 8 * (r >> 2) + 4 * hi);

  int b = bh >> 4, h = bh & 15;
  ushort* Op = Ob + (size_t)(b * 2048 + q0) * 1024 + h * 64 + lc5;
#pragma unroll
  for (int r = 0; r < 16; r++) {
    int rrow = (r & 3) + 8 * (r >> 2) + 4 * hi;
    Op[(size_t)rrow * 1024]      = f2b(o0[r] * invr[r]);
    Op[(size_t)rrow * 1024 + 32] = f2b(o1[r] * invr[r]);
  }
}

// ---------------------------------------------------------------------------
// Workspace layout: xb 8M | wqb/wkb/wvb/wob 2M each | Qb 8M | Kb 8M | Vtb 8M
// | Ob 8M  (total 48 MiB)
// ---------------------------------------------------------------------------
extern "C" void kernel_launch(void* const* d_in, const int* in_sizes, int n_in,
                              void* d_out, int out_size, void* d_ws, size_t ws_size,
                              hipStream_t stream) {
  const float* x  = (const float*)d_in[0];
  const float* wq = (const float*)d_in[1];
  const float* wk = (const float*)d_in[2];
  const float* wv = (const float*)d_in[3];
  const float* wo = (const float*)d_in[4];
  float* out = (float*)d_out;
  char* ws = (char*)d_ws;
  const size_t MiB = 1024 * 1024;
  ushort* xb  = (ushort*)(ws + 0);
  ushort* wqb = (ushort*)(ws + 8 * MiB);
  ushort* wkb = (ushort*)(ws + 10 * MiB);
  ushort* wvb = (ushort*)(ws + 12 * MiB);
  ushort* wob = (ushort*)(ws + 14 * MiB);
  ushort* Qb  = (ushort*)(ws + 16 * MiB);
  ushort* Kb  = (ushort*)(ws + 24 * MiB);
  ushort* Vtb = (ushort*)(ws + 32 * MiB);
  ushort* Ob  = (ushort*)(ws + 40 * MiB);

  cvt_all_k<<<8192, 256, 0, stream>>>(x, wq, wk, wv, wo, xb);
  dim3 gqkv(32, 8, 3);
  gemm_qkv_k<<<gqkv, 256, 0, stream>>>(xb, wqb, wkb, wvb, Qb, Kb, Vtb);
  rope_k<<<8192, 256, 0, stream>>>(Qb, Kb);
  attn_k<<<512, 256, 0, stream>>>(Qb, Kb, Vtb, Ob);
  dim3 gout(32, 8);
  gemm_out_k<<<gout, 256, 0, stream>>>(Ob, wob, out);
}

// Round 12
// 110.871 us; speedup vs baseline: 3.0234x; 1.0202x over previous
//
#include <hip/hip_runtime.h>
#include <hip/hip_bf16.h>
#include <stdint.h>

// ---------------------------------------------------------------------------
// MHA block: out = softmax( rope(xWq^T) rope(xWk^T)^T / 8 ) (xWv^T) Wo^T
// B=2 S=2048 H=16 D=64 DIM=1024.  bf16 MFMA compute, fp32 accum/softmax.
// ---------------------------------------------------------------------------

#define AS1(p) ((const __attribute__((address_space(1))) void*)(p))
#define AS3(p) ((__attribute__((address_space(3))) void*)(p))

typedef __attribute__((ext_vector_type(8)))  __bf16 bf16x8;
typedef __attribute__((ext_vector_type(4)))  float  f32x4;
typedef __attribute__((ext_vector_type(16))) float  f32x16;

__device__ __forceinline__ ushort f2b(float f) {
  union { float f; uint32_t u; } v; v.f = f;
  uint32_t u = v.u;
  u += 0x7fffu + ((u >> 16) & 1);   // RNE
  return (ushort)(u >> 16);
}
__device__ __forceinline__ float b2f(ushort s) {
  union { uint32_t u; float f; } v; v.u = ((uint32_t)s) << 16;
  return v.f;
}
__device__ __forceinline__ uint32_t pkbf16(float lo, float hi) {
  uint32_t w;
  asm("v_cvt_pk_bf16_f32 %0, %1, %2" : "=v"(w) : "v"(lo), "v"(hi));
  return w;
}
// Fast exp2 via native v_exp_f32.  R10 LESSON: raw inline-asm v_exp_f32 has
// a TRANS->VALU dependent-use hazard the compiler does NOT guard for asm.
// Prefer the builtin; asm fallback carries its own s_nop.
__device__ __forceinline__ float fast_exp2(float x) {
#if __has_builtin(__builtin_amdgcn_exp2f)
  return __builtin_amdgcn_exp2f(x);
#else
  float r;
  asm("v_exp_f32 %0, %1\n\ts_nop 1" : "=v"(r) : "v"(x));
  return r;
#endif
}

// ---------------------------------------------------------------------------
// 1) fp32 -> bf16 conversion of x and the four weights (contiguous in ws).
// ---------------------------------------------------------------------------
__global__ __launch_bounds__(256) void cvt_all_k(
    const float* __restrict__ x,  const float* __restrict__ wq,
    const float* __restrict__ wk, const float* __restrict__ wv,
    const float* __restrict__ wo, ushort* __restrict__ dst) {
  int i = blockIdx.x * 256 + threadIdx.x;          // 2,097,152 total
  const float* src;
  if      (i < 1048576) src = x  + (size_t)i * 4;
  else if (i < 1310720) src = wq + (size_t)(i - 1048576) * 4;
  else if (i < 1572864) src = wk + (size_t)(i - 1310720) * 4;
  else if (i < 1835008) src = wv + (size_t)(i - 1572864) * 4;
  else                  src = wo + (size_t)(i - 1835008) * 4;
  float4 v = *(const float4*)src;
  ushort4 o;
  o.x = f2b(v.x); o.y = f2b(v.y); o.z = f2b(v.z); o.w = f2b(v.w);
  ((ushort4*)dst)[i] = o;
}

// ---------------------------------------------------------------------------
// 2) GEMM mainloop: C = A(MxK) * W(NxK)^T, 128x128 tile, BK=32, 4 waves (2x2).
//    Double-buffered LDS, single barrier per K-step (stage(next) || compute).
// ---------------------------------------------------------------------------
__device__ __forceinline__ void gemm_mainloop(
    const ushort* __restrict__ A, const ushort* __restrict__ W,
    int row0, int col0, ushort* lds, f32x4 acc[4][4]) {
  const int K = 1024;
  int tid = threadIdx.x;
  int lane = tid & 63, wid = tid >> 6;
  int wr = wid >> 1, wc = wid & 1;
  int lr = lane >> 4, lc = lane & 15;
  ushort* lA = lds;
  ushort* lB = lds + 8192;

  auto stage = [&](int buf, int k0) {
#pragma unroll
    for (int i = 0; i < 2; i++) {
      int idx = tid + i * 256;                       // 16B chunk id, 4 per row
      const ushort* ga = A + (size_t)(row0 + (idx >> 2)) * K + k0 + (idx & 3) * 8;
      __builtin_amdgcn_global_load_lds(AS1(ga),
          AS3(lA + buf * 4096 + (i * 256 + wid * 64) * 8), 16, 0, 0);
      const ushort* gb = W + (size_t)(col0 + (idx >> 2)) * K + k0 + (idx & 3) * 8;
      __builtin_amdgcn_global_load_lds(AS1(gb),
          AS3(lB + buf * 4096 + (i * 256 + wid * 64) * 8), 16, 0, 0);
    }
  };

  stage(0, 0);
  __syncthreads();
  int cur = 0;
  for (int k0 = 0; k0 < K; k0 += 32) {
    if (k0 + 32 < K) stage(cur ^ 1, k0 + 32);
    const ushort* a  = lA + cur * 4096;
    const ushort* bm = lB + cur * 4096;
    bf16x8 af[4], bfr[4];
#pragma unroll
    for (int m = 0; m < 4; m++)
      af[m] = *(const bf16x8*)(a + (wr * 64 + m * 16 + lc) * 32 + lr * 8);
#pragma unroll
    for (int n = 0; n < 4; n++)
      bfr[n] = *(const bf16x8*)(bm + (wc * 64 + n * 16 + lc) * 32 + lr * 8);
#pragma unroll
    for (int m = 0; m < 4; m++)
#pragma unroll
      for (int n = 0; n < 4; n++)
        acc[m][n] = __builtin_amdgcn_mfma_f32_16x16x32_bf16(af[m], bfr[n], acc[m][n], 0, 0, 0);
    __syncthreads();     // drains: my ds_reads + next-buffer gload_lds writes
    cur ^= 1;
  }
}

// QKV projections in one launch (z = 0:Q, 1:K, 2:V).
// Q,K -> [B,H,S,D]; V -> [B,H,D,S] via XOR-swizzled LDS transpose.
__global__ __launch_bounds__(256) void gemm_qkv_k(
    const ushort* __restrict__ xb,
    const ushort* __restrict__ wqb, const ushort* __restrict__ wkb,
    const ushort* __restrict__ wvb,
    ushort* __restrict__ Qb, ushort* __restrict__ Kb, ushort* __restrict__ Vtb) {
  __shared__ ushort lds[16384];        // 32 KiB: dbuf staging, then V scratch
  int z = blockIdx.z;
  const ushort* w = (z == 0) ? wqb : (z == 1) ? wkb : wvb;
  int row0 = blockIdx.x * 128, col0 = blockIdx.y * 128;
  f32x4 acc[4][4] = {};
  gemm_mainloop(xb, w, row0, col0, lds, acc);

  int tid = threadIdx.x, lane = tid & 63, wid = tid >> 6;
  int wr = wid >> 1, wc = wid & 1, lr = lane >> 4, lc = lane & 15;

  if (z < 2) {
    ushort* dst = (z == 0) ? Qb : Kb;
#pragma unroll
    for (int m = 0; m < 4; m++)
#pragma unroll
      for (int n = 0; n < 4; n++)
#pragma unroll
        for (int j = 0; j < 4; j++) {
          int i = row0 + wr * 64 + m * 16 + lr * 4 + j;   // row: b,s
          int c = col0 + wc * 64 + n * 16 + lc;           // col: h,d
          int b = i >> 11, s = i & 2047, h = c >> 6, d = c & 63;
          dst[(size_t)(b * 16 + h) * 131072 + (size_t)s * 64 + d] = f2b(acc[m][n][j]);
        }
  } else {
    // V: transpose 128x128 tile through LDS (free after final barrier).
#pragma unroll
    for (int m = 0; m < 4; m++)
#pragma unroll
      for (int n = 0; n < 4; n++) {
        int c = wc * 64 + n * 16 + lc;
        int sb = wr * 64 + m * 16 + lr * 4;            // j=0..3 consecutive
        uint32_t w0 = pkbf16(acc[m][n][0], acc[m][n][1]);
        uint32_t w1 = pkbf16(acc[m][n][2], acc[m][n][3]);
        int soff = sb ^ ((c & 7) << 3);                // multiple of 4 ushorts
        uint2 val; val.x = w0; val.y = w1;
        *(uint2*)(lds + c * 128 + soff) = val;         // 8B store
      }
    __syncthreads();
    int b = row0 >> 11, srow = row0 & 2047;
#pragma unroll
    for (int i = 0; i < 8; i++) {
      int idx = i * 256 + tid;                 // 2048 16B chunks
      int cl = idx >> 4, sc = idx & 15;
      int soff = (sc * 8) ^ ((cl & 7) << 3);
      bf16x8 v = *(const bf16x8*)(lds + cl * 128 + soff);
      int cg = col0 + cl, h = cg >> 6, d = cg & 63;
      *(bf16x8*)(Vtb + (size_t)(b * 16 + h) * 131072 + (size_t)d * 2048 + srow + sc * 8) = v;
    }
  }
}

// Final projection: out(fp32) = attn @ Wo^T.
__global__ __launch_bounds__(256) void gemm_out_k(
    const ushort* __restrict__ Ab, const ushort* __restrict__ wob,
    float* __restrict__ out) {
  __shared__ ushort lds[16384];
  int row0 = blockIdx.x * 128, col0 = blockIdx.y * 128;
  f32x4 acc[4][4] = {};
  gemm_mainloop(Ab, wob, row0, col0, lds, acc);

  int tid = threadIdx.x, lane = tid & 63, wid = tid >> 6;
  int wr = wid >> 1, wc = wid & 1, lr = lane >> 4, lc = lane & 15;
#pragma unroll
  for (int m = 0; m < 4; m++)
#pragma unroll
    for (int n = 0; n < 4; n++)
#pragma unroll
      for (int j = 0; j < 4; j++) {
        int i = row0 + wr * 64 + m * 16 + lr * 4 + j;
        int c = col0 + wc * 64 + n * 16 + lc;
        out[(size_t)i * 1024 + c] = acc[m][n][j];
      }
}

// ---------------------------------------------------------------------------
// 3) RoPE in place on Q,K.  Q additionally folded-scaled by 0.125*log2(e)
//    so attention scores are natively in exp2 domain.
// ---------------------------------------------------------------------------
__global__ __launch_bounds__(256) void rope_k(ushort* __restrict__ Qb,
                                              ushort* __restrict__ Kb) {
  const float QSCL = 0.125f * 1.44269504088896f;
  int idx = blockIdx.x * 256 + threadIdx.x;   // 32*2048*32 = 2,097,152
  int dp = idx & 31;
  int s  = (idx >> 5) & 2047;
  int bh = idx >> 16;
  float inv = exp2f((float)dp * (-13.2877123795494f / 32.0f));
  float ang = (float)s * inv;
  float sn, cs;
  sincosf(ang, &sn, &cs);
  size_t off = (size_t)bh * 131072 + (size_t)s * 64 + dp;
  float q1 = b2f(Qb[off]), q2 = b2f(Qb[off + 32]);
  Qb[off]      = f2b((q1 * cs - q2 * sn) * QSCL);
  Qb[off + 32] = f2b((q2 * cs + q1 * sn) * QSCL);
  float k1 = b2f(Kb[off]), k2 = b2f(Kb[off + 32]);
  Kb[off]      = f2b(k1 * cs - k2 * sn);
  Kb[off + 32] = f2b(k2 * cs + k1 * sn);
}

// ---------------------------------------------------------------------------
// 4) Flash attention, 32x32 swapped-QK + WITHIN-BLOCK KV-SPLIT.
//    512 threads = 8 waves: wave w -> q-subtile (w&3), kv-half (w>>2).
//    Each iteration stages a PAIR of 64-key tiles (group 0: even tile,
//    group 1: odd tile); 4-tile LDS rotation (64 KiB -> 2 blocks/CU ->
//    16 waves/CU, 2x the R11 occupancy).  Fixed-shift exp2 softmax has no
//    running max, so the two kv-halves' (o, lsum) combine by PURE ADDITION
//    through LDS at the end.
// ---------------------------------------------------------------------------
__global__ __launch_bounds__(512, 4) void attn_k(
    const ushort* __restrict__ Qb, const ushort* __restrict__ Kb,
    const ushort* __restrict__ Vtb, ushort* __restrict__ Ob) {
  __shared__ char ldsb[65536];   // [buf:2][tile:2][K 8KB | V 8KB]; reused
  int tid = threadIdx.x, lane = tid & 63, wid = tid >> 6;   // wid in [0,8)
  int lc5 = lane & 31, hi = lane >> 5;
  int qsub = wid & 3, grp = wid >> 2;

  // XCD swizzle: all q-tiles of a head on one XCD
  int bid = blockIdx.x;
  int qt = (bid >> 3) & 15;
  int bh = (bid & 7) + ((bid >> 7) << 3);
  int q0 = qt * 128 + qsub * 32;
  const ushort* Qp = Qb  + (size_t)bh * 131072 + (size_t)q0 * 64;
  const ushort* Kp = Kb  + (size_t)bh * 131072;
  const ushort* Vp = Vtb + (size_t)bh * 131072;

  // Q as B-operand: col = q = lc5, k-dim = d: slice ks -> d = ks*16+8*hi+i
  bf16x8 qf[4];
#pragma unroll
  for (int ks = 0; ks < 4; ks++)
    qf[ks] = *(const bf16x8*)(Qp + lc5 * 64 + ks * 16 + hi * 8);

  f32x16 o0, o1;
#pragma unroll
  for (int i = 0; i < 16; i++) { o0[i] = 0.f; o1[i] = 0.f; }
  float lsum = 0.f;

  // swizzled in-row chunk offsets: chunk(ks) = (2ks+hi) ^ (row&7), row&7=lc5&7
  int swz[4];
#pragma unroll
  for (int ks = 0; ks < 4; ks++)
    swz[ks] = (((2 * ks + hi) ^ (lc5 & 7)) << 4);
  const int rbase = lc5 * 128;

  // stage the 128-key pair [kvp, kvp+128): tile t keys [kvp+64t, kvp+64t+64).
  // 512 threads x 1 chunk per (tile, K/V).  LDS dest wave-uniform wid*1024
  // within each 8KB region (HW appends lane*16 -> chunk tid*16).
  auto stage = [&](int buf, int kvp) {
    int r = tid >> 3, cp = tid & 7;
    int ubase = wid * 1024;
#pragma unroll
    for (int t = 0; t < 2; t++) {
      char* tb = ldsb + buf * 32768 + t * 16384;
      const ushort* gk = Kp + (size_t)(kvp + 64 * t + r) * 64 + ((cp ^ (r & 7)) << 3);
      __builtin_amdgcn_global_load_lds(AS1(gk), AS3(tb + ubase), 16, 0, 0);
      const ushort* gv = Vp + (size_t)r * 2048 + kvp + 64 * t + ((cp ^ (r & 7)) << 3);
      __builtin_amdgcn_global_load_lds(AS1(gv), AS3(tb + 8192 + ubase), 16, 0, 0);
    }
  };

  stage(0, 0);
  __syncthreads();
  int cur = 0;

  for (int kvp = 0; kvp < 2048; kvp += 128) {
    if (kvp + 128 < 2048) stage(cur ^ 1, kvp + 128);
    const char* kbuf = ldsb + cur * 32768 + grp * 16384;   // my tile
    const char* vbuf = kbuf + 8192;

    // QK^T for my 64 keys; col = own q
    f32x16 s0 = {}, s1 = {};
    __builtin_amdgcn_s_setprio(1);
#pragma unroll
    for (int ks = 0; ks < 4; ks++) {
      bf16x8 ka0 = *(const bf16x8*)(kbuf + rbase + swz[ks]);
      bf16x8 ka1 = *(const bf16x8*)(kbuf + 4096 + rbase + swz[ks]);
      s0 = __builtin_amdgcn_mfma_f32_32x32x16_bf16(ka0, qf[ks], s0, 0, 0, 0);
      s1 = __builtin_amdgcn_mfma_f32_32x32x16_bf16(ka1, qf[ks], s1, 0, 0, 0);
    }
    __builtin_amdgcn_s_setprio(0);

    // P = exp2(s_raw) (common scale cancels in final divide); scalar row-sum
#pragma unroll
    for (int i = 0; i < 16; i++) {
      s0[i] = fast_exp2(s0[i]);
      s1[i] = fast_exp2(s1[i]);
    }
    float acc = 0.f;
#pragma unroll
    for (int i = 0; i < 16; i++) acc += s0[i] + s1[i];
    lsum += acc;

    // P -> PV A-frags: 16 cvt_pk + 8 permlane32_swap (T12)
    bf16x8 a[4];
#pragma unroll
    for (int t = 0; t < 2; t++) {
      const f32x16& s = t ? s1 : s0;
#pragma unroll
      for (int h2 = 0; h2 < 2; h2++) {
        int rb = 8 * h2;
        uint32_t wa1 = pkbf16(s[rb],     s[rb + 1]);
        uint32_t wb1 = pkbf16(s[rb + 4], s[rb + 5]);
        asm("v_permlane32_swap_b32 %0, %1" : "+v"(wa1), "+v"(wb1));
        uint32_t wa2 = pkbf16(s[rb + 2], s[rb + 3]);
        uint32_t wb2 = pkbf16(s[rb + 6], s[rb + 7]);
        asm("v_permlane32_swap_b32 %0, %1" : "+v"(wa2), "+v"(wb2));
        union { uint32_t u[4]; bf16x8 v; } tmp;
        tmp.u[0] = wa1; tmp.u[1] = wa2; tmp.u[2] = wb1; tmp.u[3] = wb2;
        a[t * 2 + h2] = tmp.v;
      }
    }

    // PV: B = V^T rows = d, k-dim = keys
    __builtin_amdgcn_s_setprio(1);
#pragma unroll
    for (int ks = 0; ks < 4; ks++) {
      bf16x8 vb0 = *(const bf16x8*)(vbuf + rbase + swz[ks]);
      bf16x8 vb1 = *(const bf16x8*)(vbuf + 4096 + rbase + swz[ks]);
      o0 = __builtin_amdgcn_mfma_f32_32x32x16_bf16(a[ks], vb0, o0, 0, 0, 0);
      o1 = __builtin_amdgcn_mfma_f32_32x32x16_bf16(a[ks], vb1, o1, 0, 0, 0);
    }
    __builtin_amdgcn_s_setprio(0);
    __syncthreads();
    cur ^= 1;
  }

  // combine the two kv-halves: group 1 writes partials, group 0 adds.
  // stride 33 floats (odd) -> conflict-free.  ldsb is free after last barrier.
  float* cb = (float*)ldsb;
  float* p = cb + (size_t)(qsub * 64 + lane) * 33;
  if (grp == 1) {
#pragma unroll
    for (int i = 0; i < 16; i++) { p[i] = o0[i]; p[16 + i] = o1[i]; }
    p[32] = lsum;
  }
  __syncthreads();
  if (grp == 0) {
#pragma unroll
    for (int i = 0; i < 16; i++) { o0[i] += p[i]; o1[i] += p[16 + i]; }
    lsum += p[32];

    // combine the two key-halves of lsum (lanes q and q+32), then normalize
    lsum += __shfl_xor(lsum, 32);
    float invq = 1.0f / lsum;
    float invr[16];
#pragma unroll
    for (int r = 0; r < 16; r++)
      invr[r] = __shfl(invq, (r & 3) + 8 * (r >> 2) + 4 * hi);

    int b = bh >> 4, h = bh & 15;
    ushort* Op = Ob + (size_t)(b * 2048 + q0) * 1024 + h * 64 + lc5;
#pragma unroll
    for (int r = 0; r < 16; r++) {
      int rrow = (r & 3) + 8 * (r >> 2) + 4 * hi;
      Op[(size_t)rrow * 1024]      = f2b(o0[r] * invr[r]);
      Op[(size_t)rrow * 1024 + 32] = f2b(o1[r] * invr[r]);
    }
  }
}

// ---------------------------------------------------------------------------
// Workspace layout: xb 8M | wqb/wkb/wvb/wob 2M each | Qb 8M | Kb 8M | Vtb 8M
// | Ob 8M  (total 48 MiB)
// ---------------------------------------------------------------------------
extern "C" void kernel_launch(void* const* d_in, const int* in_sizes, int n_in,
                              void* d_out, int out_size, void* d_ws, size_t ws_size,
                              hipStream_t stream) {
  const float* x  = (const float*)d_in[0];
  const float* wq = (const float*)d_in[1];
  const float* wk = (const float*)d_in[2];
  const float* wv = (const float*)d_in[3];
  const float* wo = (const float*)d_in[4];
  float* out = (float*)d_out;
  char* ws = (char*)d_ws;
  const size_t MiB = 1024 * 1024;
  ushort* xb  = (ushort*)(ws + 0);
  ushort* wqb = (ushort*)(ws + 8 * MiB);
  ushort* wkb = (ushort*)(ws + 10 * MiB);
  ushort* wvb = (ushort*)(ws + 12 * MiB);
  ushort* wob = (ushort*)(ws + 14 * MiB);
  ushort* Qb  = (ushort*)(ws + 16 * MiB);
  ushort* Kb  = (ushort*)(ws + 24 * MiB);
  ushort* Vtb = (ushort*)(ws + 32 * MiB);
  ushort* Ob  = (ushort*)(ws + 40 * MiB);

  cvt_all_k<<<8192, 256, 0, stream>>>(x, wq, wk, wv, wo, xb);
  dim3 gqkv(32, 8, 3);
  gemm_qkv_k<<<gqkv, 256, 0, stream>>>(xb, wqb, wkb, wvb, Qb, Kb, Vtb);
  rope_k<<<8192, 256, 0, stream>>>(Qb, Kb);
  attn_k<<<512, 512, 0, stream>>>(Qb, Kb, Vtb, Ob);
  dim3 gout(32, 8);
  gemm_out_k<<<gout, 256, 0, stream>>>(Ob, wob, out);
}

// Round 13
// 110.111 us; speedup vs baseline: 3.0442x; 1.0069x over previous
//
#include <hip/hip_runtime.h>
#include <hip/hip_bf16.h>
#include <stdint.h>

// ---------------------------------------------------------------------------
// MHA block: out = softmax( rope(xWq^T) rope(xWk^T)^T / 8 ) (xWv^T) Wo^T
// B=2 S=2048 H=16 D=64 DIM=1024.  bf16 MFMA compute, fp32 accum/softmax.
// ---------------------------------------------------------------------------

#define AS1(p) ((const __attribute__((address_space(1))) void*)(p))
#define AS3(p) ((__attribute__((address_space(3))) void*)(p))

typedef __attribute__((ext_vector_type(8)))  __bf16 bf16x8;
typedef __attribute__((ext_vector_type(4)))  float  f32x4;
typedef __attribute__((ext_vector_type(16))) float  f32x16;

__device__ __forceinline__ ushort f2b(float f) {
  union { float f; uint32_t u; } v; v.f = f;
  uint32_t u = v.u;
  u += 0x7fffu + ((u >> 16) & 1);   // RNE
  return (ushort)(u >> 16);
}
__device__ __forceinline__ float b2f(ushort s) {
  union { uint32_t u; float f; } v; v.u = ((uint32_t)s) << 16;
  return v.f;
}
__device__ __forceinline__ uint32_t pkbf16(float lo, float hi) {
  uint32_t w;
  asm("v_cvt_pk_bf16_f32 %0, %1, %2" : "=v"(w) : "v"(lo), "v"(hi));
  return w;
}
// Fast exp2 via native v_exp_f32.  R10 LESSON: raw inline-asm v_exp_f32 has
// a TRANS->VALU dependent-use hazard the compiler does NOT guard for asm.
// Prefer the builtin; asm fallback carries its own s_nop.
__device__ __forceinline__ float fast_exp2(float x) {
#if __has_builtin(__builtin_amdgcn_exp2f)
  return __builtin_amdgcn_exp2f(x);
#else
  float r;
  asm("v_exp_f32 %0, %1\n\ts_nop 1" : "=v"(r) : "v"(x));
  return r;
#endif
}

// ---------------------------------------------------------------------------
// 1) fp32 -> bf16 conversion of x and the four weights (contiguous in ws).
// ---------------------------------------------------------------------------
__global__ __launch_bounds__(256) void cvt_all_k(
    const float* __restrict__ x,  const float* __restrict__ wq,
    const float* __restrict__ wk, const float* __restrict__ wv,
    const float* __restrict__ wo, ushort* __restrict__ dst) {
  int i = blockIdx.x * 256 + threadIdx.x;          // 2,097,152 total
  const float* src;
  if      (i < 1048576) src = x  + (size_t)i * 4;
  else if (i < 1310720) src = wq + (size_t)(i - 1048576) * 4;
  else if (i < 1572864) src = wk + (size_t)(i - 1310720) * 4;
  else if (i < 1835008) src = wv + (size_t)(i - 1572864) * 4;
  else                  src = wo + (size_t)(i - 1835008) * 4;
  float4 v = *(const float4*)src;
  ushort4 o;
  o.x = f2b(v.x); o.y = f2b(v.y); o.z = f2b(v.z); o.w = f2b(v.w);
  ((ushort4*)dst)[i] = o;
}

// ---------------------------------------------------------------------------
// 2) GEMM mainloop: C = A(MxK) * W(NxK)^T, 128x128 tile, BK=32, 4 waves (2x2).
//    Double-buffered LDS, single barrier per K-step (stage(next) || compute).
// ---------------------------------------------------------------------------
__device__ __forceinline__ void gemm_mainloop(
    const ushort* __restrict__ A, const ushort* __restrict__ W,
    int row0, int col0, ushort* lds, f32x4 acc[4][4]) {
  const int K = 1024;
  int tid = threadIdx.x;
  int lane = tid & 63, wid = tid >> 6;
  int wr = wid >> 1, wc = wid & 1;
  int lr = lane >> 4, lc = lane & 15;
  ushort* lA = lds;
  ushort* lB = lds + 8192;

  auto stage = [&](int buf, int k0) {
#pragma unroll
    for (int i = 0; i < 2; i++) {
      int idx = tid + i * 256;                       // 16B chunk id, 4 per row
      const ushort* ga = A + (size_t)(row0 + (idx >> 2)) * K + k0 + (idx & 3) * 8;
      __builtin_amdgcn_global_load_lds(AS1(ga),
          AS3(lA + buf * 4096 + (i * 256 + wid * 64) * 8), 16, 0, 0);
      const ushort* gb = W + (size_t)(col0 + (idx >> 2)) * K + k0 + (idx & 3) * 8;
      __builtin_amdgcn_global_load_lds(AS1(gb),
          AS3(lB + buf * 4096 + (i * 256 + wid * 64) * 8), 16, 0, 0);
    }
  };

  stage(0, 0);
  __syncthreads();
  int cur = 0;
  for (int k0 = 0; k0 < K; k0 += 32) {
    if (k0 + 32 < K) stage(cur ^ 1, k0 + 32);
    const ushort* a  = lA + cur * 4096;
    const ushort* bm = lB + cur * 4096;
    bf16x8 af[4], bfr[4];
#pragma unroll
    for (int m = 0; m < 4; m++)
      af[m] = *(const bf16x8*)(a + (wr * 64 + m * 16 + lc) * 32 + lr * 8);
#pragma unroll
    for (int n = 0; n < 4; n++)
      bfr[n] = *(const bf16x8*)(bm + (wc * 64 + n * 16 + lc) * 32 + lr * 8);
#pragma unroll
    for (int m = 0; m < 4; m++)
#pragma unroll
      for (int n = 0; n < 4; n++)
        acc[m][n] = __builtin_amdgcn_mfma_f32_16x16x32_bf16(af[m], bfr[n], acc[m][n], 0, 0, 0);
    __syncthreads();     // drains: my ds_reads + next-buffer gload_lds writes
    cur ^= 1;
  }
}

// QKV projections in one launch (z = 0:Q, 1:K, 2:V).
// Q,K -> [B,H,S,D]; V -> [B,H,D,S] via XOR-swizzled LDS transpose.
__global__ __launch_bounds__(256) void gemm_qkv_k(
    const ushort* __restrict__ xb,
    const ushort* __restrict__ wqb, const ushort* __restrict__ wkb,
    const ushort* __restrict__ wvb,
    ushort* __restrict__ Qb, ushort* __restrict__ Kb, ushort* __restrict__ Vtb) {
  __shared__ ushort lds[16384];        // 32 KiB: dbuf staging, then V scratch
  int z = blockIdx.z;
  const ushort* w = (z == 0) ? wqb : (z == 1) ? wkb : wvb;
  int row0 = blockIdx.x * 128, col0 = blockIdx.y * 128;
  f32x4 acc[4][4] = {};
  gemm_mainloop(xb, w, row0, col0, lds, acc);

  int tid = threadIdx.x, lane = tid & 63, wid = tid >> 6;
  int wr = wid >> 1, wc = wid & 1, lr = lane >> 4, lc = lane & 15;

  if (z < 2) {
    ushort* dst = (z == 0) ? Qb : Kb;
#pragma unroll
    for (int m = 0; m < 4; m++)
#pragma unroll
      for (int n = 0; n < 4; n++)
#pragma unroll
        for (int j = 0; j < 4; j++) {
          int i = row0 + wr * 64 + m * 16 + lr * 4 + j;   // row: b,s
          int c = col0 + wc * 64 + n * 16 + lc;           // col: h,d
          int b = i >> 11, s = i & 2047, h = c >> 6, d = c & 63;
          dst[(size_t)(b * 16 + h) * 131072 + (size_t)s * 64 + d] = f2b(acc[m][n][j]);
        }
  } else {
    // V: transpose 128x128 tile through LDS (free after final barrier).
#pragma unroll
    for (int m = 0; m < 4; m++)
#pragma unroll
      for (int n = 0; n < 4; n++) {
        int c = wc * 64 + n * 16 + lc;
        int sb = wr * 64 + m * 16 + lr * 4;            // j=0..3 consecutive
        uint32_t w0 = pkbf16(acc[m][n][0], acc[m][n][1]);
        uint32_t w1 = pkbf16(acc[m][n][2], acc[m][n][3]);
        int soff = sb ^ ((c & 7) << 3);                // multiple of 4 ushorts
        uint2 val; val.x = w0; val.y = w1;
        *(uint2*)(lds + c * 128 + soff) = val;         // 8B store
      }
    __syncthreads();
    int b = row0 >> 11, srow = row0 & 2047;
#pragma unroll
    for (int i = 0; i < 8; i++) {
      int idx = i * 256 + tid;                 // 2048 16B chunks
      int cl = idx >> 4, sc = idx & 15;
      int soff = (sc * 8) ^ ((cl & 7) << 3);
      bf16x8 v = *(const bf16x8*)(lds + cl * 128 + soff);
      int cg = col0 + cl, h = cg >> 6, d = cg & 63;
      *(bf16x8*)(Vtb + (size_t)(b * 16 + h) * 131072 + (size_t)d * 2048 + srow + sc * 8) = v;
    }
  }
}

// Final projection: out(fp32) = attn @ Wo^T.
__global__ __launch_bounds__(256) void gemm_out_k(
    const ushort* __restrict__ Ab, const ushort* __restrict__ wob,
    float* __restrict__ out) {
  __shared__ ushort lds[16384];
  int row0 = blockIdx.x * 128, col0 = blockIdx.y * 128;
  f32x4 acc[4][4] = {};
  gemm_mainloop(Ab, wob, row0, col0, lds, acc);

  int tid = threadIdx.x, lane = tid & 63, wid = tid >> 6;
  int wr = wid >> 1, wc = wid & 1, lr = lane >> 4, lc = lane & 15;
#pragma unroll
  for (int m = 0; m < 4; m++)
#pragma unroll
    for (int n = 0; n < 4; n++)
#pragma unroll
      for (int j = 0; j < 4; j++) {
        int i = row0 + wr * 64 + m * 16 + lr * 4 + j;
        int c = col0 + wc * 64 + n * 16 + lc;
        out[(size_t)i * 1024 + c] = acc[m][n][j];
      }
}

// ---------------------------------------------------------------------------
// 3) RoPE in place on Q,K.  Q additionally folded-scaled by 0.125*log2(e)
//    so attention scores are natively in exp2 domain.
// ---------------------------------------------------------------------------
__global__ __launch_bounds__(256) void rope_k(ushort* __restrict__ Qb,
                                              ushort* __restrict__ Kb) {
  const float QSCL = 0.125f * 1.44269504088896f;
  int idx = blockIdx.x * 256 + threadIdx.x;   // 32*2048*32 = 2,097,152
  int dp = idx & 31;
  int s  = (idx >> 5) & 2047;
  int bh = idx >> 16;
  float inv = exp2f((float)dp * (-13.2877123795494f / 32.0f));
  float ang = (float)s * inv;
  float sn, cs;
  sincosf(ang, &sn, &cs);
  size_t off = (size_t)bh * 131072 + (size_t)s * 64 + dp;
  float q1 = b2f(Qb[off]), q2 = b2f(Qb[off + 32]);
  Qb[off]      = f2b((q1 * cs - q2 * sn) * QSCL);
  Qb[off + 32] = f2b((q2 * cs + q1 * sn) * QSCL);
  float k1 = b2f(Kb[off]), k2 = b2f(Kb[off + 32]);
  Kb[off]      = f2b(k1 * cs - k2 * sn);
  Kb[off + 32] = f2b(k2 * cs + k1 * sn);
}

// ---------------------------------------------------------------------------
// 4) Flash attention, 32x32 swapped-QK + within-block KV-split + T4
//    COUNTED-VMCNT pipeline.  512 threads = 8 waves: wave w -> q-subtile
//    (w&3), kv-half (w>>2).  2-ahead prefetch; per iter:
//      vmcnt(4)  -- waits pair-p loads (issued TWO iters ago); pair-(p+1)'s
//                   4 loads stay in flight across the barrier (T4: never
//                   drain to 0 in the main loop)
//      s_barrier -- all waves' pair-p tile writes now visible
//      compute   -- ds_read+MFMA+softmax (lgkmcnt waits precede MFMAs)
//      s_barrier -- all waves done READING buf (WAR guard)
//      stage(p+2) into the buffer just freed
//    Barriers are raw (no vmcnt drain); asm volatile + "memory" pins order.
// ---------------------------------------------------------------------------
__global__ __launch_bounds__(512, 4) void attn_k(
    const ushort* __restrict__ Qb, const ushort* __restrict__ Kb,
    const ushort* __restrict__ Vtb, ushort* __restrict__ Ob) {
  __shared__ char ldsb[65536];   // [buf:2][tile:2][K 8KB | V 8KB]; reused
  int tid = threadIdx.x, lane = tid & 63, wid = tid >> 6;   // wid in [0,8)
  int lc5 = lane & 31, hi = lane >> 5;
  int qsub = wid & 3, grp = wid >> 2;

  // XCD swizzle: all q-tiles of a head on one XCD
  int bid = blockIdx.x;
  int qt = (bid >> 3) & 15;
  int bh = (bid & 7) + ((bid >> 7) << 3);
  int q0 = qt * 128 + qsub * 32;
  const ushort* Qp = Qb  + (size_t)bh * 131072 + (size_t)q0 * 64;
  const ushort* Kp = Kb  + (size_t)bh * 131072;
  const ushort* Vp = Vtb + (size_t)bh * 131072;

  // Q as B-operand: col = q = lc5, k-dim = d: slice ks -> d = ks*16+8*hi+i
  bf16x8 qf[4];
#pragma unroll
  for (int ks = 0; ks < 4; ks++)
    qf[ks] = *(const bf16x8*)(Qp + lc5 * 64 + ks * 16 + hi * 8);

  f32x16 o0, o1;
#pragma unroll
  for (int i = 0; i < 16; i++) { o0[i] = 0.f; o1[i] = 0.f; }
  float lsum = 0.f;

  // swizzled in-row chunk offsets: chunk(ks) = (2ks+hi) ^ (row&7), row&7=lc5&7
  int swz[4];
#pragma unroll
  for (int ks = 0; ks < 4; ks++)
    swz[ks] = (((2 * ks + hi) ^ (lc5 & 7)) << 4);
  const int rbase = lc5 * 128;

  // stage the 128-key pair [kvp, kvp+128) into buf: tile t = keys
  // [kvp+64t, kvp+64t+64).  4 gload_lds per thread per call.
  auto stage = [&](int buf, int kvp) {
    int r = tid >> 3, cp = tid & 7;
    int ubase = wid * 1024;
#pragma unroll
    for (int t = 0; t < 2; t++) {
      char* tb = ldsb + buf * 32768 + t * 16384;
      const ushort* gk = Kp + (size_t)(kvp + 64 * t + r) * 64 + ((cp ^ (r & 7)) << 3);
      __builtin_amdgcn_global_load_lds(AS1(gk), AS3(tb + ubase), 16, 0, 0);
      const ushort* gv = Vp + (size_t)r * 2048 + kvp + 64 * t + ((cp ^ (r & 7)) << 3);
      __builtin_amdgcn_global_load_lds(AS1(gv), AS3(tb + 8192 + ubase), 16, 0, 0);
    }
  };

  stage(0, 0);      // pair 0 -> buf 0   (4 loads)
  stage(1, 128);    // pair 1 -> buf 1   (4 loads)
  int cur = 0;

  for (int kvp = 0; kvp < 2048; kvp += 128) {
    // wait MY pair-p loads (oldest 4); keep pair-(p+1)'s 4 in flight
    if (kvp + 128 < 2048) asm volatile("s_waitcnt vmcnt(4)" ::: "memory");
    else                  asm volatile("s_waitcnt vmcnt(0)" ::: "memory");
    asm volatile("s_barrier" ::: "memory");   // pair-p writes visible block-wide

    const char* kbuf = ldsb + cur * 32768 + grp * 16384;   // my tile
    const char* vbuf = kbuf + 8192;

    // QK^T for my 64 keys; col = own q
    f32x16 s0 = {}, s1 = {};
    __builtin_amdgcn_s_setprio(1);
#pragma unroll
    for (int ks = 0; ks < 4; ks++) {
      bf16x8 ka0 = *(const bf16x8*)(kbuf + rbase + swz[ks]);
      bf16x8 ka1 = *(const bf16x8*)(kbuf + 4096 + rbase + swz[ks]);
      s0 = __builtin_amdgcn_mfma_f32_32x32x16_bf16(ka0, qf[ks], s0, 0, 0, 0);
      s1 = __builtin_amdgcn_mfma_f32_32x32x16_bf16(ka1, qf[ks], s1, 0, 0, 0);
    }
    __builtin_amdgcn_s_setprio(0);

    // P = exp2(s_raw) (common scale cancels in final divide); scalar row-sum
#pragma unroll
    for (int i = 0; i < 16; i++) {
      s0[i] = fast_exp2(s0[i]);
      s1[i] = fast_exp2(s1[i]);
    }
    float acc = 0.f;
#pragma unroll
    for (int i = 0; i < 16; i++) acc += s0[i] + s1[i];
    lsum += acc;

    // P -> PV A-frags: 16 cvt_pk + 8 permlane32_swap (T12)
    bf16x8 a[4];
#pragma unroll
    for (int t = 0; t < 2; t++) {
      const f32x16& s = t ? s1 : s0;
#pragma unroll
      for (int h2 = 0; h2 < 2; h2++) {
        int rb = 8 * h2;
        uint32_t wa1 = pkbf16(s[rb],     s[rb + 1]);
        uint32_t wb1 = pkbf16(s[rb + 4], s[rb + 5]);
        asm("v_permlane32_swap_b32 %0, %1" : "+v"(wa1), "+v"(wb1));
        uint32_t wa2 = pkbf16(s[rb + 2], s[rb + 3]);
        uint32_t wb2 = pkbf16(s[rb + 6], s[rb + 7]);
        asm("v_permlane32_swap_b32 %0, %1" : "+v"(wa2), "+v"(wb2));
        union { uint32_t u[4]; bf16x8 v; } tmp;
        tmp.u[0] = wa1; tmp.u[1] = wa2; tmp.u[2] = wb1; tmp.u[3] = wb2;
        a[t * 2 + h2] = tmp.v;
      }
    }

    // PV: B = V^T rows = d, k-dim = keys
    __builtin_amdgcn_s_setprio(1);
#pragma unroll
    for (int ks = 0; ks < 4; ks++) {
      bf16x8 vb0 = *(const bf16x8*)(vbuf + rbase + swz[ks]);
      bf16x8 vb1 = *(const bf16x8*)(vbuf + 4096 + rbase + swz[ks]);
      o0 = __builtin_amdgcn_mfma_f32_32x32x16_bf16(a[ks], vb0, o0, 0, 0, 0);
      o1 = __builtin_amdgcn_mfma_f32_32x32x16_bf16(a[ks], vb1, o1, 0, 0, 0);
    }
    __builtin_amdgcn_s_setprio(0);

    asm volatile("s_barrier" ::: "memory");   // all waves done reading buf cur
    if (kvp + 256 < 2048) stage(cur, kvp + 256);   // overwrite freed buffer
    cur ^= 1;
  }

  // combine the two kv-halves: group 1 writes partials, group 0 adds.
  // stride 33 floats (odd) -> conflict-free.  ldsb free: vmcnt drained at
  // last iter, all reads done at its trailing barrier.
  float* cb = (float*)ldsb;
  float* p = cb + (size_t)(qsub * 64 + lane) * 33;
  if (grp == 1) {
#pragma unroll
    for (int i = 0; i < 16; i++) { p[i] = o0[i]; p[16 + i] = o1[i]; }
    p[32] = lsum;
  }
  __syncthreads();
  if (grp == 0) {
#pragma unroll
    for (int i = 0; i < 16; i++) { o0[i] += p[i]; o1[i] += p[16 + i]; }
    lsum += p[32];

    // combine the two key-halves of lsum (lanes q and q+32), then normalize
    lsum += __shfl_xor(lsum, 32);
    float invq = 1.0f / lsum;
    float invr[16];
#pragma unroll
    for (int r = 0; r < 16; r++)
      invr[r] = __shfl(invq, (r & 3) + 8 * (r >> 2) + 4 * hi);

    int b = bh >> 4, h = bh & 15;
    ushort* Op = Ob + (size_t)(b * 2048 + q0) * 1024 + h * 64 + lc5;
#pragma unroll
    for (int r = 0; r < 16; r++) {
      int rrow = (r & 3) + 8 * (r >> 2) + 4 * hi;
      Op[(size_t)rrow * 1024]      = f2b(o0[r] * invr[r]);
      Op[(size_t)rrow * 1024 + 32] = f2b(o1[r] * invr[r]);
    }
  }
}

// ---------------------------------------------------------------------------
// Workspace layout: xb 8M | wqb/wkb/wvb/wob 2M each | Qb 8M | Kb 8M | Vtb 8M
// | Ob 8M  (total 48 MiB)
// ---------------------------------------------------------------------------
extern "C" void kernel_launch(void* const* d_in, const int* in_sizes, int n_in,
                              void* d_out, int out_size, void* d_ws, size_t ws_size,
                              hipStream_t stream) {
  const float* x  = (const float*)d_in[0];
  const float* wq = (const float*)d_in[1];
  const float* wk = (const float*)d_in[2];
  const float* wv = (const float*)d_in[3];
  const float* wo = (const float*)d_in[4];
  float* out = (float*)d_out;
  char* ws = (char*)d_ws;
  const size_t MiB = 1024 * 1024;
  ushort* xb  = (ushort*)(ws + 0);
  ushort* wqb = (ushort*)(ws + 8 * MiB);
  ushort* wkb = (ushort*)(ws + 10 * MiB);
  ushort* wvb = (ushort*)(ws + 12 * MiB);
  ushort* wob = (ushort*)(ws + 14 * MiB);
  ushort* Qb  = (ushort*)(ws + 16 * MiB);
  ushort* Kb  = (ushort*)(ws + 24 * MiB);
  ushort* Vtb = (ushort*)(ws + 32 * MiB);
  ushort* Ob  = (ushort*)(ws + 40 * MiB);

  cvt_all_k<<<8192, 256, 0, stream>>>(x, wq, wk, wv, wo, xb);
  dim3 gqkv(32, 8, 3);
  gemm_qkv_k<<<gqkv, 256, 0, stream>>>(xb, wqb, wkb, wvb, Qb, Kb, Vtb);
  rope_k<<<8192, 256, 0, stream>>>(Qb, Kb);
  attn_k<<<512, 512, 0, stream>>>(Qb, Kb, Vtb, Ob);
  dim3 gout(32, 8);
  gemm_out_k<<<gout, 256, 0, stream>>>(Ob, wob, out);
}

// Round 14
// 103.879 us; speedup vs baseline: 3.2269x; 1.0600x over previous
//
#include <hip/hip_runtime.h>
#include <hip/hip_bf16.h>
#include <stdint.h>

// ---------------------------------------------------------------------------
// MHA block: out = softmax( rope(xWq^T) rope(xWk^T)^T / 8 ) (xWv^T) Wo^T
// B=2 S=2048 H=16 D=64 DIM=1024.  bf16 MFMA compute, fp32 accum/softmax.
// ---------------------------------------------------------------------------

#define AS1(p) ((const __attribute__((address_space(1))) void*)(p))
#define AS3(p) ((__attribute__((address_space(3))) void*)(p))

typedef __attribute__((ext_vector_type(8)))  __bf16 bf16x8;
typedef __attribute__((ext_vector_type(4)))  float  f32x4;
typedef __attribute__((ext_vector_type(16))) float  f32x16;

__device__ __forceinline__ ushort f2b(float f) {
  union { float f; uint32_t u; } v; v.f = f;
  uint32_t u = v.u;
  u += 0x7fffu + ((u >> 16) & 1);   // RNE
  return (ushort)(u >> 16);
}
__device__ __forceinline__ float b2f(ushort s) {
  union { uint32_t u; float f; } v; v.u = ((uint32_t)s) << 16;
  return v.f;
}
__device__ __forceinline__ uint32_t pkbf16(float lo, float hi) {
  uint32_t w;
  asm("v_cvt_pk_bf16_f32 %0, %1, %2" : "=v"(w) : "v"(lo), "v"(hi));
  return w;
}
// Fast exp2 via native v_exp_f32.  R10 LESSON: raw inline-asm v_exp_f32 has
// a TRANS->VALU dependent-use hazard the compiler does NOT guard for asm.
// Prefer the builtin; asm fallback carries its own s_nop.
__device__ __forceinline__ float fast_exp2(float x) {
#if __has_builtin(__builtin_amdgcn_exp2f)
  return __builtin_amdgcn_exp2f(x);
#else
  float r;
  asm("v_exp_f32 %0, %1\n\ts_nop 1" : "=v"(r) : "v"(x));
  return r;
#endif
}

// ---------------------------------------------------------------------------
// 1) fp32 -> bf16 conversion of x and the four weights; ALSO generates the
//    RoPE cos/sin table (2048 x 32 float2, 512 KB) used by gemm_qkv's fused
//    rope epilogue.  Table lives in the Ob region (dead until attn runs).
// ---------------------------------------------------------------------------
__global__ __launch_bounds__(256) void cvt_all_k(
    const float* __restrict__ x,  const float* __restrict__ wq,
    const float* __restrict__ wk, const float* __restrict__ wv,
    const float* __restrict__ wo, ushort* __restrict__ dst,
    float2* __restrict__ tab) {
  int i = blockIdx.x * 256 + threadIdx.x;          // 2,097,152 total
  const float* src;
  if      (i < 1048576) src = x  + (size_t)i * 4;
  else if (i < 1310720) src = wq + (size_t)(i - 1048576) * 4;
  else if (i < 1572864) src = wk + (size_t)(i - 1310720) * 4;
  else if (i < 1835008) src = wv + (size_t)(i - 1572864) * 4;
  else                  src = wo + (size_t)(i - 1835008) * 4;
  float4 v = *(const float4*)src;
  ushort4 o;
  o.x = f2b(v.x); o.y = f2b(v.y); o.z = f2b(v.z); o.w = f2b(v.w);
  ((ushort4*)dst)[i] = o;

  if (i < 65536) {                                 // rope table: s x dp
    int s = i >> 5, dp = i & 31;
    float inv = exp2f((float)dp * (-13.2877123795494f / 32.0f));
    float ang = (float)s * inv;
    float sn, cs;
    sincosf(ang, &sn, &cs);
    tab[i] = make_float2(cs, sn);
  }
}

// ---------------------------------------------------------------------------
// 2) GEMM mainloop: C = A(MxK) * W(NxK)^T, 128x128 tile, BK=32, 4 waves (2x2).
//    Double-buffered LDS, single barrier per K-step (stage(next) || compute).
// ---------------------------------------------------------------------------
__device__ __forceinline__ void gemm_mainloop(
    const ushort* __restrict__ A, const ushort* __restrict__ W,
    int row0, int col0, ushort* lds, f32x4 acc[4][4]) {
  const int K = 1024;
  int tid = threadIdx.x;
  int lane = tid & 63, wid = tid >> 6;
  int wr = wid >> 1, wc = wid & 1;
  int lr = lane >> 4, lc = lane & 15;
  ushort* lA = lds;
  ushort* lB = lds + 8192;

  auto stage = [&](int buf, int k0) {
#pragma unroll
    for (int i = 0; i < 2; i++) {
      int idx = tid + i * 256;                       // 16B chunk id, 4 per row
      const ushort* ga = A + (size_t)(row0 + (idx >> 2)) * K + k0 + (idx & 3) * 8;
      __builtin_amdgcn_global_load_lds(AS1(ga),
          AS3(lA + buf * 4096 + (i * 256 + wid * 64) * 8), 16, 0, 0);
      const ushort* gb = W + (size_t)(col0 + (idx >> 2)) * K + k0 + (idx & 3) * 8;
      __builtin_amdgcn_global_load_lds(AS1(gb),
          AS3(lB + buf * 4096 + (i * 256 + wid * 64) * 8), 16, 0, 0);
    }
  };

  stage(0, 0);
  __syncthreads();
  int cur = 0;
  for (int k0 = 0; k0 < K; k0 += 32) {
    if (k0 + 32 < K) stage(cur ^ 1, k0 + 32);
    const ushort* a  = lA + cur * 4096;
    const ushort* bm = lB + cur * 4096;
    bf16x8 af[4], bfr[4];
#pragma unroll
    for (int m = 0; m < 4; m++)
      af[m] = *(const bf16x8*)(a + (wr * 64 + m * 16 + lc) * 32 + lr * 8);
#pragma unroll
    for (int n = 0; n < 4; n++)
      bfr[n] = *(const bf16x8*)(bm + (wc * 64 + n * 16 + lc) * 32 + lr * 8);
#pragma unroll
    for (int m = 0; m < 4; m++)
#pragma unroll
      for (int n = 0; n < 4; n++)
        acc[m][n] = __builtin_amdgcn_mfma_f32_16x16x32_bf16(af[m], bfr[n], acc[m][n], 0, 0, 0);
    __syncthreads();     // drains: my ds_reads + next-buffer gload_lds writes
    cur ^= 1;
  }
}

// QKV projections in one launch (z = 0:Q, 1:K, 2:V).
// Q,K -> [B,H,S,D] with FUSED ROPE (rotation pair (d, d+32) lives in the
// same thread: acc[m][n] and acc[m][n+2] for n<2); Q scaled by 0.125*log2e
// so attention scores are natively exp2-domain.  cos/sin from tab (L2).
// V -> [B,H,D,S] via XOR-swizzled LDS transpose.
__global__ __launch_bounds__(256) void gemm_qkv_k(
    const ushort* __restrict__ xb,
    const ushort* __restrict__ wqb, const ushort* __restrict__ wkb,
    const ushort* __restrict__ wvb,
    const float2* __restrict__ tab,
    ushort* __restrict__ Qb, ushort* __restrict__ Kb, ushort* __restrict__ Vtb) {
  __shared__ ushort lds[16384];        // 32 KiB: dbuf staging, then V scratch
  int z = blockIdx.z;
  const ushort* w = (z == 0) ? wqb : (z == 1) ? wkb : wvb;
  int row0 = blockIdx.x * 128, col0 = blockIdx.y * 128;
  f32x4 acc[4][4] = {};
  gemm_mainloop(xb, w, row0, col0, lds, acc);

  int tid = threadIdx.x, lane = tid & 63, wid = tid >> 6;
  int wr = wid >> 1, wc = wid & 1, lr = lane >> 4, lc = lane & 15;

  if (z < 2) {
    ushort* dst = (z == 0) ? Qb : Kb;
    const float qs = (z == 0) ? 0.125f * 1.44269504088896f : 1.0f;
#pragma unroll
    for (int m = 0; m < 4; m++)
#pragma unroll
      for (int n = 0; n < 2; n++)
#pragma unroll
        for (int j = 0; j < 4; j++) {
          int i = row0 + wr * 64 + m * 16 + lr * 4 + j;   // row: b,s
          int c = col0 + wc * 64 + n * 16 + lc;           // col: h,d (d<32)
          int b = i >> 11, s = i & 2047, h = c >> 6, dp = c & 31;
          float2 cs = tab[s * 32 + dp];
          float q1 = acc[m][n][j], q2 = acc[m][n + 2][j];
          float r1 = (q1 * cs.x - q2 * cs.y) * qs;
          float r2 = (q2 * cs.x + q1 * cs.y) * qs;
          size_t base = (size_t)(b * 16 + h) * 131072 + (size_t)s * 64;
          dst[base + dp]      = f2b(r1);
          dst[base + dp + 32] = f2b(r2);
        }
  } else {
    // V: transpose 128x128 tile through LDS (free after final barrier).
#pragma unroll
    for (int m = 0; m < 4; m++)
#pragma unroll
      for (int n = 0; n < 4; n++) {
        int c = wc * 64 + n * 16 + lc;
        int sb = wr * 64 + m * 16 + lr * 4;            // j=0..3 consecutive
        uint32_t w0 = pkbf16(acc[m][n][0], acc[m][n][1]);
        uint32_t w1 = pkbf16(acc[m][n][2], acc[m][n][3]);
        int soff = sb ^ ((c & 7) << 3);                // multiple of 4 ushorts
        uint2 val; val.x = w0; val.y = w1;
        *(uint2*)(lds + c * 128 + soff) = val;         // 8B store
      }
    __syncthreads();
    int b = row0 >> 11, srow = row0 & 2047;
#pragma unroll
    for (int i = 0; i < 8; i++) {
      int idx = i * 256 + tid;                 // 2048 16B chunks
      int cl = idx >> 4, sc = idx & 15;
      int soff = (sc * 8) ^ ((cl & 7) << 3);
      bf16x8 v = *(const bf16x8*)(lds + cl * 128 + soff);
      int cg = col0 + cl, h = cg >> 6, d = cg & 63;
      *(bf16x8*)(Vtb + (size_t)(b * 16 + h) * 131072 + (size_t)d * 2048 + srow + sc * 8) = v;
    }
  }
}

// Final projection: out(fp32) = attn @ Wo^T.
__global__ __launch_bounds__(256) void gemm_out_k(
    const ushort* __restrict__ Ab, const ushort* __restrict__ wob,
    float* __restrict__ out) {
  __shared__ ushort lds[16384];
  int row0 = blockIdx.x * 128, col0 = blockIdx.y * 128;
  f32x4 acc[4][4] = {};
  gemm_mainloop(Ab, wob, row0, col0, lds, acc);

  int tid = threadIdx.x, lane = tid & 63, wid = tid >> 6;
  int wr = wid >> 1, wc = wid & 1, lr = lane >> 4, lc = lane & 15;
#pragma unroll
  for (int m = 0; m < 4; m++)
#pragma unroll
    for (int n = 0; n < 4; n++)
#pragma unroll
      for (int j = 0; j < 4; j++) {
        int i = row0 + wr * 64 + m * 16 + lr * 4 + j;
        int c = col0 + wc * 64 + n * 16 + lc;
        out[(size_t)i * 1024 + c] = acc[m][n][j];
      }
}

// ---------------------------------------------------------------------------
// 3) Flash attention, 32x32 swapped-QK + within-block KV-split + counted
//    vmcnt pipeline (unchanged from R13).
// ---------------------------------------------------------------------------
__global__ __launch_bounds__(512, 4) void attn_k(
    const ushort* __restrict__ Qb, const ushort* __restrict__ Kb,
    const ushort* __restrict__ Vtb, ushort* __restrict__ Ob) {
  __shared__ char ldsb[65536];   // [buf:2][tile:2][K 8KB | V 8KB]; reused
  int tid = threadIdx.x, lane = tid & 63, wid = tid >> 6;   // wid in [0,8)
  int lc5 = lane & 31, hi = lane >> 5;
  int qsub = wid & 3, grp = wid >> 2;

  // XCD swizzle: all q-tiles of a head on one XCD
  int bid = blockIdx.x;
  int qt = (bid >> 3) & 15;
  int bh = (bid & 7) + ((bid >> 7) << 3);
  int q0 = qt * 128 + qsub * 32;
  const ushort* Qp = Qb  + (size_t)bh * 131072 + (size_t)q0 * 64;
  const ushort* Kp = Kb  + (size_t)bh * 131072;
  const ushort* Vp = Vtb + (size_t)bh * 131072;

  // Q as B-operand: col = q = lc5, k-dim = d: slice ks -> d = ks*16+8*hi+i
  bf16x8 qf[4];
#pragma unroll
  for (int ks = 0; ks < 4; ks++)
    qf[ks] = *(const bf16x8*)(Qp + lc5 * 64 + ks * 16 + hi * 8);

  f32x16 o0, o1;
#pragma unroll
  for (int i = 0; i < 16; i++) { o0[i] = 0.f; o1[i] = 0.f; }
  float lsum = 0.f;

  // swizzled in-row chunk offsets: chunk(ks) = (2ks+hi) ^ (row&7), row&7=lc5&7
  int swz[4];
#pragma unroll
  for (int ks = 0; ks < 4; ks++)
    swz[ks] = (((2 * ks + hi) ^ (lc5 & 7)) << 4);
  const int rbase = lc5 * 128;

  // stage the 128-key pair [kvp, kvp+128) into buf: tile t = keys
  // [kvp+64t, kvp+64t+64).  4 gload_lds per thread per call.
  auto stage = [&](int buf, int kvp) {
    int r = tid >> 3, cp = tid & 7;
    int ubase = wid * 1024;
#pragma unroll
    for (int t = 0; t < 2; t++) {
      char* tb = ldsb + buf * 32768 + t * 16384;
      const ushort* gk = Kp + (size_t)(kvp + 64 * t + r) * 64 + ((cp ^ (r & 7)) << 3);
      __builtin_amdgcn_global_load_lds(AS1(gk), AS3(tb + ubase), 16, 0, 0);
      const ushort* gv = Vp + (size_t)r * 2048 + kvp + 64 * t + ((cp ^ (r & 7)) << 3);
      __builtin_amdgcn_global_load_lds(AS1(gv), AS3(tb + 8192 + ubase), 16, 0, 0);
    }
  };

  stage(0, 0);      // pair 0 -> buf 0   (4 loads)
  stage(1, 128);    // pair 1 -> buf 1   (4 loads)
  int cur = 0;

  for (int kvp = 0; kvp < 2048; kvp += 128) {
    // wait MY pair-p loads (oldest 4); keep pair-(p+1)'s 4 in flight
    if (kvp + 128 < 2048) asm volatile("s_waitcnt vmcnt(4)" ::: "memory");
    else                  asm volatile("s_waitcnt vmcnt(0)" ::: "memory");
    asm volatile("s_barrier" ::: "memory");   // pair-p writes visible block-wide

    const char* kbuf = ldsb + cur * 32768 + grp * 16384;   // my tile
    const char* vbuf = kbuf + 8192;

    // QK^T for my 64 keys; col = own q
    f32x16 s0 = {}, s1 = {};
    __builtin_amdgcn_s_setprio(1);
#pragma unroll
    for (int ks = 0; ks < 4; ks++) {
      bf16x8 ka0 = *(const bf16x8*)(kbuf + rbase + swz[ks]);
      bf16x8 ka1 = *(const bf16x8*)(kbuf + 4096 + rbase + swz[ks]);
      s0 = __builtin_amdgcn_mfma_f32_32x32x16_bf16(ka0, qf[ks], s0, 0, 0, 0);
      s1 = __builtin_amdgcn_mfma_f32_32x32x16_bf16(ka1, qf[ks], s1, 0, 0, 0);
    }
    __builtin_amdgcn_s_setprio(0);

    // P = exp2(s_raw) (common scale cancels in final divide); scalar row-sum
#pragma unroll
    for (int i = 0; i < 16; i++) {
      s0[i] = fast_exp2(s0[i]);
      s1[i] = fast_exp2(s1[i]);
    }
    float acc = 0.f;
#pragma unroll
    for (int i = 0; i < 16; i++) acc += s0[i] + s1[i];
    lsum += acc;

    // P -> PV A-frags: 16 cvt_pk + 8 permlane32_swap (T12)
    bf16x8 a[4];
#pragma unroll
    for (int t = 0; t < 2; t++) {
      const f32x16& s = t ? s1 : s0;
#pragma unroll
      for (int h2 = 0; h2 < 2; h2++) {
        int rb = 8 * h2;
        uint32_t wa1 = pkbf16(s[rb],     s[rb + 1]);
        uint32_t wb1 = pkbf16(s[rb + 4], s[rb + 5]);
        asm("v_permlane32_swap_b32 %0, %1" : "+v"(wa1), "+v"(wb1));
        uint32_t wa2 = pkbf16(s[rb + 2], s[rb + 3]);
        uint32_t wb2 = pkbf16(s[rb + 6], s[rb + 7]);
        asm("v_permlane32_swap_b32 %0, %1" : "+v"(wa2), "+v"(wb2));
        union { uint32_t u[4]; bf16x8 v; } tmp;
        tmp.u[0] = wa1; tmp.u[1] = wa2; tmp.u[2] = wb1; tmp.u[3] = wb2;
        a[t * 2 + h2] = tmp.v;
      }
    }

    // PV: B = V^T rows = d, k-dim = keys
    __builtin_amdgcn_s_setprio(1);
#pragma unroll
    for (int ks = 0; ks < 4; ks++) {
      bf16x8 vb0 = *(const bf16x8*)(vbuf + rbase + swz[ks]);
      bf16x8 vb1 = *(const bf16x8*)(vbuf + 4096 + rbase + swz[ks]);
      o0 = __builtin_amdgcn_mfma_f32_32x32x16_bf16(a[ks], vb0, o0, 0, 0, 0);
      o1 = __builtin_amdgcn_mfma_f32_32x32x16_bf16(a[ks], vb1, o1, 0, 0, 0);
    }
    __builtin_amdgcn_s_setprio(0);

    asm volatile("s_barrier" ::: "memory");   // all waves done reading buf cur
    if (kvp + 256 < 2048) stage(cur, kvp + 256);   // overwrite freed buffer
    cur ^= 1;
  }

  // combine the two kv-halves: group 1 writes partials, group 0 adds.
  // stride 33 floats (odd) -> conflict-free.  ldsb free: vmcnt drained at
  // last iter, all reads done at its trailing barrier.
  float* cb = (float*)ldsb;
  float* p = cb + (size_t)(qsub * 64 + lane) * 33;
  if (grp == 1) {
#pragma unroll
    for (int i = 0; i < 16; i++) { p[i] = o0[i]; p[16 + i] = o1[i]; }
    p[32] = lsum;
  }
  __syncthreads();
  if (grp == 0) {
#pragma unroll
    for (int i = 0; i < 16; i++) { o0[i] += p[i]; o1[i] += p[16 + i]; }
    lsum += p[32];

    // combine the two key-halves of lsum (lanes q and q+32), then normalize
    lsum += __shfl_xor(lsum, 32);
    float invq = 1.0f / lsum;
    float invr[16];
#pragma unroll
    for (int r = 0; r < 16; r++)
      invr[r] = __shfl(invq, (r & 3) + 8 * (r >> 2) + 4 * hi);

    int b = bh >> 4, h = bh & 15;
    ushort* Op = Ob + (size_t)(b * 2048 + q0) * 1024 + h * 64 + lc5;
#pragma unroll
    for (int r = 0; r < 16; r++) {
      int rrow = (r & 3) + 8 * (r >> 2) + 4 * hi;
      Op[(size_t)rrow * 1024]      = f2b(o0[r] * invr[r]);
      Op[(size_t)rrow * 1024 + 32] = f2b(o1[r] * invr[r]);
    }
  }
}

// ---------------------------------------------------------------------------
// Workspace layout: xb 8M | wqb/wkb/wvb/wob 2M each | Qb 8M | Kb 8M | Vtb 8M
// | Ob 8M  (total 48 MiB).  The rope cos/sin table (512 KB) borrows the
// head of the Ob region: alive only cvt->qkv; attn overwrites it later.
// ---------------------------------------------------------------------------
extern "C" void kernel_launch(void* const* d_in, const int* in_sizes, int n_in,
                              void* d_out, int out_size, void* d_ws, size_t ws_size,
                              hipStream_t stream) {
  const float* x  = (const float*)d_in[0];
  const float* wq = (const float*)d_in[1];
  const float* wk = (const float*)d_in[2];
  const float* wv = (const float*)d_in[3];
  const float* wo = (const float*)d_in[4];
  float* out = (float*)d_out;
  char* ws = (char*)d_ws;
  const size_t MiB = 1024 * 1024;
  ushort* xb  = (ushort*)(ws + 0);
  ushort* wqb = (ushort*)(ws + 8 * MiB);
  ushort* wkb = (ushort*)(ws + 10 * MiB);
  ushort* wvb = (ushort*)(ws + 12 * MiB);
  ushort* wob = (ushort*)(ws + 14 * MiB);
  ushort* Qb  = (ushort*)(ws + 16 * MiB);
  ushort* Kb  = (ushort*)(ws + 24 * MiB);
  ushort* Vtb = (ushort*)(ws + 32 * MiB);
  ushort* Ob  = (ushort*)(ws + 40 * MiB);
  float2* tab = (float2*)Ob;                 // 65536 * 8B = 512 KB, transient

  cvt_all_k<<<8192, 256, 0, stream>>>(x, wq, wk, wv, wo, xb, tab);
  dim3 gqkv(32, 8, 3);
  gemm_qkv_k<<<gqkv, 256, 0, stream>>>(xb, wqb, wkb, wvb, tab, Qb, Kb, Vtb);
  attn_k<<<512, 512, 0, stream>>>(Qb, Kb, Vtb, Ob);
  dim3 gout(32, 8);
  gemm_out_k<<<gout, 256, 0, stream>>>(Ob, wob, out);
}

// Round 15
// 103.728 us; speedup vs baseline: 3.2316x; 1.0015x over previous
//
#include <hip/hip_runtime.h>
#include <hip/hip_bf16.h>
#include <stdint.h>

// ---------------------------------------------------------------------------
// MHA block: out = softmax( rope(xWq^T) rope(xWk^T)^T / 8 ) (xWv^T) Wo^T
// B=2 S=2048 H=16 D=64 DIM=1024.  bf16 MFMA compute, fp32 accum/softmax.
// ---------------------------------------------------------------------------

#define AS1(p) ((const __attribute__((address_space(1))) void*)(p))
#define AS3(p) ((__attribute__((address_space(3))) void*)(p))

typedef __attribute__((ext_vector_type(8)))  __bf16 bf16x8;
typedef __attribute__((ext_vector_type(4)))  float  f32x4;
typedef __attribute__((ext_vector_type(16))) float  f32x16;

__device__ __forceinline__ ushort f2b(float f) {
  union { float f; uint32_t u; } v; v.f = f;
  uint32_t u = v.u;
  u += 0x7fffu + ((u >> 16) & 1);   // RNE
  return (ushort)(u >> 16);
}
__device__ __forceinline__ float b2f(ushort s) {
  union { uint32_t u; float f; } v; v.u = ((uint32_t)s) << 16;
  return v.f;
}
__device__ __forceinline__ uint32_t pkbf16(float lo, float hi) {
  uint32_t w;
  asm("v_cvt_pk_bf16_f32 %0, %1, %2" : "=v"(w) : "v"(lo), "v"(hi));
  return w;
}
// Fast exp2 via native v_exp_f32.  R10 LESSON: raw inline-asm v_exp_f32 has
// a TRANS->VALU dependent-use hazard the compiler does NOT guard for asm.
// Prefer the builtin; asm fallback carries its own s_nop.
__device__ __forceinline__ float fast_exp2(float x) {
#if __has_builtin(__builtin_amdgcn_exp2f)
  return __builtin_amdgcn_exp2f(x);
#else
  float r;
  asm("v_exp_f32 %0, %1\n\ts_nop 1" : "=v"(r) : "v"(x));
  return r;
#endif
}

// ---------------------------------------------------------------------------
// 1) fp32 -> bf16 conversion of x and the four weights; ALSO generates the
//    RoPE cos/sin table (2048 x 32 float2, 512 KB) used by gemm_qkv's fused
//    rope epilogue.  Table lives in the Ob region (dead until attn runs).
// ---------------------------------------------------------------------------
__global__ __launch_bounds__(256) void cvt_all_k(
    const float* __restrict__ x,  const float* __restrict__ wq,
    const float* __restrict__ wk, const float* __restrict__ wv,
    const float* __restrict__ wo, ushort* __restrict__ dst,
    float2* __restrict__ tab) {
  int i = blockIdx.x * 256 + threadIdx.x;          // 2,097,152 total
  const float* src;
  if      (i < 1048576) src = x  + (size_t)i * 4;
  else if (i < 1310720) src = wq + (size_t)(i - 1048576) * 4;
  else if (i < 1572864) src = wk + (size_t)(i - 1310720) * 4;
  else if (i < 1835008) src = wv + (size_t)(i - 1572864) * 4;
  else                  src = wo + (size_t)(i - 1835008) * 4;
  float4 v = *(const float4*)src;
  ushort4 o;
  o.x = f2b(v.x); o.y = f2b(v.y); o.z = f2b(v.z); o.w = f2b(v.w);
  ((ushort4*)dst)[i] = o;

  if (i < 65536) {                                 // rope table: s x dp
    int s = i >> 5, dp = i & 31;
    float inv = exp2f((float)dp * (-13.2877123795494f / 32.0f));
    float ang = (float)s * inv;
    float sn, cs;
    sincosf(ang, &sn, &cs);
    tab[i] = make_float2(cs, sn);
  }
}

// ---------------------------------------------------------------------------
// 2) GEMM mainloop: C = A(MxK) * W(NxK)^T, 128x128 tile, BK=32, 4 waves (2x2).
//    Double-buffered LDS, single barrier per K-step (stage(next) || compute).
// ---------------------------------------------------------------------------
__device__ __forceinline__ void gemm_mainloop(
    const ushort* __restrict__ A, const ushort* __restrict__ W,
    int row0, int col0, ushort* lds, f32x4 acc[4][4]) {
  const int K = 1024;
  int tid = threadIdx.x;
  int lane = tid & 63, wid = tid >> 6;
  int wr = wid >> 1, wc = wid & 1;
  int lr = lane >> 4, lc = lane & 15;
  ushort* lA = lds;
  ushort* lB = lds + 8192;

  auto stage = [&](int buf, int k0) {
#pragma unroll
    for (int i = 0; i < 2; i++) {
      int idx = tid + i * 256;                       // 16B chunk id, 4 per row
      const ushort* ga = A + (size_t)(row0 + (idx >> 2)) * K + k0 + (idx & 3) * 8;
      __builtin_amdgcn_global_load_lds(AS1(ga),
          AS3(lA + buf * 4096 + (i * 256 + wid * 64) * 8), 16, 0, 0);
      const ushort* gb = W + (size_t)(col0 + (idx >> 2)) * K + k0 + (idx & 3) * 8;
      __builtin_amdgcn_global_load_lds(AS1(gb),
          AS3(lB + buf * 4096 + (i * 256 + wid * 64) * 8), 16, 0, 0);
    }
  };

  stage(0, 0);
  __syncthreads();
  int cur = 0;
  for (int k0 = 0; k0 < K; k0 += 32) {
    if (k0 + 32 < K) stage(cur ^ 1, k0 + 32);
    const ushort* a  = lA + cur * 4096;
    const ushort* bm = lB + cur * 4096;
    bf16x8 af[4], bfr[4];
#pragma unroll
    for (int m = 0; m < 4; m++)
      af[m] = *(const bf16x8*)(a + (wr * 64 + m * 16 + lc) * 32 + lr * 8);
#pragma unroll
    for (int n = 0; n < 4; n++)
      bfr[n] = *(const bf16x8*)(bm + (wc * 64 + n * 16 + lc) * 32 + lr * 8);
#pragma unroll
    for (int m = 0; m < 4; m++)
#pragma unroll
      for (int n = 0; n < 4; n++)
        acc[m][n] = __builtin_amdgcn_mfma_f32_16x16x32_bf16(af[m], bfr[n], acc[m][n], 0, 0, 0);
    __syncthreads();     // drains: my ds_reads + next-buffer gload_lds writes
    cur ^= 1;
  }
}

// QKV projections in one launch (z = 0:Q, 1:K, 2:V).
// Q,K -> [B,H,S,D] with FUSED ROPE (rotation pair (d, d+32) lives in the
// same thread: acc[m][n] and acc[m][n+2] for n<2); Q scaled by 0.125*log2e
// so attention scores are natively exp2-domain.  cos/sin from tab (L2).
// V -> [B,H,D,S] via XOR-swizzled LDS transpose.
__global__ __launch_bounds__(256) void gemm_qkv_k(
    const ushort* __restrict__ xb,
    const ushort* __restrict__ wqb, const ushort* __restrict__ wkb,
    const ushort* __restrict__ wvb,
    const float2* __restrict__ tab,
    ushort* __restrict__ Qb, ushort* __restrict__ Kb, ushort* __restrict__ Vtb) {
  __shared__ ushort lds[16384];        // 32 KiB: dbuf staging, then V scratch
  int z = blockIdx.z;
  const ushort* w = (z == 0) ? wqb : (z == 1) ? wkb : wvb;
  int row0 = blockIdx.x * 128, col0 = blockIdx.y * 128;
  f32x4 acc[4][4] = {};
  gemm_mainloop(xb, w, row0, col0, lds, acc);

  int tid = threadIdx.x, lane = tid & 63, wid = tid >> 6;
  int wr = wid >> 1, wc = wid & 1, lr = lane >> 4, lc = lane & 15;

  if (z < 2) {
    ushort* dst = (z == 0) ? Qb : Kb;
    const float qs = (z == 0) ? 0.125f * 1.44269504088896f : 1.0f;
#pragma unroll
    for (int m = 0; m < 4; m++)
#pragma unroll
      for (int n = 0; n < 2; n++)
#pragma unroll
        for (int j = 0; j < 4; j++) {
          int i = row0 + wr * 64 + m * 16 + lr * 4 + j;   // row: b,s
          int c = col0 + wc * 64 + n * 16 + lc;           // col: h,d (d<32)
          int b = i >> 11, s = i & 2047, h = c >> 6, dp = c & 31;
          float2 cs = tab[s * 32 + dp];
          float q1 = acc[m][n][j], q2 = acc[m][n + 2][j];
          float r1 = (q1 * cs.x - q2 * cs.y) * qs;
          float r2 = (q2 * cs.x + q1 * cs.y) * qs;
          size_t base = (size_t)(b * 16 + h) * 131072 + (size_t)s * 64;
          dst[base + dp]      = f2b(r1);
          dst[base + dp + 32] = f2b(r2);
        }
  } else {
    // V: transpose 128x128 tile through LDS (free after final barrier).
#pragma unroll
    for (int m = 0; m < 4; m++)
#pragma unroll
      for (int n = 0; n < 4; n++) {
        int c = wc * 64 + n * 16 + lc;
        int sb = wr * 64 + m * 16 + lr * 4;            // j=0..3 consecutive
        uint32_t w0 = pkbf16(acc[m][n][0], acc[m][n][1]);
        uint32_t w1 = pkbf16(acc[m][n][2], acc[m][n][3]);
        int soff = sb ^ ((c & 7) << 3);                // multiple of 4 ushorts
        uint2 val; val.x = w0; val.y = w1;
        *(uint2*)(lds + c * 128 + soff) = val;         // 8B store
      }
    __syncthreads();
    int b = row0 >> 11, srow = row0 & 2047;
#pragma unroll
    for (int i = 0; i < 8; i++) {
      int idx = i * 256 + tid;                 // 2048 16B chunks
      int cl = idx >> 4, sc = idx & 15;
      int soff = (sc * 8) ^ ((cl & 7) << 3);
      bf16x8 v = *(const bf16x8*)(lds + cl * 128 + soff);
      int cg = col0 + cl, h = cg >> 6, d = cg & 63;
      *(bf16x8*)(Vtb + (size_t)(b * 16 + h) * 131072 + (size_t)d * 2048 + srow + sc * 8) = v;
    }
  }
}

// Final projection: out(fp32) = attn @ Wo^T.
__global__ __launch_bounds__(256) void gemm_out_k(
    const ushort* __restrict__ Ab, const ushort* __restrict__ wob,
    float* __restrict__ out) {
  __shared__ ushort lds[16384];
  int row0 = blockIdx.x * 128, col0 = blockIdx.y * 128;
  f32x4 acc[4][4] = {};
  gemm_mainloop(Ab, wob, row0, col0, lds, acc);

  int tid = threadIdx.x, lane = tid & 63, wid = tid >> 6;
  int wr = wid >> 1, wc = wid & 1, lr = lane >> 4, lc = lane & 15;
#pragma unroll
  for (int m = 0; m < 4; m++)
#pragma unroll
    for (int n = 0; n < 4; n++)
#pragma unroll
      for (int j = 0; j < 4; j++) {
        int i = row0 + wr * 64 + m * 16 + lr * 4 + j;
        int c = col0 + wc * 64 + n * 16 + lc;
        out[(size_t)i * 1024 + c] = acc[m][n][j];
      }
}

// ---------------------------------------------------------------------------
// 3) Flash attention, 32x32 swapped-QK + within-block KV-split + counted
//    vmcnt pipeline.  R15: T15-lite intra-iteration software pipeline --
//    QK-s0 chain, QK-s1 chain, softmax(s0) [VALU overlaps s1's MFMAs],
//    PV(ks=0,1) [MFMA overlaps softmax(s1)], softmax(s1), PV(ks=2,3).
//    Breaks the MFMA-burst/VALU-burst lockstep without touching sync.
// ---------------------------------------------------------------------------
__global__ __launch_bounds__(512, 4) void attn_k(
    const ushort* __restrict__ Qb, const ushort* __restrict__ Kb,
    const ushort* __restrict__ Vtb, ushort* __restrict__ Ob) {
  __shared__ char ldsb[65536];   // [buf:2][tile:2][K 8KB | V 8KB]; reused
  int tid = threadIdx.x, lane = tid & 63, wid = tid >> 6;   // wid in [0,8)
  int lc5 = lane & 31, hi = lane >> 5;
  int qsub = wid & 3, grp = wid >> 2;

  // XCD swizzle: all q-tiles of a head on one XCD
  int bid = blockIdx.x;
  int qt = (bid >> 3) & 15;
  int bh = (bid & 7) + ((bid >> 7) << 3);
  int q0 = qt * 128 + qsub * 32;
  const ushort* Qp = Qb  + (size_t)bh * 131072 + (size_t)q0 * 64;
  const ushort* Kp = Kb  + (size_t)bh * 131072;
  const ushort* Vp = Vtb + (size_t)bh * 131072;

  // Q as B-operand: col = q = lc5, k-dim = d: slice ks -> d = ks*16+8*hi+i
  bf16x8 qf[4];
#pragma unroll
  for (int ks = 0; ks < 4; ks++)
    qf[ks] = *(const bf16x8*)(Qp + lc5 * 64 + ks * 16 + hi * 8);

  f32x16 o0, o1;
#pragma unroll
  for (int i = 0; i < 16; i++) { o0[i] = 0.f; o1[i] = 0.f; }
  float lsum = 0.f;

  // swizzled in-row chunk offsets: chunk(ks) = (2ks+hi) ^ (row&7), row&7=lc5&7
  int swz[4];
#pragma unroll
  for (int ks = 0; ks < 4; ks++)
    swz[ks] = (((2 * ks + hi) ^ (lc5 & 7)) << 4);
  const int rbase = lc5 * 128;

  // stage the 128-key pair [kvp, kvp+128) into buf: tile t = keys
  // [kvp+64t, kvp+64t+64).  4 gload_lds per thread per call.
  auto stage = [&](int buf, int kvp) {
    int r = tid >> 3, cp = tid & 7;
    int ubase = wid * 1024;
#pragma unroll
    for (int t = 0; t < 2; t++) {
      char* tb = ldsb + buf * 32768 + t * 16384;
      const ushort* gk = Kp + (size_t)(kvp + 64 * t + r) * 64 + ((cp ^ (r & 7)) << 3);
      __builtin_amdgcn_global_load_lds(AS1(gk), AS3(tb + ubase), 16, 0, 0);
      const ushort* gv = Vp + (size_t)r * 2048 + kvp + 64 * t + ((cp ^ (r & 7)) << 3);
      __builtin_amdgcn_global_load_lds(AS1(gv), AS3(tb + 8192 + ubase), 16, 0, 0);
    }
  };

  // softmax + pack one 32-key half: exp2, row-sum accumulate, -> 2 A-frags
  auto smpack = [&](f32x16& s, bf16x8* aout) {
#pragma unroll
    for (int i = 0; i < 16; i++) s[i] = fast_exp2(s[i]);
    float acc = 0.f;
#pragma unroll
    for (int i = 0; i < 16; i++) acc += s[i];
    lsum += acc;
#pragma unroll
    for (int h2 = 0; h2 < 2; h2++) {
      int rb = 8 * h2;
      uint32_t wa1 = pkbf16(s[rb],     s[rb + 1]);
      uint32_t wb1 = pkbf16(s[rb + 4], s[rb + 5]);
      asm("v_permlane32_swap_b32 %0, %1" : "+v"(wa1), "+v"(wb1));
      uint32_t wa2 = pkbf16(s[rb + 2], s[rb + 3]);
      uint32_t wb2 = pkbf16(s[rb + 6], s[rb + 7]);
      asm("v_permlane32_swap_b32 %0, %1" : "+v"(wa2), "+v"(wb2));
      union { uint32_t u[4]; bf16x8 v; } tmp;
      tmp.u[0] = wa1; tmp.u[1] = wa2; tmp.u[2] = wb1; tmp.u[3] = wb2;
      aout[h2] = tmp.v;
    }
  };

  stage(0, 0);      // pair 0 -> buf 0   (4 loads)
  stage(1, 128);    // pair 1 -> buf 1   (4 loads)
  int cur = 0;

  for (int kvp = 0; kvp < 2048; kvp += 128) {
    // wait MY pair-p loads (oldest 4); keep pair-(p+1)'s 4 in flight
    if (kvp + 128 < 2048) asm volatile("s_waitcnt vmcnt(4)" ::: "memory");
    else                  asm volatile("s_waitcnt vmcnt(0)" ::: "memory");
    asm volatile("s_barrier" ::: "memory");   // pair-p writes visible block-wide

    const char* kbuf = ldsb + cur * 32768 + grp * 16384;   // my tile
    const char* vbuf = kbuf + 8192;

    // --- QK chains: s0 fully first, then s1 (independent chains) ---
    f32x16 s0 = {}, s1 = {};
    __builtin_amdgcn_s_setprio(1);
#pragma unroll
    for (int ks = 0; ks < 4; ks++) {
      bf16x8 ka0 = *(const bf16x8*)(kbuf + rbase + swz[ks]);
      s0 = __builtin_amdgcn_mfma_f32_32x32x16_bf16(ka0, qf[ks], s0, 0, 0, 0);
    }
#pragma unroll
    for (int ks = 0; ks < 4; ks++) {
      bf16x8 ka1 = *(const bf16x8*)(kbuf + 4096 + rbase + swz[ks]);
      s1 = __builtin_amdgcn_mfma_f32_32x32x16_bf16(ka1, qf[ks], s1, 0, 0, 0);
    }
    __builtin_amdgcn_s_setprio(0);

    // --- softmax(s0): VALU overlaps s1's in-flight MFMAs ---
    bf16x8 a01[2], a23[2];
    smpack(s0, a01);

    // --- PV ks=0,1 (uses only a01): MFMA overlaps softmax(s1) below ---
    __builtin_amdgcn_s_setprio(1);
#pragma unroll
    for (int ks = 0; ks < 2; ks++) {
      bf16x8 vb0 = *(const bf16x8*)(vbuf + rbase + swz[ks]);
      bf16x8 vb1 = *(const bf16x8*)(vbuf + 4096 + rbase + swz[ks]);
      o0 = __builtin_amdgcn_mfma_f32_32x32x16_bf16(a01[ks], vb0, o0, 0, 0, 0);
      o1 = __builtin_amdgcn_mfma_f32_32x32x16_bf16(a01[ks], vb1, o1, 0, 0, 0);
    }
    __builtin_amdgcn_s_setprio(0);

    // --- softmax(s1): VALU overlaps PV ks=0,1 ---
    smpack(s1, a23);

    // --- PV ks=2,3 ---
    __builtin_amdgcn_s_setprio(1);
#pragma unroll
    for (int ks = 2; ks < 4; ks++) {
      bf16x8 vb0 = *(const bf16x8*)(vbuf + rbase + swz[ks]);
      bf16x8 vb1 = *(const bf16x8*)(vbuf + 4096 + rbase + swz[ks]);
      o0 = __builtin_amdgcn_mfma_f32_32x32x16_bf16(a23[ks - 2], vb0, o0, 0, 0, 0);
      o1 = __builtin_amdgcn_mfma_f32_32x32x16_bf16(a23[ks - 2], vb1, o1, 0, 0, 0);
    }
    __builtin_amdgcn_s_setprio(0);

    asm volatile("s_barrier" ::: "memory");   // all waves done reading buf cur
    if (kvp + 256 < 2048) stage(cur, kvp + 256);   // overwrite freed buffer
    cur ^= 1;
  }

  // combine the two kv-halves: group 1 writes partials, group 0 adds.
  // stride 33 floats (odd) -> conflict-free.  ldsb free: vmcnt drained at
  // last iter, all reads done at its trailing barrier.
  float* cb = (float*)ldsb;
  float* p = cb + (size_t)(qsub * 64 + lane) * 33;
  if (grp == 1) {
#pragma unroll
    for (int i = 0; i < 16; i++) { p[i] = o0[i]; p[16 + i] = o1[i]; }
    p[32] = lsum;
  }
  __syncthreads();
  if (grp == 0) {
#pragma unroll
    for (int i = 0; i < 16; i++) { o0[i] += p[i]; o1[i] += p[16 + i]; }
    lsum += p[32];

    // combine the two key-halves of lsum (lanes q and q+32), then normalize
    lsum += __shfl_xor(lsum, 32);
    float invq = 1.0f / lsum;
    float invr[16];
#pragma unroll
    for (int r = 0; r < 16; r++)
      invr[r] = __shfl(invq, (r & 3) + 8 * (r >> 2) + 4 * hi);

    int b = bh >> 4, h = bh & 15;
    ushort* Op = Ob + (size_t)(b * 2048 + q0) * 1024 + h * 64 + lc5;
#pragma unroll
    for (int r = 0; r < 16; r++) {
      int rrow = (r & 3) + 8 * (r >> 2) + 4 * hi;
      Op[(size_t)rrow * 1024]      = f2b(o0[r] * invr[r]);
      Op[(size_t)rrow * 1024 + 32] = f2b(o1[r] * invr[r]);
    }
  }
}

// ---------------------------------------------------------------------------
// Workspace layout: xb 8M | wqb/wkb/wvb/wob 2M each | Qb 8M | Kb 8M | Vtb 8M
// | Ob 8M  (total 48 MiB).  The rope cos/sin table (512 KB) borrows the
// head of the Ob region: alive only cvt->qkv; attn overwrites it later.
// ---------------------------------------------------------------------------
extern "C" void kernel_launch(void* const* d_in, const int* in_sizes, int n_in,
                              void* d_out, int out_size, void* d_ws, size_t ws_size,
                              hipStream_t stream) {
  const float* x  = (const float*)d_in[0];
  const float* wq = (const float*)d_in[1];
  const float* wk = (const float*)d_in[2];
  const float* wv = (const float*)d_in[3];
  const float* wo = (const float*)d_in[4];
  float* out = (float*)d_out;
  char* ws = (char*)d_ws;
  const size_t MiB = 1024 * 1024;
  ushort* xb  = (ushort*)(ws + 0);
  ushort* wqb = (ushort*)(ws + 8 * MiB);
  ushort* wkb = (ushort*)(ws + 10 * MiB);
  ushort* wvb = (ushort*)(ws + 12 * MiB);
  ushort* wob = (ushort*)(ws + 14 * MiB);
  ushort* Qb  = (ushort*)(ws + 16 * MiB);
  ushort* Kb  = (ushort*)(ws + 24 * MiB);
  ushort* Vtb = (ushort*)(ws + 32 * MiB);
  ushort* Ob  = (ushort*)(ws + 40 * MiB);
  float2* tab = (float2*)Ob;                 // 65536 * 8B = 512 KB, transient

  cvt_all_k<<<8192, 256, 0, stream>>>(x, wq, wk, wv, wo, xb, tab);
  dim3 gqkv(32, 8, 3);
  gemm_qkv_k<<<gqkv, 256, 0, stream>>>(xb, wqb, wkb, wvb, tab, Qb, Kb, Vtb);
  attn_k<<<512, 512, 0, stream>>>(Qb, Kb, Vtb, Ob);
  dim3 gout(32, 8);
  gemm_out_k<<<gout, 256, 0, stream>>>(Ob, wob, out);
}

// Round 16
// 102.363 us; speedup vs baseline: 3.2747x; 1.0133x over previous
//
#include <hip/hip_runtime.h>
#include <hip/hip_bf16.h>
#include <stdint.h>

// ---------------------------------------------------------------------------
// MHA block: out = softmax( rope(xWq^T) rope(xWk^T)^T / 8 ) (xWv^T) Wo^T
// B=2 S=2048 H=16 D=64 DIM=1024.  bf16 MFMA compute, fp32 accum/softmax.
// ---------------------------------------------------------------------------

#define AS1(p) ((const __attribute__((address_space(1))) void*)(p))
#define AS3(p) ((__attribute__((address_space(3))) void*)(p))

typedef __attribute__((ext_vector_type(8)))  __bf16 bf16x8;
typedef __attribute__((ext_vector_type(4)))  float  f32x4;
typedef __attribute__((ext_vector_type(16))) float  f32x16;

__device__ __forceinline__ ushort f2b(float f) {
  union { float f; uint32_t u; } v; v.f = f;
  uint32_t u = v.u;
  u += 0x7fffu + ((u >> 16) & 1);   // RNE
  return (ushort)(u >> 16);
}
__device__ __forceinline__ float b2f(ushort s) {
  union { uint32_t u; float f; } v; v.u = ((uint32_t)s) << 16;
  return v.f;
}
__device__ __forceinline__ uint32_t pkbf16(float lo, float hi) {
  uint32_t w;
  asm("v_cvt_pk_bf16_f32 %0, %1, %2" : "=v"(w) : "v"(lo), "v"(hi));
  return w;
}
// Fast exp2 via native v_exp_f32.  R10 LESSON: raw inline-asm v_exp_f32 has
// a TRANS->VALU dependent-use hazard the compiler does NOT guard for asm.
// Prefer the builtin; asm fallback carries its own s_nop.
__device__ __forceinline__ float fast_exp2(float x) {
#if __has_builtin(__builtin_amdgcn_exp2f)
  return __builtin_amdgcn_exp2f(x);
#else
  float r;
  asm("v_exp_f32 %0, %1\n\ts_nop 1" : "=v"(r) : "v"(x));
  return r;
#endif
}

// ---------------------------------------------------------------------------
// 1) fp32 -> bf16 conversion of x and the four weights; ALSO generates the
//    RoPE cos/sin table (2048 x 32 float2, 512 KB) used by gemm_qkv's fused
//    rope epilogue.  Table lives in the Ob region (dead until attn runs).
// ---------------------------------------------------------------------------
__global__ __launch_bounds__(256) void cvt_all_k(
    const float* __restrict__ x,  const float* __restrict__ wq,
    const float* __restrict__ wk, const float* __restrict__ wv,
    const float* __restrict__ wo, ushort* __restrict__ dst,
    float2* __restrict__ tab) {
  int i = blockIdx.x * 256 + threadIdx.x;          // 2,097,152 total
  const float* src;
  if      (i < 1048576) src = x  + (size_t)i * 4;
  else if (i < 1310720) src = wq + (size_t)(i - 1048576) * 4;
  else if (i < 1572864) src = wk + (size_t)(i - 1310720) * 4;
  else if (i < 1835008) src = wv + (size_t)(i - 1572864) * 4;
  else                  src = wo + (size_t)(i - 1835008) * 4;
  float4 v = *(const float4*)src;
  ushort4 o;
  o.x = f2b(v.x); o.y = f2b(v.y); o.z = f2b(v.z); o.w = f2b(v.w);
  ((ushort4*)dst)[i] = o;

  if (i < 65536) {                                 // rope table: s x dp
    int s = i >> 5, dp = i & 31;
    float inv = exp2f((float)dp * (-13.2877123795494f / 32.0f));
    float ang = (float)s * inv;
    float sn, cs;
    sincosf(ang, &sn, &cs);
    tab[i] = make_float2(cs, sn);
  }
}

// ---------------------------------------------------------------------------
// 2) GEMM mainloop: C = A(MxK) * W(NxK)^T, 128x128 tile, BK=32, 4 waves (2x2).
//    Double-buffered LDS, single barrier per K-step (stage(next) || compute).
// ---------------------------------------------------------------------------
__device__ __forceinline__ void gemm_mainloop(
    const ushort* __restrict__ A, const ushort* __restrict__ W,
    int row0, int col0, ushort* lds, f32x4 acc[4][4]) {
  const int K = 1024;
  int tid = threadIdx.x;
  int lane = tid & 63, wid = tid >> 6;
  int wr = wid >> 1, wc = wid & 1;
  int lr = lane >> 4, lc = lane & 15;
  ushort* lA = lds;
  ushort* lB = lds + 8192;

  auto stage = [&](int buf, int k0) {
#pragma unroll
    for (int i = 0; i < 2; i++) {
      int idx = tid + i * 256;                       // 16B chunk id, 4 per row
      const ushort* ga = A + (size_t)(row0 + (idx >> 2)) * K + k0 + (idx & 3) * 8;
      __builtin_amdgcn_global_load_lds(AS1(ga),
          AS3(lA + buf * 4096 + (i * 256 + wid * 64) * 8), 16, 0, 0);
      const ushort* gb = W + (size_t)(col0 + (idx >> 2)) * K + k0 + (idx & 3) * 8;
      __builtin_amdgcn_global_load_lds(AS1(gb),
          AS3(lB + buf * 4096 + (i * 256 + wid * 64) * 8), 16, 0, 0);
    }
  };

  stage(0, 0);
  __syncthreads();
  int cur = 0;
  for (int k0 = 0; k0 < K; k0 += 32) {
    if (k0 + 32 < K) stage(cur ^ 1, k0 + 32);
    const ushort* a  = lA + cur * 4096;
    const ushort* bm = lB + cur * 4096;
    bf16x8 af[4], bfr[4];
#pragma unroll
    for (int m = 0; m < 4; m++)
      af[m] = *(const bf16x8*)(a + (wr * 64 + m * 16 + lc) * 32 + lr * 8);
#pragma unroll
    for (int n = 0; n < 4; n++)
      bfr[n] = *(const bf16x8*)(bm + (wc * 64 + n * 16 + lc) * 32 + lr * 8);
#pragma unroll
    for (int m = 0; m < 4; m++)
#pragma unroll
      for (int n = 0; n < 4; n++)
        acc[m][n] = __builtin_amdgcn_mfma_f32_16x16x32_bf16(af[m], bfr[n], acc[m][n], 0, 0, 0);
    __syncthreads();     // drains: my ds_reads + next-buffer gload_lds writes
    cur ^= 1;
  }
}

// QKV projections in one launch (z = 0:Q, 1:K, 2:V).
// Q,K -> [B,H,S,D] with FUSED ROPE (rotation pair (d, d+32) lives in the
// same thread: acc[m][n] and acc[m][n+2] for n<2); Q scaled by 0.125*log2e
// so attention scores are natively exp2-domain.  cos/sin from tab (L2).
// V -> [B,H,D,S] via XOR-swizzled LDS transpose.
__global__ __launch_bounds__(256) void gemm_qkv_k(
    const ushort* __restrict__ xb,
    const ushort* __restrict__ wqb, const ushort* __restrict__ wkb,
    const ushort* __restrict__ wvb,
    const float2* __restrict__ tab,
    ushort* __restrict__ Qb, ushort* __restrict__ Kb, ushort* __restrict__ Vtb) {
  __shared__ ushort lds[16384];        // 32 KiB: dbuf staging, then V scratch
  int z = blockIdx.z;
  const ushort* w = (z == 0) ? wqb : (z == 1) ? wkb : wvb;
  int row0 = blockIdx.x * 128, col0 = blockIdx.y * 128;
  f32x4 acc[4][4] = {};
  gemm_mainloop(xb, w, row0, col0, lds, acc);

  int tid = threadIdx.x, lane = tid & 63, wid = tid >> 6;
  int wr = wid >> 1, wc = wid & 1, lr = lane >> 4, lc = lane & 15;

  if (z < 2) {
    ushort* dst = (z == 0) ? Qb : Kb;
    const float qs = (z == 0) ? 0.125f * 1.44269504088896f : 1.0f;
#pragma unroll
    for (int m = 0; m < 4; m++)
#pragma unroll
      for (int n = 0; n < 2; n++)
#pragma unroll
        for (int j = 0; j < 4; j++) {
          int i = row0 + wr * 64 + m * 16 + lr * 4 + j;   // row: b,s
          int c = col0 + wc * 64 + n * 16 + lc;           // col: h,d (d<32)
          int b = i >> 11, s = i & 2047, h = c >> 6, dp = c & 31;
          float2 cs = tab[s * 32 + dp];
          float q1 = acc[m][n][j], q2 = acc[m][n + 2][j];
          float r1 = (q1 * cs.x - q2 * cs.y) * qs;
          float r2 = (q2 * cs.x + q1 * cs.y) * qs;
          size_t base = (size_t)(b * 16 + h) * 131072 + (size_t)s * 64;
          dst[base + dp]      = f2b(r1);
          dst[base + dp + 32] = f2b(r2);
        }
  } else {
    // V: transpose 128x128 tile through LDS (free after final barrier).
#pragma unroll
    for (int m = 0; m < 4; m++)
#pragma unroll
      for (int n = 0; n < 4; n++) {
        int c = wc * 64 + n * 16 + lc;
        int sb = wr * 64 + m * 16 + lr * 4;            // j=0..3 consecutive
        uint32_t w0 = pkbf16(acc[m][n][0], acc[m][n][1]);
        uint32_t w1 = pkbf16(acc[m][n][2], acc[m][n][3]);
        int soff = sb ^ ((c & 7) << 3);                // multiple of 4 ushorts
        uint2 val; val.x = w0; val.y = w1;
        *(uint2*)(lds + c * 128 + soff) = val;         // 8B store
      }
    __syncthreads();
    int b = row0 >> 11, srow = row0 & 2047;
#pragma unroll
    for (int i = 0; i < 8; i++) {
      int idx = i * 256 + tid;                 // 2048 16B chunks
      int cl = idx >> 4, sc = idx & 15;
      int soff = (sc * 8) ^ ((cl & 7) << 3);
      bf16x8 v = *(const bf16x8*)(lds + cl * 128 + soff);
      int cg = col0 + cl, h = cg >> 6, d = cg & 63;
      *(bf16x8*)(Vtb + (size_t)(b * 16 + h) * 131072 + (size_t)d * 2048 + srow + sc * 8) = v;
    }
  }
}

// Final projection: out(fp32) = attn @ Wo^T.
// R16: 128x64 tile (grid 32x16 = 512 blocks -> 2 blocks/CU vs the 128x128
// version's 1/CU -- gemm_out was occupancy-starved at 1 wave/SIMD).
// Wave owns 32 rows x 64 cols: acc[2][4], 8 MFMA/K-step.
__global__ __launch_bounds__(256) void gemm_out_k(
    const ushort* __restrict__ Ab, const ushort* __restrict__ wob,
    float* __restrict__ out) {
  __shared__ ushort lds[12288];   // lA dbuf 2x[128][32], lB dbuf 2x[64][32]
  const int K = 1024;
  int tid = threadIdx.x, lane = tid & 63, wid = tid >> 6;
  int lr = lane >> 4, lc = lane & 15;
  int row0 = blockIdx.x * 128, col0 = blockIdx.y * 64;
  ushort* lA = lds;
  ushort* lB = lds + 8192;

  auto stage = [&](int buf, int k0) {
#pragma unroll
    for (int i = 0; i < 2; i++) {
      int idx = tid + i * 256;                       // A: 512 chunks, 4/row
      const ushort* ga = Ab + (size_t)(row0 + (idx >> 2)) * K + k0 + (idx & 3) * 8;
      __builtin_amdgcn_global_load_lds(AS1(ga),
          AS3(lA + buf * 4096 + (i * 256 + wid * 64) * 8), 16, 0, 0);
    }
    // B: 256 chunks (64 rows x 4), one per thread; wave-uniform dest
    const ushort* gb = wob + (size_t)(col0 + (tid >> 2)) * K + k0 + (tid & 3) * 8;
    __builtin_amdgcn_global_load_lds(AS1(gb),
        AS3(lB + buf * 2048 + wid * 512), 16, 0, 0);
  };

  f32x4 acc[2][4] = {};
  stage(0, 0);
  __syncthreads();
  int cur = 0;
  for (int k0 = 0; k0 < K; k0 += 32) {
    if (k0 + 32 < K) stage(cur ^ 1, k0 + 32);
    const ushort* a  = lA + cur * 4096;
    const ushort* bm = lB + cur * 2048;
    bf16x8 af[2], bfr[4];
#pragma unroll
    for (int m = 0; m < 2; m++)
      af[m] = *(const bf16x8*)(a + (wid * 32 + m * 16 + lc) * 32 + lr * 8);
#pragma unroll
    for (int n = 0; n < 4; n++)
      bfr[n] = *(const bf16x8*)(bm + (n * 16 + lc) * 32 + lr * 8);
#pragma unroll
    for (int m = 0; m < 2; m++)
#pragma unroll
      for (int n = 0; n < 4; n++)
        acc[m][n] = __builtin_amdgcn_mfma_f32_16x16x32_bf16(af[m], bfr[n], acc[m][n], 0, 0, 0);
    __syncthreads();
    cur ^= 1;
  }

  int base_r = row0 + wid * 32;
#pragma unroll
  for (int m = 0; m < 2; m++)
#pragma unroll
    for (int n = 0; n < 4; n++)
#pragma unroll
      for (int j = 0; j < 4; j++) {
        int i = base_r + m * 16 + lr * 4 + j;
        int c = col0 + n * 16 + lc;
        out[(size_t)i * 1024 + c] = acc[m][n][j];
      }
}

// ---------------------------------------------------------------------------
// 3) Flash attention, 32x32 swapped-QK + within-block KV-split + counted
//    vmcnt pipeline + intra-iteration MFMA/VALU interleave (R15 form).
// ---------------------------------------------------------------------------
__global__ __launch_bounds__(512, 4) void attn_k(
    const ushort* __restrict__ Qb, const ushort* __restrict__ Kb,
    const ushort* __restrict__ Vtb, ushort* __restrict__ Ob) {
  __shared__ char ldsb[65536];   // [buf:2][tile:2][K 8KB | V 8KB]; reused
  int tid = threadIdx.x, lane = tid & 63, wid = tid >> 6;   // wid in [0,8)
  int lc5 = lane & 31, hi = lane >> 5;
  int qsub = wid & 3, grp = wid >> 2;

  // XCD swizzle: all q-tiles of a head on one XCD
  int bid = blockIdx.x;
  int qt = (bid >> 3) & 15;
  int bh = (bid & 7) + ((bid >> 7) << 3);
  int q0 = qt * 128 + qsub * 32;
  const ushort* Qp = Qb  + (size_t)bh * 131072 + (size_t)q0 * 64;
  const ushort* Kp = Kb  + (size_t)bh * 131072;
  const ushort* Vp = Vtb + (size_t)bh * 131072;

  // Q as B-operand: col = q = lc5, k-dim = d: slice ks -> d = ks*16+8*hi+i
  bf16x8 qf[4];
#pragma unroll
  for (int ks = 0; ks < 4; ks++)
    qf[ks] = *(const bf16x8*)(Qp + lc5 * 64 + ks * 16 + hi * 8);

  f32x16 o0, o1;
#pragma unroll
  for (int i = 0; i < 16; i++) { o0[i] = 0.f; o1[i] = 0.f; }
  float lsum = 0.f;

  // swizzled in-row chunk offsets: chunk(ks) = (2ks+hi) ^ (row&7), row&7=lc5&7
  int swz[4];
#pragma unroll
  for (int ks = 0; ks < 4; ks++)
    swz[ks] = (((2 * ks + hi) ^ (lc5 & 7)) << 4);
  const int rbase = lc5 * 128;

  // stage the 128-key pair [kvp, kvp+128) into buf: tile t = keys
  // [kvp+64t, kvp+64t+64).  4 gload_lds per thread per call.
  auto stage = [&](int buf, int kvp) {
    int r = tid >> 3, cp = tid & 7;
    int ubase = wid * 1024;
#pragma unroll
    for (int t = 0; t < 2; t++) {
      char* tb = ldsb + buf * 32768 + t * 16384;
      const ushort* gk = Kp + (size_t)(kvp + 64 * t + r) * 64 + ((cp ^ (r & 7)) << 3);
      __builtin_amdgcn_global_load_lds(AS1(gk), AS3(tb + ubase), 16, 0, 0);
      const ushort* gv = Vp + (size_t)r * 2048 + kvp + 64 * t + ((cp ^ (r & 7)) << 3);
      __builtin_amdgcn_global_load_lds(AS1(gv), AS3(tb + 8192 + ubase), 16, 0, 0);
    }
  };

  // softmax + pack one 32-key half: exp2, row-sum accumulate, -> 2 A-frags
  auto smpack = [&](f32x16& s, bf16x8* aout) {
#pragma unroll
    for (int i = 0; i < 16; i++) s[i] = fast_exp2(s[i]);
    float acc = 0.f;
#pragma unroll
    for (int i = 0; i < 16; i++) acc += s[i];
    lsum += acc;
#pragma unroll
    for (int h2 = 0; h2 < 2; h2++) {
      int rb = 8 * h2;
      uint32_t wa1 = pkbf16(s[rb],     s[rb + 1]);
      uint32_t wb1 = pkbf16(s[rb + 4], s[rb + 5]);
      asm("v_permlane32_swap_b32 %0, %1" : "+v"(wa1), "+v"(wb1));
      uint32_t wa2 = pkbf16(s[rb + 2], s[rb + 3]);
      uint32_t wb2 = pkbf16(s[rb + 6], s[rb + 7]);
      asm("v_permlane32_swap_b32 %0, %1" : "+v"(wa2), "+v"(wb2));
      union { uint32_t u[4]; bf16x8 v; } tmp;
      tmp.u[0] = wa1; tmp.u[1] = wa2; tmp.u[2] = wb1; tmp.u[3] = wb2;
      aout[h2] = tmp.v;
    }
  };

  stage(0, 0);      // pair 0 -> buf 0   (4 loads)
  stage(1, 128);    // pair 1 -> buf 1   (4 loads)
  int cur = 0;

  for (int kvp = 0; kvp < 2048; kvp += 128) {
    // wait MY pair-p loads (oldest 4); keep pair-(p+1)'s 4 in flight
    if (kvp + 128 < 2048) asm volatile("s_waitcnt vmcnt(4)" ::: "memory");
    else                  asm volatile("s_waitcnt vmcnt(0)" ::: "memory");
    asm volatile("s_barrier" ::: "memory");   // pair-p writes visible block-wide

    const char* kbuf = ldsb + cur * 32768 + grp * 16384;   // my tile
    const char* vbuf = kbuf + 8192;

    // --- QK chains: s0 fully first, then s1 (independent chains) ---
    f32x16 s0 = {}, s1 = {};
    __builtin_amdgcn_s_setprio(1);
#pragma unroll
    for (int ks = 0; ks < 4; ks++) {
      bf16x8 ka0 = *(const bf16x8*)(kbuf + rbase + swz[ks]);
      s0 = __builtin_amdgcn_mfma_f32_32x32x16_bf16(ka0, qf[ks], s0, 0, 0, 0);
    }
#pragma unroll
    for (int ks = 0; ks < 4; ks++) {
      bf16x8 ka1 = *(const bf16x8*)(kbuf + 4096 + rbase + swz[ks]);
      s1 = __builtin_amdgcn_mfma_f32_32x32x16_bf16(ka1, qf[ks], s1, 0, 0, 0);
    }
    __builtin_amdgcn_s_setprio(0);

    // --- softmax(s0): VALU overlaps s1's in-flight MFMAs ---
    bf16x8 a01[2], a23[2];
    smpack(s0, a01);

    // --- PV ks=0,1 (uses only a01): MFMA overlaps softmax(s1) below ---
    __builtin_amdgcn_s_setprio(1);
#pragma unroll
    for (int ks = 0; ks < 2; ks++) {
      bf16x8 vb0 = *(const bf16x8*)(vbuf + rbase + swz[ks]);
      bf16x8 vb1 = *(const bf16x8*)(vbuf + 4096 + rbase + swz[ks]);
      o0 = __builtin_amdgcn_mfma_f32_32x32x16_bf16(a01[ks], vb0, o0, 0, 0, 0);
      o1 = __builtin_amdgcn_mfma_f32_32x32x16_bf16(a01[ks], vb1, o1, 0, 0, 0);
    }
    __builtin_amdgcn_s_setprio(0);

    // --- softmax(s1): VALU overlaps PV ks=0,1 ---
    smpack(s1, a23);

    // --- PV ks=2,3 ---
    __builtin_amdgcn_s_setprio(1);
#pragma unroll
    for (int ks = 2; ks < 4; ks++) {
      bf16x8 vb0 = *(const bf16x8*)(vbuf + rbase + swz[ks]);
      bf16x8 vb1 = *(const bf16x8*)(vbuf + 4096 + rbase + swz[ks]);
      o0 = __builtin_amdgcn_mfma_f32_32x32x16_bf16(a23[ks - 2], vb0, o0, 0, 0, 0);
      o1 = __builtin_amdgcn_mfma_f32_32x32x16_bf16(a23[ks - 2], vb1, o1, 0, 0, 0);
    }
    __builtin_amdgcn_s_setprio(0);

    asm volatile("s_barrier" ::: "memory");   // all waves done reading buf cur
    if (kvp + 256 < 2048) stage(cur, kvp + 256);   // overwrite freed buffer
    cur ^= 1;
  }

  // combine the two kv-halves: group 1 writes partials, group 0 adds.
  // stride 33 floats (odd) -> conflict-free.  ldsb free: vmcnt drained at
  // last iter, all reads done at its trailing barrier.
  float* cb = (float*)ldsb;
  float* p = cb + (size_t)(qsub * 64 + lane) * 33;
  if (grp == 1) {
#pragma unroll
    for (int i = 0; i < 16; i++) { p[i] = o0[i]; p[16 + i] = o1[i]; }
    p[32] = lsum;
  }
  __syncthreads();
  if (grp == 0) {
#pragma unroll
    for (int i = 0; i < 16; i++) { o0[i] += p[i]; o1[i] += p[16 + i]; }
    lsum += p[32];

    // combine the two key-halves of lsum (lanes q and q+32), then normalize
    lsum += __shfl_xor(lsum, 32);
    float invq = 1.0f / lsum;
    float invr[16];
#pragma unroll
    for (int r = 0; r < 16; r++)
      invr[r] = __shfl(invq, (r & 3) + 8 * (r >> 2) + 4 * hi);

    int b = bh >> 4, h = bh & 15;
    ushort* Op = Ob + (size_t)(b * 2048 + q0) * 1024 + h * 64 + lc5;
#pragma unroll
    for (int r = 0; r < 16; r++) {
      int rrow = (r & 3) + 8 * (r >> 2) + 4 * hi;
      Op[(size_t)rrow * 1024]      = f2b(o0[r] * invr[r]);
      Op[(size_t)rrow * 1024 + 32] = f2b(o1[r] * invr[r]);
    }
  }
}

// ---------------------------------------------------------------------------
// Workspace layout: xb 8M | wqb/wkb/wvb/wob 2M each | Qb 8M | Kb 8M | Vtb 8M
// | Ob 8M  (total 48 MiB).  The rope cos/sin table (512 KB) borrows the
// head of the Ob region: alive only cvt->qkv; attn overwrites it later.
// ---------------------------------------------------------------------------
extern "C" void kernel_launch(void* const* d_in, const int* in_sizes, int n_in,
                              void* d_out, int out_size, void* d_ws, size_t ws_size,
                              hipStream_t stream) {
  const float* x  = (const float*)d_in[0];
  const float* wq = (const float*)d_in[1];
  const float* wk = (const float*)d_in[2];
  const float* wv = (const float*)d_in[3];
  const float* wo = (const float*)d_in[4];
  float* out = (float*)d_out;
  char* ws = (char*)d_ws;
  const size_t MiB = 1024 * 1024;
  ushort* xb  = (ushort*)(ws + 0);
  ushort* wqb = (ushort*)(ws + 8 * MiB);
  ushort* wkb = (ushort*)(ws + 10 * MiB);
  ushort* wvb = (ushort*)(ws + 12 * MiB);
  ushort* wob = (ushort*)(ws + 14 * MiB);
  ushort* Qb  = (ushort*)(ws + 16 * MiB);
  ushort* Kb  = (ushort*)(ws + 24 * MiB);
  ushort* Vtb = (ushort*)(ws + 32 * MiB);
  ushort* Ob  = (ushort*)(ws + 40 * MiB);
  float2* tab = (float2*)Ob;                 // 65536 * 8B = 512 KB, transient

  cvt_all_k<<<8192, 256, 0, stream>>>(x, wq, wk, wv, wo, xb, tab);
  dim3 gqkv(32, 8, 3);
  gemm_qkv_k<<<gqkv, 256, 0, stream>>>(xb, wqb, wkb, wvb, tab, Qb, Kb, Vtb);
  attn_k<<<512, 512, 0, stream>>>(Qb, Kb, Vtb, Ob);
  dim3 gout(32, 16);
  gemm_out_k<<<gout, 256, 0, stream>>>(Ob, wob, out);
}